// Round 1
// baseline (1498.834 us; speedup 1.0000x reference)
//
#include <hip/hip_runtime.h>
#include <math.h>

// Problem constants
#define B_SZ   2
#define N_TOK  2048
#define DM     512
#define NH     8
#define DHH    64
#define NF     256     // nb_features (m)
#define DFF    2048
#define HF     2048    // NH*NF

constexpr float DN_SCALE   = 0.35355339059327373f; // 64^-0.25
constexpr float DIAG_SCALE = 0.0625f;              // 0.5 * dn^2
constexpr float RATIO      = 0.0625f;              // 256^-0.5
constexpr float FEPS       = 1e-4f;
constexpr float LN_EPS     = 1e-5f;

// Workspace layout (float offsets)
constexpr size_t OFF_QFEAT = 0;                       // [B,N,H,NF] = 8388608
constexpr size_t OFF_KFEAT = 8388608;                 // [B,N,H,NF]  (later: ff1 [4096,2048])
constexpr size_t OFF_QLIN  = 16777216;                // [4096,512]  (later: attn_out, then ff2)
constexpr size_t OFF_KLIN  = 18874368;                // [4096,512]  (later: out2)
constexpr size_t OFF_VLIN  = 20971520;                // [4096,512]  (later: h1)
constexpr size_t OFF_KSUM  = 23068672;                // [16,256]
constexpr size_t OFF_PART  = 23072768;                // [16,8,256]
constexpr size_t OFF_DINV  = 23105536;                // [16,2048]
constexpr size_t OFF_CTX   = 23138304;                // [16,256,64]
constexpr size_t OFF_BMAX  = 23400448;                // [32768]
constexpr size_t OFF_GMAX  = 23433216;                // [1]

// ---------------- generic NN GEMM: C = A[M,K] @ B[K,N] + bias, optional relu
template<bool RELU>
__global__ void gemm_nn(const float* __restrict__ A, const float* __restrict__ B,
                        const float* __restrict__ bias, float* __restrict__ C,
                        int M, int N, int K) {
  __shared__ float As[16][68];
  __shared__ float Bs[16][68];
  int bm = blockIdx.y * 64, bn = blockIdx.x * 64;
  int tid = threadIdx.x;
  int tm = (tid >> 4) * 4, tn = (tid & 15) * 4;
  float acc[4][4] = {};
  for (int k0 = 0; k0 < K; k0 += 16) {
    #pragma unroll
    for (int i = 0; i < 4; i++) {
      int idx = tid + i * 256;
      int m = idx >> 4, k = idx & 15;
      As[k][m] = A[(size_t)(bm + m) * K + k0 + k];
    }
    #pragma unroll
    for (int i = 0; i < 4; i++) {
      int idx = tid + i * 256;
      int k = idx >> 6, n = idx & 63;
      Bs[k][n] = B[(size_t)(k0 + k) * N + bn + n];
    }
    __syncthreads();
    #pragma unroll
    for (int k = 0; k < 16; k++) {
      float a[4], b[4];
      #pragma unroll
      for (int i = 0; i < 4; i++) a[i] = As[k][tm + i];
      #pragma unroll
      for (int j = 0; j < 4; j++) b[j] = Bs[k][tn + j];
      #pragma unroll
      for (int i = 0; i < 4; i++)
        #pragma unroll
        for (int j = 0; j < 4; j++) acc[i][j] += a[i] * b[j];
    }
    __syncthreads();
  }
  #pragma unroll
  for (int i = 0; i < 4; i++)
    #pragma unroll
    for (int j = 0; j < 4; j++) {
      float v = acc[i][j] + bias[bn + tn + j];
      if (RELU) v = fmaxf(v, 0.f);
      C[(size_t)(bm + tm + i) * N + bn + tn + j] = v;
    }
}

// ---------------- Q feature map: per-row max
__global__ void featq_kernel(const float* __restrict__ Qlin, const float* __restrict__ proj,
                             float* __restrict__ qfeat) {
  int n = blockIdx.x, bh = blockIdx.y, b = bh >> 3, h = bh & 7;
  int t = threadIdx.x;
  __shared__ float data[DHH];
  __shared__ float red[4];
  const float* row = Qlin + (size_t)(b * N_TOK + n) * DM + h * DHH;
  if (t < DHH) data[t] = row[t];
  __syncthreads();
  float dot = 0.f, s2 = 0.f;
  const float* pr = proj + t * DHH;
  #pragma unroll 8
  for (int d = 0; d < DHH; ++d) { float a = data[d]; dot += a * pr[d]; s2 += a * a; }
  float dd = DN_SCALE * dot;
  float diag = DIAG_SCALE * s2;
  float m = dd;
  #pragma unroll
  for (int o = 32; o > 0; o >>= 1) m = fmaxf(m, __shfl_xor(m, o, 64));
  if ((t & 63) == 0) red[t >> 6] = m;
  __syncthreads();
  if (t == 0) red[0] = fmaxf(fmaxf(red[0], red[1]), fmaxf(red[2], red[3]));
  __syncthreads();
  m = red[0];
  float v = RATIO * (expf(dd - diag - m) + FEPS);
  qfeat[(size_t)(b * N_TOK + n) * HF + h * NF + t] = v;
}

// ---------------- K feature map pass 1: store dd - diag, per-block max of dd
__global__ void featk1_kernel(const float* __restrict__ Klin, const float* __restrict__ proj,
                              float* __restrict__ ktmp, float* __restrict__ bmax) {
  int n = blockIdx.x, bh = blockIdx.y, b = bh >> 3, h = bh & 7;
  int t = threadIdx.x;
  __shared__ float data[DHH];
  __shared__ float red[4];
  const float* row = Klin + (size_t)(b * N_TOK + n) * DM + h * DHH;
  if (t < DHH) data[t] = row[t];
  __syncthreads();
  float dot = 0.f, s2 = 0.f;
  const float* pr = proj + t * DHH;
  #pragma unroll 8
  for (int d = 0; d < DHH; ++d) { float a = data[d]; dot += a * pr[d]; s2 += a * a; }
  float dd = DN_SCALE * dot;
  float diag = DIAG_SCALE * s2;
  ktmp[(size_t)(b * N_TOK + n) * HF + h * NF + t] = dd - diag;
  float m = dd;
  #pragma unroll
  for (int o = 32; o > 0; o >>= 1) m = fmaxf(m, __shfl_xor(m, o, 64));
  if ((t & 63) == 0) red[t >> 6] = m;
  __syncthreads();
  if (t == 0) bmax[bh * N_TOK + n] = fmaxf(fmaxf(red[0], red[1]), fmaxf(red[2], red[3]));
}

// ---------------- global max reduce
__global__ void gmax_kernel(const float* __restrict__ bmax, float* __restrict__ gmax) {
  __shared__ float red[4];
  float m = -3.4e38f;
  for (int i = threadIdx.x; i < B_SZ * NH * N_TOK; i += 256) m = fmaxf(m, bmax[i]);
  #pragma unroll
  for (int o = 32; o > 0; o >>= 1) m = fmaxf(m, __shfl_xor(m, o, 64));
  if ((threadIdx.x & 63) == 0) red[threadIdx.x >> 6] = m;
  __syncthreads();
  if (threadIdx.x == 0) gmax[0] = fmaxf(fmaxf(red[0], red[1]), fmaxf(red[2], red[3]));
}

// ---------------- K feature map pass 2: exponentiate
__global__ void featk2_kernel(float* __restrict__ kfeat, const float* __restrict__ gmax) {
  size_t i = (size_t)blockIdx.x * 256 + threadIdx.x;
  float M = gmax[0];
  kfeat[i] = RATIO * (expf(kfeat[i] - M) + FEPS);
}

// ---------------- ksum partial: sum over 256-row chunk
__global__ void ksum_part_kernel(const float* __restrict__ kfeat, float* __restrict__ part) {
  int f = threadIdx.x, chunk = blockIdx.x, bh = blockIdx.y;
  int b = bh >> 3, h = bh & 7;
  int n0 = chunk * 256;
  float s = 0.f;
  for (int n = n0; n < n0 + 256; ++n)
    s += kfeat[(size_t)(b * N_TOK + n) * HF + h * NF + f];
  part[(size_t)(bh * 8 + chunk) * NF + f] = s;
}

__global__ void ksum_final_kernel(const float* __restrict__ part, float* __restrict__ ksum) {
  int f = threadIdx.x, bh = blockIdx.x;
  float s = 0.f;
  #pragma unroll
  for (int c = 0; c < 8; ++c) s += part[(size_t)(bh * 8 + c) * NF + f];
  ksum[bh * NF + f] = s;
}

// ---------------- D_inv: one wave per row
__global__ void dinv_kernel(const float* __restrict__ qfeat, const float* __restrict__ ksum,
                            float* __restrict__ Dinv) {
  __shared__ float ks[NF];
  int r0 = blockIdx.x * 4;
  int bh = r0 >> 11, b = bh >> 3, h = bh & 7;
  int n0 = r0 & 2047;
  int lane = threadIdx.x & 63, w = threadIdx.x >> 6;
  ks[threadIdx.x] = ksum[bh * NF + threadIdx.x];
  __syncthreads();
  int n = n0 + w;
  const float* qr = qfeat + (size_t)(b * N_TOK + n) * HF + h * NF;
  float s = 0.f;
  #pragma unroll
  for (int f0 = 0; f0 < NF; f0 += 64) s += qr[f0 + lane] * ks[f0 + lane];
  #pragma unroll
  for (int o = 32; o > 0; o >>= 1) s += __shfl_xor(s, o, 64);
  if (lane == 0) Dinv[bh * N_TOK + n] = 1.0f / s;
}

// ---------------- context: ctx[bh][f][e] = sum_n kfeat[n,f] * v[n,e]
__global__ void ctx_kernel(const float* __restrict__ kfeat, const float* __restrict__ Vlin,
                           float* __restrict__ ctx) {
  int bh = blockIdx.y, b = bh >> 3, h = bh & 7;
  int f0 = blockIdx.x * 64;
  __shared__ float kf[32][68];
  __shared__ float vs[32][68];
  int tid = threadIdx.x;
  int tf = (tid >> 4) * 4, te = (tid & 15) * 4;
  float acc[4][4] = {};
  for (int n0 = 0; n0 < N_TOK; n0 += 32) {
    #pragma unroll
    for (int i = 0; i < 8; i++) {
      int idx = tid + i * 256;
      int nn = idx >> 6, f = idx & 63;
      kf[nn][f] = kfeat[(size_t)(b * N_TOK + n0 + nn) * HF + h * NF + f0 + f];
    }
    #pragma unroll
    for (int i = 0; i < 8; i++) {
      int idx = tid + i * 256;
      int nn = idx >> 6, e = idx & 63;
      vs[nn][e] = Vlin[(size_t)(b * N_TOK + n0 + nn) * DM + h * DHH + e];
    }
    __syncthreads();
    #pragma unroll
    for (int nn = 0; nn < 32; nn++) {
      float a[4], bb[4];
      #pragma unroll
      for (int i = 0; i < 4; i++) a[i] = kf[nn][tf + i];
      #pragma unroll
      for (int j = 0; j < 4; j++) bb[j] = vs[nn][te + j];
      #pragma unroll
      for (int i = 0; i < 4; i++)
        #pragma unroll
        for (int j = 0; j < 4; j++) acc[i][j] += a[i] * bb[j];
    }
    __syncthreads();
  }
  #pragma unroll
  for (int i = 0; i < 4; i++)
    #pragma unroll
    for (int j = 0; j < 4; j++)
      ctx[(size_t)bh * NF * DHH + (size_t)(f0 + tf + i) * DHH + te + j] = acc[i][j];
}

// ---------------- PV: attn_out[b,n,h*64+e] = Dinv * (qfeat row @ ctx)
__global__ void pv_kernel(const float* __restrict__ qfeat, const float* __restrict__ ctx,
                          const float* __restrict__ Dinv, float* __restrict__ attn_out) {
  int bh = blockIdx.y, b = bh >> 3, h = bh & 7;
  int n0 = blockIdx.x * 64;
  __shared__ float qs[16][68];
  __shared__ float cs[16][68];
  int tid = threadIdx.x;
  int tn = (tid >> 4) * 4, te = (tid & 15) * 4;
  float acc[4][4] = {};
  for (int k0 = 0; k0 < NF; k0 += 16) {
    #pragma unroll
    for (int i = 0; i < 4; i++) {
      int idx = tid + i * 256;
      int n = idx >> 4, k = idx & 15;
      qs[k][n] = qfeat[(size_t)(b * N_TOK + n0 + n) * HF + h * NF + k0 + k];
    }
    #pragma unroll
    for (int i = 0; i < 4; i++) {
      int idx = tid + i * 256;
      int k = idx >> 6, e = idx & 63;
      cs[k][e] = ctx[(size_t)bh * NF * DHH + (size_t)(k0 + k) * DHH + e];
    }
    __syncthreads();
    #pragma unroll
    for (int k = 0; k < 16; k++) {
      float a[4], bb[4];
      #pragma unroll
      for (int i = 0; i < 4; i++) a[i] = qs[k][tn + i];
      #pragma unroll
      for (int j = 0; j < 4; j++) bb[j] = cs[k][te + j];
      #pragma unroll
      for (int i = 0; i < 4; i++)
        #pragma unroll
        for (int j = 0; j < 4; j++) acc[i][j] += a[i] * bb[j];
    }
    __syncthreads();
  }
  #pragma unroll
  for (int i = 0; i < 4; i++) {
    float dv = Dinv[bh * N_TOK + n0 + tn + i];
    #pragma unroll
    for (int j = 0; j < 4; j++)
      attn_out[(size_t)(b * N_TOK + n0 + tn + i) * DM + h * DHH + te + j] = acc[i][j] * dv;
  }
}

// ---------------- attn weight: C[b,i,j] = sum_c (qfeat[i,c]*Dinv[b,c/256,i]/8) * kfeat[j,c]
__global__ void attnw_kernel(const float* __restrict__ qfeat, const float* __restrict__ kfeat,
                             const float* __restrict__ Dinv, float* __restrict__ out) {
  int b = blockIdx.z;
  int i0 = blockIdx.y * 64, j0 = blockIdx.x * 64;
  __shared__ float As[16][68];
  __shared__ float Bs[16][68];
  int tid = threadIdx.x;
  int ti = (tid >> 4) * 4, tj = (tid & 15) * 4;
  float acc[4][4] = {};
  for (int c0 = 0; c0 < HF; c0 += 16) {
    int hsel = c0 >> 8;  // head for this chunk (constant within 16-wide chunk)
    #pragma unroll
    for (int l = 0; l < 4; l++) {
      int idx = tid + l * 256;
      int i = idx >> 4, k = idx & 15;
      float dv = Dinv[(b * NH + hsel) * N_TOK + i0 + i];
      As[k][i] = qfeat[(size_t)(b * N_TOK + i0 + i) * HF + c0 + k] * dv * 0.125f;
    }
    #pragma unroll
    for (int l = 0; l < 4; l++) {
      int idx = tid + l * 256;
      int j = idx >> 4, k = idx & 15;
      Bs[k][j] = kfeat[(size_t)(b * N_TOK + j0 + j) * HF + c0 + k];
    }
    __syncthreads();
    #pragma unroll
    for (int k = 0; k < 16; k++) {
      float a[4], bb[4];
      #pragma unroll
      for (int x = 0; x < 4; x++) a[x] = As[k][ti + x];
      #pragma unroll
      for (int y = 0; y < 4; y++) bb[y] = Bs[k][tj + y];
      #pragma unroll
      for (int x = 0; x < 4; x++)
        #pragma unroll
        for (int y = 0; y < 4; y++) acc[x][y] += a[x] * bb[y];
    }
    __syncthreads();
  }
  #pragma unroll
  for (int x = 0; x < 4; x++)
    #pragma unroll
    for (int y = 0; y < 4; y++)
      out[(size_t)b * N_TOK * N_TOK + (size_t)(i0 + ti + x) * N_TOK + j0 + tj + y] = acc[x][y];
}

// ---------------- LayerNorm over D=512, one block per row
__global__ void ln_kernel(const float* __restrict__ x, const float* __restrict__ g,
                          const float* __restrict__ beta, float* __restrict__ y) {
  int row = blockIdx.x, t = threadIdx.x;
  __shared__ float red[4];
  __shared__ float bcast[2];
  const float* xr = x + (size_t)row * DM;
  float v0 = xr[t], v1 = xr[t + 256];
  float s = v0 + v1;
  #pragma unroll
  for (int o = 32; o > 0; o >>= 1) s += __shfl_xor(s, o, 64);
  if ((t & 63) == 0) red[t >> 6] = s;
  __syncthreads();
  if (t == 0) bcast[0] = (red[0] + red[1] + red[2] + red[3]) * (1.0f / 512.0f);
  __syncthreads();
  float mean = bcast[0];
  float d0 = v0 - mean, d1 = v1 - mean;
  float s2 = d0 * d0 + d1 * d1;
  #pragma unroll
  for (int o = 32; o > 0; o >>= 1) s2 += __shfl_xor(s2, o, 64);
  if ((t & 63) == 0) red[t >> 6] = s2;
  __syncthreads();
  if (t == 0) bcast[1] = (red[0] + red[1] + red[2] + red[3]) * (1.0f / 512.0f);
  __syncthreads();
  float inv = rsqrtf(bcast[1] + LN_EPS);
  y[(size_t)row * DM + t] = g[t] * d0 * inv + beta[t];
  y[(size_t)row * DM + t + 256] = g[t + 256] * d1 * inv + beta[t + 256];
}

extern "C" void kernel_launch(void* const* d_in, const int* in_sizes, int n_in,
                              void* d_out, int out_size, void* d_ws, size_t ws_size,
                              hipStream_t stream) {
  const float* x     = (const float*)d_in[0];
  const float* Wq    = (const float*)d_in[1];
  const float* bq    = (const float*)d_in[2];
  const float* Wk    = (const float*)d_in[3];
  const float* bk    = (const float*)d_in[4];
  const float* Wv    = (const float*)d_in[5];
  const float* bv    = (const float*)d_in[6];
  const float* Wo    = (const float*)d_in[7];
  const float* bo    = (const float*)d_in[8];
  const float* proj  = (const float*)d_in[9];
  const float* W1    = (const float*)d_in[10];
  const float* b1    = (const float*)d_in[11];
  const float* W2    = (const float*)d_in[12];
  const float* b2    = (const float*)d_in[13];
  const float* g1    = (const float*)d_in[14];
  const float* beta1 = (const float*)d_in[15];
  const float* g2    = (const float*)d_in[16];
  const float* beta2 = (const float*)d_in[17];

  float* ws = (float*)d_ws;
  float* y_out   = (float*)d_out;                       // [2,2048,512]
  float* attnw   = y_out + (size_t)B_SZ * N_TOK * DM;   // [2,2048,2048]

  float* qfeat = ws + OFF_QFEAT;
  float* kfeat = ws + OFF_KFEAT;
  float* Qlin  = ws + OFF_QLIN;
  float* Klin  = ws + OFF_KLIN;
  float* Vlin  = ws + OFF_VLIN;
  float* ksum  = ws + OFF_KSUM;
  float* part  = ws + OFF_PART;
  float* Dinv  = ws + OFF_DINV;
  float* ctx   = ws + OFF_CTX;
  float* bmax  = ws + OFF_BMAX;
  float* gmax  = ws + OFF_GMAX;
  float* attn_out = Qlin;   // overlay: Qlin dead after featq
  float* out2     = Klin;   // overlay: Klin dead after featk1
  float* h1       = Vlin;   // overlay: Vlin dead after ctx
  float* ff1      = kfeat;  // overlay: kfeat dead after attnw
  float* ff2      = Qlin;   // overlay: attn_out dead after Wo gemm

  dim3 blk(256);
  int MT = B_SZ * N_TOK;  // 4096 rows

  // 1) QKV projections
  gemm_nn<false><<<dim3(DM / 64, MT / 64), blk, 0, stream>>>(x, Wq, bq, Qlin, MT, DM, DM);
  gemm_nn<false><<<dim3(DM / 64, MT / 64), blk, 0, stream>>>(x, Wk, bk, Klin, MT, DM, DM);
  gemm_nn<false><<<dim3(DM / 64, MT / 64), blk, 0, stream>>>(x, Wv, bv, Vlin, MT, DM, DM);

  // 2) feature maps
  featq_kernel<<<dim3(N_TOK, B_SZ * NH), blk, 0, stream>>>(Qlin, proj, qfeat);
  featk1_kernel<<<dim3(N_TOK, B_SZ * NH), blk, 0, stream>>>(Klin, proj, kfeat, bmax);
  gmax_kernel<<<1, blk, 0, stream>>>(bmax, gmax);
  featk2_kernel<<<(B_SZ * N_TOK * HF) / 256, blk, 0, stream>>>(kfeat, gmax);

  // 3) k_sum and D_inv
  ksum_part_kernel<<<dim3(8, B_SZ * NH), blk, 0, stream>>>(kfeat, part);
  ksum_final_kernel<<<B_SZ * NH, blk, 0, stream>>>(part, ksum);
  dinv_kernel<<<(B_SZ * NH * N_TOK) / 4, blk, 0, stream>>>(qfeat, ksum, Dinv);

  // 4) linear attention
  ctx_kernel<<<dim3(NF / 64, B_SZ * NH), blk, 0, stream>>>(kfeat, Vlin, ctx);
  pv_kernel<<<dim3(N_TOK / 64, B_SZ * NH), blk, 0, stream>>>(qfeat, ctx, Dinv, attn_out);
  gemm_nn<false><<<dim3(DM / 64, MT / 64), blk, 0, stream>>>(attn_out, Wo, bo, out2, MT, DM, DM);

  // 5) attention-weight output (positive => abs is identity; head-mean folded as 1/8)
  attnw_kernel<<<dim3(N_TOK / 64, N_TOK / 64, B_SZ), blk, 0, stream>>>(qfeat, kfeat, Dinv, attnw);

  // 6) FFN
  ln_kernel<<<MT, blk, 0, stream>>>(out2, g1, beta1, h1);
  gemm_nn<true><<<dim3(DFF / 64, MT / 64), blk, 0, stream>>>(h1, W1, b1, ff1, MT, DFF, DM);
  gemm_nn<false><<<dim3(DM / 64, MT / 64), blk, 0, stream>>>(ff1, W2, b2, ff2, MT, DM, DFF);
  ln_kernel<<<MT, blk, 0, stream>>>(ff2, g2, beta2, y_out);
}

// Round 2
// 894.304 us; speedup vs baseline: 1.6760x; 1.6760x over previous
//
#include <hip/hip_runtime.h>
#include <math.h>

// Problem constants
#define B_SZ   2
#define N_TOK  2048
#define DM     512
#define NH     8
#define DHH    64
#define NF     256
#define DFF    2048
#define HF     2048    // NH*NF

constexpr float DN_SCALE   = 0.35355339059327373f; // 64^-0.25
constexpr float DIAG_SCALE = 0.0625f;              // 0.5 * dn^2
constexpr float RATIO      = 0.0625f;              // 256^-0.5
constexpr float FEPS       = 1e-4f;
constexpr float LN_EPS     = 1e-5f;

typedef __attribute__((ext_vector_type(8))) short bf16x8;
typedef __attribute__((ext_vector_type(4))) float f32x4;

__device__ __forceinline__ short f2b(float f) {
  union { float f; unsigned u; } x; x.f = f;
  unsigned r = (x.u + 0x7fff + ((x.u >> 16) & 1)) >> 16;
  return (short)r;
}
__device__ __forceinline__ float b2f(short s) {
  union { unsigned u; float f; } x; x.u = ((unsigned)(unsigned short)s) << 16;
  return x.f;
}
__device__ __forceinline__ void gload16(const void* g, void* l) {
  __builtin_amdgcn_global_load_lds((const __attribute__((address_space(1))) void*)g,
                                   (__attribute__((address_space(3))) void*)l, 16, 0, 0);
}

// Workspace layout (float-offset units)
// S0 region [0 : 8388608): ktmp (phase2) -> qb bf16 (phase5) -> out2/ff1b/ff2
constexpr size_t OFF_S0    = 0;
constexpr size_t OFF_OUT2  = 0;              // fp32 [4096,512]
constexpr size_t OFF_FF1B  = 2097152;        // bf16 [4096,2048] (8.4M shorts)
constexpr size_t OFF_FF2   = 6291456;        // fp32 [4096,512]
constexpr size_t OFF_QFB   = 8388608;        // bf16 [2,2048,2048]
constexpr size_t OFF_KB    = 12582912;       // bf16 [2,2048,2048]
constexpr size_t OFF_QLIN  = 16777216;       // fp32 [4096,512]
constexpr size_t OFF_KLIN  = 18874368;       // fp32 [4096,512]
constexpr size_t OFF_VLIN  = 20971520;       // fp32 [4096,512] -> attn_out_b, h1b
constexpr size_t OFF_AOB   = 20971520;       // bf16 [4096,512]
constexpr size_t OFF_H1B   = 22020096;       // bf16 [4096,512]
constexpr size_t OFF_WOT   = 23068672;       // bf16 [512,512]
constexpr size_t OFF_W1T   = 23199744;       // bf16 [2048,512]
constexpr size_t OFF_W2T   = 23724032;       // bf16 [512,2048]
constexpr size_t OFF_KSUM  = 24248320;
constexpr size_t OFF_PART  = 24252416;
constexpr size_t OFF_DINV  = 24285184;
constexpr size_t OFF_CTX   = 24317952;
constexpr size_t OFF_BMAX  = 24580096;
constexpr size_t OFF_GMAX  = 24612864;

// ============ bf16 MFMA GEMM: C = A[M,K] @ Bt[N,K]^T (+bias, relu), m97 structure
template<bool RELU, bool OUT_BF16, bool HAS_BIAS>
__global__ __launch_bounds__(256)
void gemm_mfma(const short* __restrict__ A, const short* __restrict__ Bt,
               const float* __restrict__ bias, void* __restrict__ Cout,
               int M, int N, int K, size_t sA, size_t sB, size_t sC) {
  __shared__ short As[128 * 64];
  __shared__ short Bs[128 * 64];
  int tid = threadIdx.x;
  int lane = tid & 63, wave = tid >> 6;
  int wm = wave >> 1, wn = wave & 1;
  int bm = blockIdx.y * 128, bn = blockIdx.x * 128;
  const short* Ab = A + (size_t)blockIdx.z * sA;
  const short* Bb = Bt + (size_t)blockIdx.z * sB;

  f32x4 acc[4][4] = {};
  int srow = tid >> 3;            // 0..31
  int scol = (tid & 7) * 8;       // element col (16B chunks)

  for (int k0 = 0; k0 < K; k0 += 64) {
    #pragma unroll
    for (int c = 0; c < 4; ++c) {
      int r = c * 32 + srow;
      gload16(Ab + (size_t)(bm + r) * K + k0 + scol, As + c * 2048 + wave * 512);
      gload16(Bb + (size_t)(bn + r) * K + k0 + scol, Bs + c * 2048 + wave * 512);
    }
    __syncthreads();
    #pragma unroll
    for (int kk = 0; kk < 2; ++kk) {
      bf16x8 af[4], bf[4];
      int kq = kk * 32 + (lane >> 4) * 8;
      #pragma unroll
      for (int i = 0; i < 4; ++i)
        af[i] = *(const bf16x8*)&As[(wm * 64 + i * 16 + (lane & 15)) * 64 + kq];
      #pragma unroll
      for (int j = 0; j < 4; ++j)
        bf[j] = *(const bf16x8*)&Bs[(wn * 64 + j * 16 + (lane & 15)) * 64 + kq];
      #pragma unroll
      for (int i = 0; i < 4; ++i)
        #pragma unroll
        for (int j = 0; j < 4; ++j)
          acc[i][j] = __builtin_amdgcn_mfma_f32_16x16x32_bf16(af[i], bf[j], acc[i][j], 0, 0, 0);
    }
    __syncthreads();
  }

  int row0 = bm + wm * 64, col0 = bn + wn * 64;
  #pragma unroll
  for (int i = 0; i < 4; ++i) {
    #pragma unroll
    for (int j = 0; j < 4; ++j) {
      int col = col0 + j * 16 + (lane & 15);
      float bv = HAS_BIAS ? bias[col] : 0.f;
      #pragma unroll
      for (int r = 0; r < 4; ++r) {
        int row = row0 + i * 16 + (lane >> 4) * 4 + r;
        float v = acc[i][j][r] + bv;
        if (RELU) v = fmaxf(v, 0.f);
        size_t off = (size_t)blockIdx.z * sC + (size_t)row * N + col;
        if (OUT_BF16) ((short*)Cout)[off] = f2b(v);
        else          ((float*)Cout)[off] = v;
      }
    }
  }
}

// ============ fp32 vector GEMM (QKV projections only)
__global__ void gemm_nn(const float* __restrict__ A, const float* __restrict__ B,
                        const float* __restrict__ bias, float* __restrict__ C,
                        int M, int N, int K) {
  __shared__ float As[16][68];
  __shared__ float Bs[16][68];
  int bm = blockIdx.y * 64, bn = blockIdx.x * 64;
  int tid = threadIdx.x;
  int tm = (tid >> 4) * 4, tn = (tid & 15) * 4;
  float acc[4][4] = {};
  for (int k0 = 0; k0 < K; k0 += 16) {
    #pragma unroll
    for (int i = 0; i < 4; i++) {
      int idx = tid + i * 256;
      int m = idx >> 4, k = idx & 15;
      As[k][m] = A[(size_t)(bm + m) * K + k0 + k];
    }
    #pragma unroll
    for (int i = 0; i < 4; i++) {
      int idx = tid + i * 256;
      int k = idx >> 6, n = idx & 63;
      Bs[k][n] = B[(size_t)(k0 + k) * N + bn + n];
    }
    __syncthreads();
    #pragma unroll
    for (int k = 0; k < 16; k++) {
      float a[4], b[4];
      #pragma unroll
      for (int i = 0; i < 4; i++) a[i] = As[k][tm + i];
      #pragma unroll
      for (int j = 0; j < 4; j++) b[j] = Bs[k][tn + j];
      #pragma unroll
      for (int i = 0; i < 4; i++)
        #pragma unroll
        for (int j = 0; j < 4; j++) acc[i][j] += a[i] * b[j];
    }
    __syncthreads();
  }
  #pragma unroll
  for (int i = 0; i < 4; i++)
    #pragma unroll
    for (int j = 0; j < 4; j++)
      C[(size_t)(bm + tm + i) * N + bn + tn + j] = acc[i][j] + bias[bn + tn + j];
}

// ============ weight transpose+convert: W[K][N] fp32 -> Wt[N][K] bf16
__global__ void transpose_w(const float* __restrict__ W, short* __restrict__ Wt, int K, int N) {
  __shared__ float t[64][65];
  int k0 = blockIdx.y * 64, n0 = blockIdx.x * 64;
  int lx = threadIdx.x & 63, ly = threadIdx.x >> 6;
  for (int r = ly; r < 64; r += 4)
    t[r][lx] = W[(size_t)(k0 + r) * N + n0 + lx];
  __syncthreads();
  for (int r = ly; r < 64; r += 4)
    Wt[(size_t)(n0 + r) * K + k0 + lx] = f2b(t[lx][r]);
}

// ============ Q feature map (per-row max), writes bf16
__global__ void featq_kernel(const float* __restrict__ Qlin, const float* __restrict__ proj,
                             short* __restrict__ qfb) {
  int n = blockIdx.x, bh = blockIdx.y, b = bh >> 3, h = bh & 7;
  int t = threadIdx.x;
  __shared__ float data[DHH];
  __shared__ float red[4];
  const float* row = Qlin + (size_t)(b * N_TOK + n) * DM + h * DHH;
  if (t < DHH) data[t] = row[t];
  __syncthreads();
  float dot = 0.f, s2 = 0.f;
  const float* pr = proj + t * DHH;
  #pragma unroll 8
  for (int d = 0; d < DHH; ++d) { float a = data[d]; dot += a * pr[d]; s2 += a * a; }
  float dd = DN_SCALE * dot;
  float diag = DIAG_SCALE * s2;
  float m = dd;
  #pragma unroll
  for (int o = 32; o > 0; o >>= 1) m = fmaxf(m, __shfl_xor(m, o, 64));
  if ((t & 63) == 0) red[t >> 6] = m;
  __syncthreads();
  if (t == 0) red[0] = fmaxf(fmaxf(red[0], red[1]), fmaxf(red[2], red[3]));
  __syncthreads();
  m = red[0];
  float v = RATIO * (expf(dd - diag - m) + FEPS);
  qfb[(size_t)(b * N_TOK + n) * HF + h * NF + t] = f2b(v);
}

// ============ K feature pass 1: ktmp = dd - diag (fp32), per-block max of dd
__global__ void featk1_kernel(const float* __restrict__ Klin, const float* __restrict__ proj,
                              float* __restrict__ ktmp, float* __restrict__ bmax) {
  int n = blockIdx.x, bh = blockIdx.y, b = bh >> 3, h = bh & 7;
  int t = threadIdx.x;
  __shared__ float data[DHH];
  __shared__ float red[4];
  const float* row = Klin + (size_t)(b * N_TOK + n) * DM + h * DHH;
  if (t < DHH) data[t] = row[t];
  __syncthreads();
  float dot = 0.f, s2 = 0.f;
  const float* pr = proj + t * DHH;
  #pragma unroll 8
  for (int d = 0; d < DHH; ++d) { float a = data[d]; dot += a * pr[d]; s2 += a * a; }
  float dd = DN_SCALE * dot;
  float diag = DIAG_SCALE * s2;
  ktmp[(size_t)(b * N_TOK + n) * HF + h * NF + t] = dd - diag;
  float m = dd;
  #pragma unroll
  for (int o = 32; o > 0; o >>= 1) m = fmaxf(m, __shfl_xor(m, o, 64));
  if ((t & 63) == 0) red[t >> 6] = m;
  __syncthreads();
  if (t == 0) bmax[bh * N_TOK + n] = fmaxf(fmaxf(red[0], red[1]), fmaxf(red[2], red[3]));
}

__global__ void gmax_kernel(const float* __restrict__ bmax, float* __restrict__ gmax) {
  __shared__ float red[4];
  float m = -3.4e38f;
  for (int i = threadIdx.x; i < B_SZ * NH * N_TOK; i += 256) m = fmaxf(m, bmax[i]);
  #pragma unroll
  for (int o = 32; o > 0; o >>= 1) m = fmaxf(m, __shfl_xor(m, o, 64));
  if ((threadIdx.x & 63) == 0) red[threadIdx.x >> 6] = m;
  __syncthreads();
  if (threadIdx.x == 0) gmax[0] = fmaxf(fmaxf(red[0], red[1]), fmaxf(red[2], red[3]));
}

// ============ K feature pass 2: exponentiate, write bf16
__global__ void featk2_kernel(const float* __restrict__ ktmp, const float* __restrict__ gmax,
                              short* __restrict__ kb) {
  size_t base = ((size_t)blockIdx.x * 256 + threadIdx.x) * 8;
  float M = gmax[0];
  #pragma unroll
  for (int u = 0; u < 8; ++u)
    kb[base + u] = f2b(RATIO * (expf(ktmp[base + u] - M) + FEPS));
}

// ============ q scaled by Dinv/8 -> qb bf16 (A-operand of attn-weight GEMM)
__global__ void qscale_kernel(const short* __restrict__ qfb, const float* __restrict__ Dinv,
                              short* __restrict__ qb) {
  size_t base = ((size_t)blockIdx.x * 256 + threadIdx.x) * 8;
  int c = (int)(base & (HF - 1));
  int i = (int)((base >> 11) & (N_TOK - 1));
  int b = (int)(base >> 22);
  float dv = Dinv[(b * NH + (c >> 8)) * N_TOK + i] * 0.125f;
  #pragma unroll
  for (int u = 0; u < 8; ++u)
    qb[base + u] = f2b(b2f(qfb[base + u]) * dv);
}

// ============ ksum partials from kb
__global__ void ksum_part_kernel(const short* __restrict__ kb, float* __restrict__ part) {
  int f = threadIdx.x, chunk = blockIdx.x, bh = blockIdx.y;
  int b = bh >> 3, h = bh & 7;
  int n0 = chunk * 256;
  float s = 0.f;
  for (int n = n0; n < n0 + 256; ++n)
    s += b2f(kb[(size_t)(b * N_TOK + n) * HF + h * NF + f]);
  part[(size_t)(bh * 8 + chunk) * NF + f] = s;
}

__global__ void ksum_final_kernel(const float* __restrict__ part, float* __restrict__ ksum) {
  int f = threadIdx.x, bh = blockIdx.x;
  float s = 0.f;
  #pragma unroll
  for (int c = 0; c < 8; ++c) s += part[(size_t)(bh * 8 + c) * NF + f];
  ksum[bh * NF + f] = s;
}

// ============ D_inv
__global__ void dinv_kernel(const short* __restrict__ qfb, const float* __restrict__ ksum,
                            float* __restrict__ Dinv) {
  __shared__ float ks[NF];
  int r0 = blockIdx.x * 4;
  int bh = r0 >> 11, b = bh >> 3, h = bh & 7;
  int n0 = r0 & 2047;
  int lane = threadIdx.x & 63, w = threadIdx.x >> 6;
  ks[threadIdx.x] = ksum[bh * NF + threadIdx.x];
  __syncthreads();
  int n = n0 + w;
  const short* qr = qfb + (size_t)(b * N_TOK + n) * HF + h * NF;
  float s = 0.f;
  #pragma unroll
  for (int f0 = 0; f0 < NF; f0 += 64) s += b2f(qr[f0 + lane]) * ks[f0 + lane];
  #pragma unroll
  for (int o = 32; o > 0; o >>= 1) s += __shfl_xor(s, o, 64);
  if (lane == 0) Dinv[bh * N_TOK + n] = 1.0f / s;
}

// ============ context: ctx[bh][f][e] = sum_n kb[n,f] * v[n,e]
__global__ void ctx_kernel(const short* __restrict__ kb, const float* __restrict__ Vlin,
                           float* __restrict__ ctx) {
  int bh = blockIdx.y, b = bh >> 3, h = bh & 7;
  int f0 = blockIdx.x * 64;
  __shared__ float kf[32][68];
  __shared__ float vs[32][68];
  int tid = threadIdx.x;
  int tf = (tid >> 4) * 4, te = (tid & 15) * 4;
  float acc[4][4] = {};
  for (int n0 = 0; n0 < N_TOK; n0 += 32) {
    #pragma unroll
    for (int i = 0; i < 8; i++) {
      int idx = tid + i * 256;
      int nn = idx >> 6, f = idx & 63;
      kf[nn][f] = b2f(kb[(size_t)(b * N_TOK + n0 + nn) * HF + h * NF + f0 + f]);
    }
    #pragma unroll
    for (int i = 0; i < 8; i++) {
      int idx = tid + i * 256;
      int nn = idx >> 6, e = idx & 63;
      vs[nn][e] = Vlin[(size_t)(b * N_TOK + n0 + nn) * DM + h * DHH + e];
    }
    __syncthreads();
    #pragma unroll
    for (int nn = 0; nn < 32; nn++) {
      float a[4], bb[4];
      #pragma unroll
      for (int i = 0; i < 4; i++) a[i] = kf[nn][tf + i];
      #pragma unroll
      for (int j = 0; j < 4; j++) bb[j] = vs[nn][te + j];
      #pragma unroll
      for (int i = 0; i < 4; i++)
        #pragma unroll
        for (int j = 0; j < 4; j++) acc[i][j] += a[i] * bb[j];
    }
    __syncthreads();
  }
  #pragma unroll
  for (int i = 0; i < 4; i++)
    #pragma unroll
    for (int j = 0; j < 4; j++)
      ctx[(size_t)bh * NF * DHH + (size_t)(f0 + tf + i) * DHH + te + j] = acc[i][j];
}

// ============ PV: attn_out_b[b,n,h*64+e] = bf16(Dinv * (qfb row @ ctx))
__global__ void pv_kernel(const short* __restrict__ qfb, const float* __restrict__ ctx,
                          const float* __restrict__ Dinv, short* __restrict__ aob) {
  int bh = blockIdx.y, b = bh >> 3, h = bh & 7;
  int n0 = blockIdx.x * 64;
  __shared__ float qs[16][68];
  __shared__ float cs[16][68];
  int tid = threadIdx.x;
  int tn = (tid >> 4) * 4, te = (tid & 15) * 4;
  float acc[4][4] = {};
  for (int k0 = 0; k0 < NF; k0 += 16) {
    #pragma unroll
    for (int i = 0; i < 4; i++) {
      int idx = tid + i * 256;
      int n = idx >> 4, k = idx & 15;
      qs[k][n] = b2f(qfb[(size_t)(b * N_TOK + n0 + n) * HF + h * NF + k0 + k]);
    }
    #pragma unroll
    for (int i = 0; i < 4; i++) {
      int idx = tid + i * 256;
      int k = idx >> 6, e = idx & 63;
      cs[k][e] = ctx[(size_t)bh * NF * DHH + (size_t)(k0 + k) * DHH + e];
    }
    __syncthreads();
    #pragma unroll
    for (int k = 0; k < 16; k++) {
      float a[4], bb[4];
      #pragma unroll
      for (int i = 0; i < 4; i++) a[i] = qs[k][tn + i];
      #pragma unroll
      for (int j = 0; j < 4; j++) bb[j] = cs[k][te + j];
      #pragma unroll
      for (int i = 0; i < 4; i++)
        #pragma unroll
        for (int j = 0; j < 4; j++) acc[i][j] += a[i] * bb[j];
    }
    __syncthreads();
  }
  #pragma unroll
  for (int i = 0; i < 4; i++) {
    float dv = Dinv[bh * N_TOK + n0 + tn + i];
    #pragma unroll
    for (int j = 0; j < 4; j++)
      aob[(size_t)(b * N_TOK + n0 + tn + i) * DM + h * DHH + te + j] = f2b(acc[i][j] * dv);
  }
}

// ============ LayerNorm over D=512
template<bool OUT_BF16>
__global__ void ln_kernel(const float* __restrict__ x, const float* __restrict__ g,
                          const float* __restrict__ beta, void* __restrict__ y) {
  int row = blockIdx.x, t = threadIdx.x;
  __shared__ float red[4];
  __shared__ float bcast[2];
  const float* xr = x + (size_t)row * DM;
  float v0 = xr[t], v1 = xr[t + 256];
  float s = v0 + v1;
  #pragma unroll
  for (int o = 32; o > 0; o >>= 1) s += __shfl_xor(s, o, 64);
  if ((t & 63) == 0) red[t >> 6] = s;
  __syncthreads();
  if (t == 0) bcast[0] = (red[0] + red[1] + red[2] + red[3]) * (1.0f / 512.0f);
  __syncthreads();
  float mean = bcast[0];
  float d0 = v0 - mean, d1 = v1 - mean;
  float s2 = d0 * d0 + d1 * d1;
  #pragma unroll
  for (int o = 32; o > 0; o >>= 1) s2 += __shfl_xor(s2, o, 64);
  if ((t & 63) == 0) red[t >> 6] = s2;
  __syncthreads();
  if (t == 0) bcast[1] = (red[0] + red[1] + red[2] + red[3]) * (1.0f / 512.0f);
  __syncthreads();
  float inv = rsqrtf(bcast[1] + LN_EPS);
  float o0 = g[t] * d0 * inv + beta[t];
  float o1 = g[t + 256] * d1 * inv + beta[t + 256];
  if (OUT_BF16) {
    ((short*)y)[(size_t)row * DM + t] = f2b(o0);
    ((short*)y)[(size_t)row * DM + t + 256] = f2b(o1);
  } else {
    ((float*)y)[(size_t)row * DM + t] = o0;
    ((float*)y)[(size_t)row * DM + t + 256] = o1;
  }
}

extern "C" void kernel_launch(void* const* d_in, const int* in_sizes, int n_in,
                              void* d_out, int out_size, void* d_ws, size_t ws_size,
                              hipStream_t stream) {
  const float* x     = (const float*)d_in[0];
  const float* Wq    = (const float*)d_in[1];
  const float* bq    = (const float*)d_in[2];
  const float* Wk    = (const float*)d_in[3];
  const float* bk    = (const float*)d_in[4];
  const float* Wv    = (const float*)d_in[5];
  const float* bv    = (const float*)d_in[6];
  const float* Wo    = (const float*)d_in[7];
  const float* bo    = (const float*)d_in[8];
  const float* proj  = (const float*)d_in[9];
  const float* W1    = (const float*)d_in[10];
  const float* b1    = (const float*)d_in[11];
  const float* W2    = (const float*)d_in[12];
  const float* b2    = (const float*)d_in[13];
  const float* g1    = (const float*)d_in[14];
  const float* beta1 = (const float*)d_in[15];
  const float* g2    = (const float*)d_in[16];
  const float* beta2 = (const float*)d_in[17];

  float* ws = (float*)d_ws;
  float* y_out = (float*)d_out;                       // [2,2048,512]
  float* attnw = y_out + (size_t)B_SZ * N_TOK * DM;   // [2,2048,2048]

  float* ktmp  = ws + OFF_S0;
  short* qb    = (short*)(ws + OFF_S0);
  float* out2  = ws + OFF_OUT2;
  short* ff1b  = (short*)(ws + OFF_FF1B);
  float* ff2   = ws + OFF_FF2;
  short* qfb   = (short*)(ws + OFF_QFB);
  short* kb    = (short*)(ws + OFF_KB);
  float* Qlin  = ws + OFF_QLIN;
  float* Klin  = ws + OFF_KLIN;
  float* Vlin  = ws + OFF_VLIN;
  short* aob   = (short*)(ws + OFF_AOB);
  short* h1b   = (short*)(ws + OFF_H1B);
  short* Wot   = (short*)(ws + OFF_WOT);
  short* W1t   = (short*)(ws + OFF_W1T);
  short* W2t   = (short*)(ws + OFF_W2T);
  float* ksum  = ws + OFF_KSUM;
  float* part  = ws + OFF_PART;
  float* Dinv  = ws + OFF_DINV;
  float* ctx   = ws + OFF_CTX;
  float* bmax  = ws + OFF_BMAX;
  float* gmax  = ws + OFF_GMAX;

  dim3 blk(256);
  int MT = B_SZ * N_TOK;  // 4096

  // weight transposes (independent)
  transpose_w<<<dim3(8, 8), blk, 0, stream>>>(Wo, Wot, DM, DM);
  transpose_w<<<dim3(32, 8), blk, 0, stream>>>(W1, W1t, DM, DFF);
  transpose_w<<<dim3(8, 32), blk, 0, stream>>>(W2, W2t, DFF, DM);

  // 1) QKV projections (fp32)
  gemm_nn<<<dim3(DM / 64, MT / 64), blk, 0, stream>>>(x, Wq, bq, Qlin, MT, DM, DM);
  gemm_nn<<<dim3(DM / 64, MT / 64), blk, 0, stream>>>(x, Wk, bk, Klin, MT, DM, DM);
  gemm_nn<<<dim3(DM / 64, MT / 64), blk, 0, stream>>>(x, Wv, bv, Vlin, MT, DM, DM);

  // 2) feature maps
  featq_kernel<<<dim3(N_TOK, B_SZ * NH), blk, 0, stream>>>(Qlin, proj, qfb);
  featk1_kernel<<<dim3(N_TOK, B_SZ * NH), blk, 0, stream>>>(Klin, proj, ktmp, bmax);
  gmax_kernel<<<1, blk, 0, stream>>>(bmax, gmax);
  featk2_kernel<<<(B_SZ * N_TOK * HF) / (256 * 8), blk, 0, stream>>>(ktmp, gmax, kb);

  // 3) k_sum and D_inv
  ksum_part_kernel<<<dim3(8, B_SZ * NH), blk, 0, stream>>>(kb, part);
  ksum_final_kernel<<<B_SZ * NH, blk, 0, stream>>>(part, ksum);
  dinv_kernel<<<(B_SZ * NH * N_TOK) / 4, blk, 0, stream>>>(qfb, ksum, Dinv);

  // 4) linear attention (fp32 vector; small)
  ctx_kernel<<<dim3(NF / 64, B_SZ * NH), blk, 0, stream>>>(kb, Vlin, ctx);
  pv_kernel<<<dim3(N_TOK / 64, B_SZ * NH), blk, 0, stream>>>(qfb, ctx, Dinv, aob);

  // 5) attn-weight output: qb = qfb*Dinv/8 (overwrites ktmp region), then bf16 MFMA GEMM
  qscale_kernel<<<(B_SZ * N_TOK * HF) / (256 * 8), blk, 0, stream>>>(qfb, Dinv, qb);
  gemm_mfma<false, false, false><<<dim3(16, 16, 2), blk, 0, stream>>>(
      qb, kb, nullptr, attnw, N_TOK, N_TOK, HF,
      (size_t)N_TOK * HF, (size_t)N_TOK * HF, (size_t)N_TOK * N_TOK);

  // 6) Wo projection (bf16 MFMA)
  gemm_mfma<false, false, true><<<dim3(4, 32, 1), blk, 0, stream>>>(
      aob, Wot, bo, out2, MT, DM, DM, 0, 0, 0);

  // 7) FFN
  ln_kernel<true><<<MT, blk, 0, stream>>>(out2, g1, beta1, h1b);
  gemm_mfma<true, true, true><<<dim3(16, 32, 1), blk, 0, stream>>>(
      h1b, W1t, b1, ff1b, MT, DFF, DM, 0, 0, 0);
  gemm_mfma<false, false, true><<<dim3(4, 32, 1), blk, 0, stream>>>(
      ff1b, W2t, b2, ff2, MT, DM, DFF, 0, 0, 0);
  ln_kernel<false><<<MT, blk, 0, stream>>>(ff2, g2, beta2, y_out);
}

// Round 3
// 476.884 us; speedup vs baseline: 3.1430x; 1.8753x over previous
//
#include <hip/hip_runtime.h>
#include <math.h>

// Problem constants
#define B_SZ   2
#define N_TOK  2048
#define DM     512
#define NH     8
#define DHH    64
#define NF     256
#define DFF    2048
#define HF     2048    // NH*NF

constexpr float DN_SCALE   = 0.35355339059327373f; // 64^-0.25
constexpr float DIAG_SCALE = 0.0625f;              // 0.5 * dn^2
constexpr float RATIO      = 0.0625f;              // 256^-0.5
constexpr float FEPS       = 1e-4f;
constexpr float LN_EPS     = 1e-5f;

typedef __attribute__((ext_vector_type(8))) short bf16x8;
typedef __attribute__((ext_vector_type(4))) float f32x4;

__device__ __forceinline__ short f2b(float f) {
  union { float f; unsigned u; } x; x.f = f;
  unsigned r = (x.u + 0x7fff + ((x.u >> 16) & 1)) >> 16;
  return (short)r;
}
__device__ __forceinline__ float b2f(short s) {
  union { unsigned u; float f; } x; x.u = ((unsigned)(unsigned short)s) << 16;
  return x.f;
}
__device__ __forceinline__ void gload16(const void* g, void* l) {
  __builtin_amdgcn_global_load_lds((const __attribute__((address_space(1))) void*)g,
                                   (__attribute__((address_space(3))) void*)l, 16, 0, 0);
}

// Workspace layout (float-offset units)
constexpr size_t OFF_S0    = 0;              // ktmp -> qb -> out2/ff1b/ff2
constexpr size_t OFF_OUT2  = 0;              // fp32 [4096,512]
constexpr size_t OFF_FF1B  = 2097152;        // bf16 [4096,2048]
constexpr size_t OFF_FF2   = 6291456;        // fp32 [4096,512]
constexpr size_t OFF_QFB   = 8388608;        // bf16 [2,2048,2048]
constexpr size_t OFF_KB    = 12582912;       // bf16 [2,2048,2048]
constexpr size_t OFF_QLIN  = 16777216;       // fp32 [4096,512]
constexpr size_t OFF_KLIN  = 18874368;       // fp32 [4096,512]
constexpr size_t OFF_VLIN  = 20971520;       // fp32 [4096,512] -> aob, h1b
constexpr size_t OFF_AOB   = 20971520;       // bf16 [4096,512]
constexpr size_t OFF_H1B   = 22020096;       // bf16 [4096,512]
constexpr size_t OFF_WOT   = 23068672;       // bf16 [512,512]
constexpr size_t OFF_W1T   = 23199744;       // bf16 [2048,512]
constexpr size_t OFF_W2T   = 23724032;       // bf16 [512,2048]
constexpr size_t OFF_KSUM  = 24248320;
constexpr size_t OFF_PART  = 24252416;
constexpr size_t OFF_DINV  = 24285184;
constexpr size_t OFF_CTX   = 24317952;
constexpr size_t OFF_BMAX  = 24580096;       // [512]
constexpr size_t OFF_GMAX  = 24612864;

// ============ bf16 MFMA GEMM: C = A[M,K] @ Bt[N,K]^T (+bias, relu), m97 structure
template<bool RELU, bool OUT_BF16, bool HAS_BIAS>
__global__ __launch_bounds__(256)
void gemm_mfma(const short* __restrict__ A, const short* __restrict__ Bt,
               const float* __restrict__ bias, void* __restrict__ Cout,
               int M, int N, int K, size_t sA, size_t sB, size_t sC) {
  __shared__ short As[128 * 64];
  __shared__ short Bs[128 * 64];
  int tid = threadIdx.x;
  int lane = tid & 63, wave = tid >> 6;
  int wm = wave >> 1, wn = wave & 1;
  int bm = blockIdx.y * 128, bn = blockIdx.x * 128;
  const short* Ab = A + (size_t)blockIdx.z * sA;
  const short* Bb = Bt + (size_t)blockIdx.z * sB;

  f32x4 acc[4][4] = {};
  int srow = tid >> 3;
  int scol = (tid & 7) * 8;

  for (int k0 = 0; k0 < K; k0 += 64) {
    #pragma unroll
    for (int c = 0; c < 4; ++c) {
      int r = c * 32 + srow;
      gload16(Ab + (size_t)(bm + r) * K + k0 + scol, As + c * 2048 + wave * 512);
      gload16(Bb + (size_t)(bn + r) * K + k0 + scol, Bs + c * 2048 + wave * 512);
    }
    __syncthreads();
    #pragma unroll
    for (int kk = 0; kk < 2; ++kk) {
      bf16x8 af[4], bf[4];
      int kq = kk * 32 + (lane >> 4) * 8;
      #pragma unroll
      for (int i = 0; i < 4; ++i)
        af[i] = *(const bf16x8*)&As[(wm * 64 + i * 16 + (lane & 15)) * 64 + kq];
      #pragma unroll
      for (int j = 0; j < 4; ++j)
        bf[j] = *(const bf16x8*)&Bs[(wn * 64 + j * 16 + (lane & 15)) * 64 + kq];
      #pragma unroll
      for (int i = 0; i < 4; ++i)
        #pragma unroll
        for (int j = 0; j < 4; ++j)
          acc[i][j] = __builtin_amdgcn_mfma_f32_16x16x32_bf16(af[i], bf[j], acc[i][j], 0, 0, 0);
    }
    __syncthreads();
  }

  int row0 = bm + wm * 64, col0 = bn + wn * 64;
  #pragma unroll
  for (int i = 0; i < 4; ++i) {
    #pragma unroll
    for (int j = 0; j < 4; ++j) {
      int col = col0 + j * 16 + (lane & 15);
      float bv = HAS_BIAS ? bias[col] : 0.f;
      #pragma unroll
      for (int r = 0; r < 4; ++r) {
        int row = row0 + i * 16 + (lane >> 4) * 4 + r;
        float v = acc[i][j][r] + bv;
        if (RELU) v = fmaxf(v, 0.f);
        size_t off = (size_t)blockIdx.z * sC + (size_t)row * N + col;
        if (OUT_BF16) ((short*)Cout)[off] = f2b(v);
        else          ((float*)Cout)[off] = v;
      }
    }
  }
}

// ============ fp32 vector GEMM (QKV projections only)
__global__ void gemm_nn(const float* __restrict__ A, const float* __restrict__ B,
                        const float* __restrict__ bias, float* __restrict__ C,
                        int M, int N, int K) {
  __shared__ float As[16][68];
  __shared__ float Bs[16][68];
  int bm = blockIdx.y * 64, bn = blockIdx.x * 64;
  int tid = threadIdx.x;
  int tm = (tid >> 4) * 4, tn = (tid & 15) * 4;
  float acc[4][4] = {};
  for (int k0 = 0; k0 < K; k0 += 16) {
    #pragma unroll
    for (int i = 0; i < 4; i++) {
      int idx = tid + i * 256;
      int m = idx >> 4, k = idx & 15;
      As[k][m] = A[(size_t)(bm + m) * K + k0 + k];
    }
    #pragma unroll
    for (int i = 0; i < 4; i++) {
      int idx = tid + i * 256;
      int k = idx >> 6, n = idx & 63;
      Bs[k][n] = B[(size_t)(k0 + k) * N + bn + n];
    }
    __syncthreads();
    #pragma unroll
    for (int k = 0; k < 16; k++) {
      float a[4], b[4];
      #pragma unroll
      for (int i = 0; i < 4; i++) a[i] = As[k][tm + i];
      #pragma unroll
      for (int j = 0; j < 4; j++) b[j] = Bs[k][tn + j];
      #pragma unroll
      for (int i = 0; i < 4; i++)
        #pragma unroll
        for (int j = 0; j < 4; j++) acc[i][j] += a[i] * b[j];
    }
    __syncthreads();
  }
  #pragma unroll
  for (int i = 0; i < 4; i++)
    #pragma unroll
    for (int j = 0; j < 4; j++)
      C[(size_t)(bm + tm + i) * N + bn + tn + j] = acc[i][j] + bias[bn + tn + j];
}

// ============ weight transpose+convert: W[K][N] fp32 -> Wt[N][K] bf16
__global__ void transpose_w(const float* __restrict__ W, short* __restrict__ Wt, int K, int N) {
  __shared__ float t[64][65];
  int k0 = blockIdx.y * 64, n0 = blockIdx.x * 64;
  int lx = threadIdx.x & 63, ly = threadIdx.x >> 6;
  for (int r = ly; r < 64; r += 4)
    t[r][lx] = W[(size_t)(k0 + r) * N + n0 + lx];
  __syncthreads();
  for (int r = ly; r < 64; r += 4)
    Wt[(size_t)(n0 + r) * K + k0 + lx] = f2b(t[lx][r]);
}

// ============ feature map as tiled GEMM: 64 rows x 256 features per block
// dd = DN_SCALE * (rows @ proj^T); Q: exp(dd - diag - rowmax) -> bf16
// K: store dd - diag fp32 + per-block max of dd
template<bool IS_QUERY>
__global__ __launch_bounds__(256)
void feat_kernel(const float* __restrict__ lin, const float* __restrict__ proj,
                 short* __restrict__ qfb, float* __restrict__ ktmp,
                 float* __restrict__ bmax) {
  __shared__ float Ds[64][65];   // [dim][row]
  __shared__ float Ps[64][65];   // [dim][feat]
  __shared__ float diag[64];
  __shared__ float wred[4];
  int bh = blockIdx.y, b = bh >> 3, h = bh & 7;
  int n0 = blockIdx.x * 64;
  int tid = threadIdx.x;
  int tr = tid >> 4, tc = tid & 15;

  // stage 64 token rows (head h): coalesced global, Ds[d][r]
  #pragma unroll
  for (int i = 0; i < 16; ++i) {
    int idx = tid + i * 256;
    int r = idx >> 6, d = idx & 63;
    Ds[d][r] = lin[(size_t)(b * N_TOK + n0 + r) * DM + h * DHH + d];
  }
  __syncthreads();
  // per-row sum of squares (column read, conflict-free: bank=(t+65d)%32 distinct)
  if (tid < 64) {
    float s = 0.f;
    #pragma unroll 8
    for (int d = 0; d < 64; ++d) { float a = Ds[d][tid]; s += a * a; }
    diag[tid] = s * DIAG_SCALE;
  }

  float ddv[4][4][4];  // [ftile][row][feat] — all static indexing
  #pragma unroll
  for (int jt = 0; jt < 4; ++jt) {
    __syncthreads();
    #pragma unroll
    for (int i = 0; i < 16; ++i) {
      int idx = tid + i * 256;
      int j = idx >> 6, d = idx & 63;
      Ps[d][j] = proj[(size_t)(jt * 64 + j) * DHH + d];
    }
    __syncthreads();
    float acc[4][4] = {};
    for (int k = 0; k < 64; ++k) {
      float a[4], bb[4];
      #pragma unroll
      for (int i = 0; i < 4; ++i) a[i] = Ds[k][tr * 4 + i];
      #pragma unroll
      for (int j = 0; j < 4; ++j) bb[j] = Ps[k][tc * 4 + j];
      #pragma unroll
      for (int i = 0; i < 4; ++i)
        #pragma unroll
        for (int j = 0; j < 4; ++j) acc[i][j] += a[i] * bb[j];
    }
    #pragma unroll
    for (int i = 0; i < 4; ++i)
      #pragma unroll
      for (int j = 0; j < 4; ++j) ddv[jt][i][j] = acc[i][j] * DN_SCALE;
  }

  if (IS_QUERY) {
    #pragma unroll
    for (int r = 0; r < 4; ++r) {
      float m = -3.4e38f;
      #pragma unroll
      for (int jt = 0; jt < 4; ++jt)
        #pragma unroll
        for (int j = 0; j < 4; ++j) m = fmaxf(m, ddv[jt][r][j]);
      // reduce across the 16 lanes (tc) sharing this row group
      #pragma unroll
      for (int o = 1; o < 16; o <<= 1) m = fmaxf(m, __shfl_xor(m, o, 64));
      float dg = diag[tr * 4 + r];
      int row = n0 + tr * 4 + r;
      #pragma unroll
      for (int jt = 0; jt < 4; ++jt)
        #pragma unroll
        for (int j = 0; j < 4; ++j) {
          float v = RATIO * (expf(ddv[jt][r][j] - dg - m) + FEPS);
          qfb[(size_t)(b * N_TOK + row) * HF + h * NF + jt * 64 + tc * 4 + j] = f2b(v);
        }
    }
  } else {
    float mx = -3.4e38f;
    #pragma unroll
    for (int r = 0; r < 4; ++r) {
      float dg = diag[tr * 4 + r];
      int row = n0 + tr * 4 + r;
      #pragma unroll
      for (int jt = 0; jt < 4; ++jt)
        #pragma unroll
        for (int j = 0; j < 4; ++j) {
          float dd = ddv[jt][r][j];
          mx = fmaxf(mx, dd);
          ktmp[(size_t)(b * N_TOK + row) * HF + h * NF + jt * 64 + tc * 4 + j] = dd - dg;
        }
    }
    #pragma unroll
    for (int o = 32; o > 0; o >>= 1) mx = fmaxf(mx, __shfl_xor(mx, o, 64));
    if ((tid & 63) == 0) wred[tid >> 6] = mx;
    __syncthreads();
    if (tid == 0)
      bmax[bh * 32 + blockIdx.x] = fmaxf(fmaxf(wred[0], wred[1]), fmaxf(wred[2], wred[3]));
  }
}

__global__ void gmax_kernel(const float* __restrict__ bmax, float* __restrict__ gmax) {
  __shared__ float red[4];
  float m = -3.4e38f;
  for (int i = threadIdx.x; i < 512; i += 256) m = fmaxf(m, bmax[i]);
  #pragma unroll
  for (int o = 32; o > 0; o >>= 1) m = fmaxf(m, __shfl_xor(m, o, 64));
  if ((threadIdx.x & 63) == 0) red[threadIdx.x >> 6] = m;
  __syncthreads();
  if (threadIdx.x == 0) gmax[0] = fmaxf(fmaxf(red[0], red[1]), fmaxf(red[2], red[3]));
}

// ============ K feature pass 2: exponentiate, write bf16
__global__ void featk2_kernel(const float* __restrict__ ktmp, const float* __restrict__ gmax,
                              short* __restrict__ kb) {
  size_t base = ((size_t)blockIdx.x * 256 + threadIdx.x) * 8;
  float M = gmax[0];
  #pragma unroll
  for (int u = 0; u < 8; ++u)
    kb[base + u] = f2b(RATIO * (expf(ktmp[base + u] - M) + FEPS));
}

// ============ q scaled by Dinv/8 -> qb bf16
__global__ void qscale_kernel(const short* __restrict__ qfb, const float* __restrict__ Dinv,
                              short* __restrict__ qb) {
  size_t base = ((size_t)blockIdx.x * 256 + threadIdx.x) * 8;
  int c = (int)(base & (HF - 1));
  int i = (int)((base >> 11) & (N_TOK - 1));
  int b = (int)(base >> 22);
  float dv = Dinv[(b * NH + (c >> 8)) * N_TOK + i] * 0.125f;
  #pragma unroll
  for (int u = 0; u < 8; ++u)
    qb[base + u] = f2b(b2f(qfb[base + u]) * dv);
}

// ============ ksum partials
__global__ void ksum_part_kernel(const short* __restrict__ kb, float* __restrict__ part) {
  int f = threadIdx.x, chunk = blockIdx.x, bh = blockIdx.y;
  int b = bh >> 3, h = bh & 7;
  int n0 = chunk * 256;
  float s = 0.f;
  for (int n = n0; n < n0 + 256; ++n)
    s += b2f(kb[(size_t)(b * N_TOK + n) * HF + h * NF + f]);
  part[(size_t)(bh * 8 + chunk) * NF + f] = s;
}

__global__ void ksum_final_kernel(const float* __restrict__ part, float* __restrict__ ksum) {
  int f = threadIdx.x, bh = blockIdx.x;
  float s = 0.f;
  #pragma unroll
  for (int c = 0; c < 8; ++c) s += part[(size_t)(bh * 8 + c) * NF + f];
  ksum[bh * NF + f] = s;
}

// ============ D_inv
__global__ void dinv_kernel(const short* __restrict__ qfb, const float* __restrict__ ksum,
                            float* __restrict__ Dinv) {
  __shared__ float ks[NF];
  int r0 = blockIdx.x * 4;
  int bh = r0 >> 11, b = bh >> 3, h = bh & 7;
  int n0 = r0 & 2047;
  int lane = threadIdx.x & 63, w = threadIdx.x >> 6;
  ks[threadIdx.x] = ksum[bh * NF + threadIdx.x];
  __syncthreads();
  int n = n0 + w;
  const short* qr = qfb + (size_t)(b * N_TOK + n) * HF + h * NF;
  float s = 0.f;
  #pragma unroll
  for (int f0 = 0; f0 < NF; f0 += 64) s += b2f(qr[f0 + lane]) * ks[f0 + lane];
  #pragma unroll
  for (int o = 32; o > 0; o >>= 1) s += __shfl_xor(s, o, 64);
  if (lane == 0) Dinv[bh * N_TOK + n] = 1.0f / s;
}

// ============ context: ctx[bh][f][e] = sum_n kb[n,f] * v[n,e]
__global__ void ctx_kernel(const short* __restrict__ kb, const float* __restrict__ Vlin,
                           float* __restrict__ ctx) {
  int bh = blockIdx.y, b = bh >> 3, h = bh & 7;
  int f0 = blockIdx.x * 64;
  __shared__ float kf[32][68];
  __shared__ float vs[32][68];
  int tid = threadIdx.x;
  int tf = (tid >> 4) * 4, te = (tid & 15) * 4;
  float acc[4][4] = {};
  for (int n0 = 0; n0 < N_TOK; n0 += 32) {
    #pragma unroll
    for (int i = 0; i < 8; i++) {
      int idx = tid + i * 256;
      int nn = idx >> 6, f = idx & 63;
      kf[nn][f] = b2f(kb[(size_t)(b * N_TOK + n0 + nn) * HF + h * NF + f0 + f]);
    }
    #pragma unroll
    for (int i = 0; i < 8; i++) {
      int idx = tid + i * 256;
      int nn = idx >> 6, e = idx & 63;
      vs[nn][e] = Vlin[(size_t)(b * N_TOK + n0 + nn) * DM + h * DHH + e];
    }
    __syncthreads();
    #pragma unroll
    for (int nn = 0; nn < 32; nn++) {
      float a[4], bb[4];
      #pragma unroll
      for (int i = 0; i < 4; i++) a[i] = kf[nn][tf + i];
      #pragma unroll
      for (int j = 0; j < 4; j++) bb[j] = vs[nn][te + j];
      #pragma unroll
      for (int i = 0; i < 4; i++)
        #pragma unroll
        for (int j = 0; j < 4; j++) acc[i][j] += a[i] * bb[j];
    }
    __syncthreads();
  }
  #pragma unroll
  for (int i = 0; i < 4; i++)
    #pragma unroll
    for (int j = 0; j < 4; j++)
      ctx[(size_t)bh * NF * DHH + (size_t)(f0 + tf + i) * DHH + te + j] = acc[i][j];
}

// ============ PV
__global__ void pv_kernel(const short* __restrict__ qfb, const float* __restrict__ ctx,
                          const float* __restrict__ Dinv, short* __restrict__ aob) {
  int bh = blockIdx.y, b = bh >> 3, h = bh & 7;
  int n0 = blockIdx.x * 64;
  __shared__ float qs[16][68];
  __shared__ float cs[16][68];
  int tid = threadIdx.x;
  int tn = (tid >> 4) * 4, te = (tid & 15) * 4;
  float acc[4][4] = {};
  for (int k0 = 0; k0 < NF; k0 += 16) {
    #pragma unroll
    for (int i = 0; i < 4; i++) {
      int idx = tid + i * 256;
      int n = idx >> 4, k = idx & 15;
      qs[k][n] = b2f(qfb[(size_t)(b * N_TOK + n0 + n) * HF + h * NF + k0 + k]);
    }
    #pragma unroll
    for (int i = 0; i < 4; i++) {
      int idx = tid + i * 256;
      int k = idx >> 6, e = idx & 63;
      cs[k][e] = ctx[(size_t)bh * NF * DHH + (size_t)(k0 + k) * DHH + e];
    }
    __syncthreads();
    #pragma unroll
    for (int k = 0; k < 16; k++) {
      float a[4], bb[4];
      #pragma unroll
      for (int i = 0; i < 4; i++) a[i] = qs[k][tn + i];
      #pragma unroll
      for (int j = 0; j < 4; j++) bb[j] = cs[k][te + j];
      #pragma unroll
      for (int i = 0; i < 4; i++)
        #pragma unroll
        for (int j = 0; j < 4; j++) acc[i][j] += a[i] * bb[j];
    }
    __syncthreads();
  }
  #pragma unroll
  for (int i = 0; i < 4; i++) {
    float dv = Dinv[bh * N_TOK + n0 + tn + i];
    #pragma unroll
    for (int j = 0; j < 4; j++)
      aob[(size_t)(b * N_TOK + n0 + tn + i) * DM + h * DHH + te + j] = f2b(acc[i][j] * dv);
  }
}

// ============ LayerNorm over D=512
template<bool OUT_BF16>
__global__ void ln_kernel(const float* __restrict__ x, const float* __restrict__ g,
                          const float* __restrict__ beta, void* __restrict__ y) {
  int row = blockIdx.x, t = threadIdx.x;
  __shared__ float red[4];
  __shared__ float bcast[2];
  const float* xr = x + (size_t)row * DM;
  float v0 = xr[t], v1 = xr[t + 256];
  float s = v0 + v1;
  #pragma unroll
  for (int o = 32; o > 0; o >>= 1) s += __shfl_xor(s, o, 64);
  if ((t & 63) == 0) red[t >> 6] = s;
  __syncthreads();
  if (t == 0) bcast[0] = (red[0] + red[1] + red[2] + red[3]) * (1.0f / 512.0f);
  __syncthreads();
  float mean = bcast[0];
  float d0 = v0 - mean, d1 = v1 - mean;
  float s2 = d0 * d0 + d1 * d1;
  #pragma unroll
  for (int o = 32; o > 0; o >>= 1) s2 += __shfl_xor(s2, o, 64);
  if ((t & 63) == 0) red[t >> 6] = s2;
  __syncthreads();
  if (t == 0) bcast[1] = (red[0] + red[1] + red[2] + red[3]) * (1.0f / 512.0f);
  __syncthreads();
  float inv = rsqrtf(bcast[1] + LN_EPS);
  float o0 = g[t] * d0 * inv + beta[t];
  float o1 = g[t + 256] * d1 * inv + beta[t + 256];
  if (OUT_BF16) {
    ((short*)y)[(size_t)row * DM + t] = f2b(o0);
    ((short*)y)[(size_t)row * DM + t + 256] = f2b(o1);
  } else {
    ((float*)y)[(size_t)row * DM + t] = o0;
    ((float*)y)[(size_t)row * DM + t + 256] = o1;
  }
}

extern "C" void kernel_launch(void* const* d_in, const int* in_sizes, int n_in,
                              void* d_out, int out_size, void* d_ws, size_t ws_size,
                              hipStream_t stream) {
  const float* x     = (const float*)d_in[0];
  const float* Wq    = (const float*)d_in[1];
  const float* bq    = (const float*)d_in[2];
  const float* Wk    = (const float*)d_in[3];
  const float* bk    = (const float*)d_in[4];
  const float* Wv    = (const float*)d_in[5];
  const float* bv    = (const float*)d_in[6];
  const float* Wo    = (const float*)d_in[7];
  const float* bo    = (const float*)d_in[8];
  const float* proj  = (const float*)d_in[9];
  const float* W1    = (const float*)d_in[10];
  const float* b1    = (const float*)d_in[11];
  const float* W2    = (const float*)d_in[12];
  const float* b2    = (const float*)d_in[13];
  const float* g1    = (const float*)d_in[14];
  const float* beta1 = (const float*)d_in[15];
  const float* g2    = (const float*)d_in[16];
  const float* beta2 = (const float*)d_in[17];

  float* ws = (float*)d_ws;
  float* y_out = (float*)d_out;
  float* attnw = y_out + (size_t)B_SZ * N_TOK * DM;

  float* ktmp  = ws + OFF_S0;
  short* qb    = (short*)(ws + OFF_S0);
  float* out2  = ws + OFF_OUT2;
  short* ff1b  = (short*)(ws + OFF_FF1B);
  float* ff2   = ws + OFF_FF2;
  short* qfb   = (short*)(ws + OFF_QFB);
  short* kb    = (short*)(ws + OFF_KB);
  float* Qlin  = ws + OFF_QLIN;
  float* Klin  = ws + OFF_KLIN;
  float* Vlin  = ws + OFF_VLIN;
  short* aob   = (short*)(ws + OFF_AOB);
  short* h1b   = (short*)(ws + OFF_H1B);
  short* Wot   = (short*)(ws + OFF_WOT);
  short* W1t   = (short*)(ws + OFF_W1T);
  short* W2t   = (short*)(ws + OFF_W2T);
  float* ksum  = ws + OFF_KSUM;
  float* part  = ws + OFF_PART;
  float* Dinv  = ws + OFF_DINV;
  float* ctx   = ws + OFF_CTX;
  float* bmax  = ws + OFF_BMAX;
  float* gmax  = ws + OFF_GMAX;

  dim3 blk(256);
  int MT = B_SZ * N_TOK;

  // weight transposes
  transpose_w<<<dim3(8, 8), blk, 0, stream>>>(Wo, Wot, DM, DM);
  transpose_w<<<dim3(32, 8), blk, 0, stream>>>(W1, W1t, DM, DFF);
  transpose_w<<<dim3(8, 32), blk, 0, stream>>>(W2, W2t, DFF, DM);

  // 1) QKV projections (fp32)
  gemm_nn<<<dim3(DM / 64, MT / 64), blk, 0, stream>>>(x, Wq, bq, Qlin, MT, DM, DM);
  gemm_nn<<<dim3(DM / 64, MT / 64), blk, 0, stream>>>(x, Wk, bk, Klin, MT, DM, DM);
  gemm_nn<<<dim3(DM / 64, MT / 64), blk, 0, stream>>>(x, Wv, bv, Vlin, MT, DM, DM);

  // 2) feature maps (tiled GEMM structure)
  feat_kernel<true><<<dim3(N_TOK / 64, B_SZ * NH), blk, 0, stream>>>(Qlin, proj, qfb, nullptr, nullptr);
  feat_kernel<false><<<dim3(N_TOK / 64, B_SZ * NH), blk, 0, stream>>>(Klin, proj, nullptr, ktmp, bmax);
  gmax_kernel<<<1, blk, 0, stream>>>(bmax, gmax);
  featk2_kernel<<<(B_SZ * N_TOK * HF) / (256 * 8), blk, 0, stream>>>(ktmp, gmax, kb);

  // 3) k_sum and D_inv
  ksum_part_kernel<<<dim3(8, B_SZ * NH), blk, 0, stream>>>(kb, part);
  ksum_final_kernel<<<B_SZ * NH, blk, 0, stream>>>(part, ksum);
  dinv_kernel<<<(B_SZ * NH * N_TOK) / 4, blk, 0, stream>>>(qfb, ksum, Dinv);

  // 4) linear attention
  ctx_kernel<<<dim3(NF / 64, B_SZ * NH), blk, 0, stream>>>(kb, Vlin, ctx);
  pv_kernel<<<dim3(N_TOK / 64, B_SZ * NH), blk, 0, stream>>>(qfb, ctx, Dinv, aob);

  // 5) attn-weight output
  qscale_kernel<<<(B_SZ * N_TOK * HF) / (256 * 8), blk, 0, stream>>>(qfb, Dinv, qb);
  gemm_mfma<false, false, false><<<dim3(16, 16, 2), blk, 0, stream>>>(
      qb, kb, nullptr, attnw, N_TOK, N_TOK, HF,
      (size_t)N_TOK * HF, (size_t)N_TOK * HF, (size_t)N_TOK * N_TOK);

  // 6) Wo projection
  gemm_mfma<false, false, true><<<dim3(4, 32, 1), blk, 0, stream>>>(
      aob, Wot, bo, out2, MT, DM, DM, 0, 0, 0);

  // 7) FFN
  ln_kernel<true><<<MT, blk, 0, stream>>>(out2, g1, beta1, h1b);
  gemm_mfma<true, true, true><<<dim3(16, 32, 1), blk, 0, stream>>>(
      h1b, W1t, b1, ff1b, MT, DFF, DM, 0, 0, 0);
  gemm_mfma<false, false, true><<<dim3(4, 32, 1), blk, 0, stream>>>(
      ff1b, W2t, b2, ff2, MT, DM, DFF, 0, 0, 0);
  ln_kernel<false><<<MT, blk, 0, stream>>>(ff2, g2, beta2, y_out);
}

// Round 4
// 337.186 us; speedup vs baseline: 4.4451x; 1.4143x over previous
//
#include <hip/hip_runtime.h>
#include <math.h>

// Problem constants
#define B_SZ   2
#define N_TOK  2048
#define DM     512
#define NH     8
#define DHH    64
#define NF     256
#define DFF    2048
#define HF     2048    // NH*NF

constexpr float DN_SCALE   = 0.35355339059327373f; // 64^-0.25
constexpr float DIAG_SCALE = 0.0625f;              // 0.5 * dn^2
constexpr float RATIO      = 0.0625f;              // 256^-0.5
constexpr float FEPS       = 1e-4f;
constexpr float LN_EPS     = 1e-5f;

typedef __attribute__((ext_vector_type(8))) short bf16x8;
typedef __attribute__((ext_vector_type(4))) float f32x4;

__device__ __forceinline__ short f2b(float f) {
  union { float f; unsigned u; } x; x.f = f;
  unsigned r = (x.u + 0x7fff + ((x.u >> 16) & 1)) >> 16;
  return (short)r;
}
__device__ __forceinline__ float b2f(short s) {
  union { unsigned u; float f; } x; x.u = ((unsigned)(unsigned short)s) << 16;
  return x.f;
}
__device__ __forceinline__ void gload16(const void* g, void* l) {
  __builtin_amdgcn_global_load_lds((const __attribute__((address_space(1))) void*)g,
                                   (__attribute__((address_space(3))) void*)l, 16, 0, 0);
}

// Workspace layout (float-offset units)
// S0 [0, 8388608): ktmp -> ctxp -> qb -> out2/ff1b/ff2
constexpr size_t OFF_S0    = 0;
constexpr size_t OFF_OUT2  = 0;              // fp32 [4096,512]
constexpr size_t OFF_FF1B  = 2097152;        // bf16 [4096,2048]
constexpr size_t OFF_FF2   = 6291456;        // fp32 [4096,512]
constexpr size_t OFF_QFB   = 8388608;        // bf16 [2,2048,2048]; earlier: xb bf16 [4096,512]
constexpr size_t OFF_KB    = 12582912;       // bf16 [2,2048,2048]; earlier: Wqt/Wkt/Wvt bf16
constexpr size_t OFF_QLIN  = 16777216;       // fp32 [4096,512]
constexpr size_t OFF_KLIN  = 18874368;       // fp32 [4096,512]
constexpr size_t OFF_VLIN  = 20971520;       // fp32 [4096,512] -> aob bf16
constexpr size_t OFF_AOB   = 20971520;       // bf16 [4096,512]
constexpr size_t OFF_H1B   = 22020096;       // bf16 [4096,512]
constexpr size_t OFF_WOT   = 23068672;       // bf16 [512,512]
constexpr size_t OFF_W1T   = 23199744;       // bf16 [2048,512]
constexpr size_t OFF_W2T   = 23724032;       // bf16 [512,2048]
constexpr size_t OFF_KSUM  = 24248320;
constexpr size_t OFF_PART  = 24252416;
constexpr size_t OFF_DINV  = 24285184;
constexpr size_t OFF_CTXT  = 24317952;       // bf16 ctxT [16,64,256] (131072 floats used)
constexpr size_t OFF_BMAX  = 24580096;       // [512]
constexpr size_t OFF_GMAX  = 24612864;

// ============ bf16 MFMA GEMM: C = A[M,K] @ Bt[N,K]^T (+bias, relu), m97 structure
template<bool RELU, bool OUT_BF16, bool HAS_BIAS>
__global__ __launch_bounds__(256)
void gemm_mfma(const short* __restrict__ A, const short* __restrict__ Bt,
               const float* __restrict__ bias, void* __restrict__ Cout,
               int M, int N, int K, size_t sA, size_t sB, size_t sC) {
  __shared__ short As[128 * 64];
  __shared__ short Bs[128 * 64];
  int tid = threadIdx.x;
  int lane = tid & 63, wave = tid >> 6;
  int wm = wave >> 1, wn = wave & 1;
  int bm = blockIdx.y * 128, bn = blockIdx.x * 128;
  const short* Ab = A + (size_t)blockIdx.z * sA;
  const short* Bb = Bt + (size_t)blockIdx.z * sB;

  f32x4 acc[4][4] = {};
  int srow = tid >> 3;
  int scol = (tid & 7) * 8;

  for (int k0 = 0; k0 < K; k0 += 64) {
    #pragma unroll
    for (int c = 0; c < 4; ++c) {
      int r = c * 32 + srow;
      gload16(Ab + (size_t)(bm + r) * K + k0 + scol, As + c * 2048 + wave * 512);
      gload16(Bb + (size_t)(bn + r) * K + k0 + scol, Bs + c * 2048 + wave * 512);
    }
    __syncthreads();
    #pragma unroll
    for (int kk = 0; kk < 2; ++kk) {
      bf16x8 af[4], bf[4];
      int kq = kk * 32 + (lane >> 4) * 8;
      #pragma unroll
      for (int i = 0; i < 4; ++i)
        af[i] = *(const bf16x8*)&As[(wm * 64 + i * 16 + (lane & 15)) * 64 + kq];
      #pragma unroll
      for (int j = 0; j < 4; ++j)
        bf[j] = *(const bf16x8*)&Bs[(wn * 64 + j * 16 + (lane & 15)) * 64 + kq];
      #pragma unroll
      for (int i = 0; i < 4; ++i)
        #pragma unroll
        for (int j = 0; j < 4; ++j)
          acc[i][j] = __builtin_amdgcn_mfma_f32_16x16x32_bf16(af[i], bf[j], acc[i][j], 0, 0, 0);
    }
    __syncthreads();
  }

  int row0 = bm + wm * 64, col0 = bn + wn * 64;
  #pragma unroll
  for (int i = 0; i < 4; ++i) {
    #pragma unroll
    for (int j = 0; j < 4; ++j) {
      int col = col0 + j * 16 + (lane & 15);
      float bv = HAS_BIAS ? bias[col] : 0.f;
      #pragma unroll
      for (int r = 0; r < 4; ++r) {
        int row = row0 + i * 16 + (lane >> 4) * 4 + r;
        float v = acc[i][j][r] + bv;
        if (RELU) v = fmaxf(v, 0.f);
        size_t off = (size_t)blockIdx.z * sC + (size_t)row * N + col;
        if (OUT_BF16) ((short*)Cout)[off] = f2b(v);
        else          ((float*)Cout)[off] = v;
      }
    }
  }
}

// ============ fp32 -> bf16 convert (vectorized x8)
__global__ void cvt_bf16_kernel(const float* __restrict__ in, short* __restrict__ out) {
  size_t base = ((size_t)blockIdx.x * 256 + threadIdx.x) * 8;
  #pragma unroll
  for (int u = 0; u < 8; ++u) out[base + u] = f2b(in[base + u]);
}

// ============ weight transpose+convert: W[K][N] fp32 -> Wt[N][K] bf16
__global__ void transpose_w(const float* __restrict__ W, short* __restrict__ Wt, int K, int N) {
  __shared__ float t[64][65];
  int k0 = blockIdx.y * 64, n0 = blockIdx.x * 64;
  int lx = threadIdx.x & 63, ly = threadIdx.x >> 6;
  for (int r = ly; r < 64; r += 4)
    t[r][lx] = W[(size_t)(k0 + r) * N + n0 + lx];
  __syncthreads();
  for (int r = ly; r < 64; r += 4)
    Wt[(size_t)(n0 + r) * K + k0 + lx] = f2b(t[lx][r]);
}

// ============ feature map as tiled GEMM: 64 rows x 256 features per block
template<bool IS_QUERY>
__global__ __launch_bounds__(256)
void feat_kernel(const float* __restrict__ lin, const float* __restrict__ proj,
                 short* __restrict__ qfb, float* __restrict__ ktmp,
                 float* __restrict__ bmax) {
  __shared__ float Ds[64][65];   // [dim][row]
  __shared__ float Ps[64][65];   // [dim][feat]
  __shared__ float diag[64];
  __shared__ float wred[4];
  int bh = blockIdx.y, b = bh >> 3, h = bh & 7;
  int n0 = blockIdx.x * 64;
  int tid = threadIdx.x;
  int tr = tid >> 4, tc = tid & 15;

  #pragma unroll
  for (int i = 0; i < 16; ++i) {
    int idx = tid + i * 256;
    int r = idx >> 6, d = idx & 63;
    Ds[d][r] = lin[(size_t)(b * N_TOK + n0 + r) * DM + h * DHH + d];
  }
  __syncthreads();
  if (tid < 64) {
    float s = 0.f;
    #pragma unroll 8
    for (int d = 0; d < 64; ++d) { float a = Ds[d][tid]; s += a * a; }
    diag[tid] = s * DIAG_SCALE;
  }

  float ddv[4][4][4];  // [ftile][row][feat]
  #pragma unroll
  for (int jt = 0; jt < 4; ++jt) {
    __syncthreads();
    #pragma unroll
    for (int i = 0; i < 16; ++i) {
      int idx = tid + i * 256;
      int j = idx >> 6, d = idx & 63;
      Ps[d][j] = proj[(size_t)(jt * 64 + j) * DHH + d];
    }
    __syncthreads();
    float acc[4][4] = {};
    for (int k = 0; k < 64; ++k) {
      float a[4], bb[4];
      #pragma unroll
      for (int i = 0; i < 4; ++i) a[i] = Ds[k][tr * 4 + i];
      #pragma unroll
      for (int j = 0; j < 4; ++j) bb[j] = Ps[k][tc * 4 + j];
      #pragma unroll
      for (int i = 0; i < 4; ++i)
        #pragma unroll
        for (int j = 0; j < 4; ++j) acc[i][j] += a[i] * bb[j];
    }
    #pragma unroll
    for (int i = 0; i < 4; ++i)
      #pragma unroll
      for (int j = 0; j < 4; ++j) ddv[jt][i][j] = acc[i][j] * DN_SCALE;
  }

  if (IS_QUERY) {
    #pragma unroll
    for (int r = 0; r < 4; ++r) {
      float m = -3.4e38f;
      #pragma unroll
      for (int jt = 0; jt < 4; ++jt)
        #pragma unroll
        for (int j = 0; j < 4; ++j) m = fmaxf(m, ddv[jt][r][j]);
      #pragma unroll
      for (int o = 1; o < 16; o <<= 1) m = fmaxf(m, __shfl_xor(m, o, 64));
      float dg = diag[tr * 4 + r];
      int row = n0 + tr * 4 + r;
      #pragma unroll
      for (int jt = 0; jt < 4; ++jt)
        #pragma unroll
        for (int j = 0; j < 4; ++j) {
          float v = RATIO * (expf(ddv[jt][r][j] - dg - m) + FEPS);
          qfb[(size_t)(b * N_TOK + row) * HF + h * NF + jt * 64 + tc * 4 + j] = f2b(v);
        }
    }
  } else {
    float mx = -3.4e38f;
    #pragma unroll
    for (int r = 0; r < 4; ++r) {
      float dg = diag[tr * 4 + r];
      int row = n0 + tr * 4 + r;
      #pragma unroll
      for (int jt = 0; jt < 4; ++jt)
        #pragma unroll
        for (int j = 0; j < 4; ++j) {
          float dd = ddv[jt][r][j];
          mx = fmaxf(mx, dd);
          ktmp[(size_t)(b * N_TOK + row) * HF + h * NF + jt * 64 + tc * 4 + j] = dd - dg;
        }
    }
    #pragma unroll
    for (int o = 32; o > 0; o >>= 1) mx = fmaxf(mx, __shfl_xor(mx, o, 64));
    if ((tid & 63) == 0) wred[tid >> 6] = mx;
    __syncthreads();
    if (tid == 0)
      bmax[bh * 32 + blockIdx.x] = fmaxf(fmaxf(wred[0], wred[1]), fmaxf(wred[2], wred[3]));
  }
}

__global__ void gmax_kernel(const float* __restrict__ bmax, float* __restrict__ gmax) {
  __shared__ float red[4];
  float m = -3.4e38f;
  for (int i = threadIdx.x; i < 512; i += 256) m = fmaxf(m, bmax[i]);
  #pragma unroll
  for (int o = 32; o > 0; o >>= 1) m = fmaxf(m, __shfl_xor(m, o, 64));
  if ((threadIdx.x & 63) == 0) red[threadIdx.x >> 6] = m;
  __syncthreads();
  if (threadIdx.x == 0) gmax[0] = fmaxf(fmaxf(red[0], red[1]), fmaxf(red[2], red[3]));
}

__global__ void featk2_kernel(const float* __restrict__ ktmp, const float* __restrict__ gmax,
                              short* __restrict__ kb) {
  size_t base = ((size_t)blockIdx.x * 256 + threadIdx.x) * 8;
  float M = gmax[0];
  #pragma unroll
  for (int u = 0; u < 8; ++u)
    kb[base + u] = f2b(RATIO * (expf(ktmp[base + u] - M) + FEPS));
}

__global__ void qscale_kernel(const short* __restrict__ qfb, const float* __restrict__ Dinv,
                              short* __restrict__ qb) {
  size_t base = ((size_t)blockIdx.x * 256 + threadIdx.x) * 8;
  int c = (int)(base & (HF - 1));
  int i = (int)((base >> 11) & (N_TOK - 1));
  int b = (int)(base >> 22);
  float dv = Dinv[(b * NH + (c >> 8)) * N_TOK + i] * 0.125f;
  #pragma unroll
  for (int u = 0; u < 8; ++u)
    qb[base + u] = f2b(b2f(qfb[base + u]) * dv);
}

__global__ void ksum_part_kernel(const short* __restrict__ kb, float* __restrict__ part) {
  int f = threadIdx.x, chunk = blockIdx.x, bh = blockIdx.y;
  int b = bh >> 3, h = bh & 7;
  int n0 = chunk * 256;
  float s = 0.f;
  for (int n = n0; n < n0 + 256; ++n)
    s += b2f(kb[(size_t)(b * N_TOK + n) * HF + h * NF + f]);
  part[(size_t)(bh * 8 + chunk) * NF + f] = s;
}

__global__ void ksum_final_kernel(const float* __restrict__ part, float* __restrict__ ksum) {
  int f = threadIdx.x, bh = blockIdx.x;
  float s = 0.f;
  #pragma unroll
  for (int c = 0; c < 8; ++c) s += part[(size_t)(bh * 8 + c) * NF + f];
  ksum[bh * NF + f] = s;
}

__global__ void dinv_kernel(const short* __restrict__ qfb, const float* __restrict__ ksum,
                            float* __restrict__ Dinv) {
  __shared__ float ks[NF];
  int r0 = blockIdx.x * 4;
  int bh = r0 >> 11, b = bh >> 3, h = bh & 7;
  int n0 = r0 & 2047;
  int lane = threadIdx.x & 63, w = threadIdx.x >> 6;
  ks[threadIdx.x] = ksum[bh * NF + threadIdx.x];
  __syncthreads();
  int n = n0 + w;
  const short* qr = qfb + (size_t)(b * N_TOK + n) * HF + h * NF;
  float s = 0.f;
  #pragma unroll
  for (int f0 = 0; f0 < NF; f0 += 64) s += b2f(qr[f0 + lane]) * ks[f0 + lane];
  #pragma unroll
  for (int o = 32; o > 0; o >>= 1) s += __shfl_xor(s, o, 64);
  if (lane == 0) Dinv[bh * N_TOK + n] = 1.0f / s;
}

// ============ ctx partial: ctxp[chunk][bh][f][e] over 128-row n-chunks
__global__ __launch_bounds__(256)
void ctx_part_kernel(const short* __restrict__ kb, const float* __restrict__ Vlin,
                     float* __restrict__ ctxp) {
  int bh = blockIdx.y, b = bh >> 3, h = bh & 7;
  int f0 = blockIdx.x * 64;
  int ns = blockIdx.z * 128;
  __shared__ float kf[32][68];
  __shared__ float vs[32][68];
  int tid = threadIdx.x;
  int tf = (tid >> 4) * 4, te = (tid & 15) * 4;
  float acc[4][4] = {};
  for (int n0 = ns; n0 < ns + 128; n0 += 32) {
    #pragma unroll
    for (int i = 0; i < 8; i++) {
      int idx = tid + i * 256;
      int nn = idx >> 6, f = idx & 63;
      kf[nn][f] = b2f(kb[(size_t)(b * N_TOK + n0 + nn) * HF + h * NF + f0 + f]);
    }
    #pragma unroll
    for (int i = 0; i < 8; i++) {
      int idx = tid + i * 256;
      int nn = idx >> 6, e = idx & 63;
      vs[nn][e] = Vlin[(size_t)(b * N_TOK + n0 + nn) * DM + h * DHH + e];
    }
    __syncthreads();
    #pragma unroll
    for (int nn = 0; nn < 32; nn++) {
      float a[4], bb[4];
      #pragma unroll
      for (int i = 0; i < 4; i++) a[i] = kf[nn][tf + i];
      #pragma unroll
      for (int j = 0; j < 4; j++) bb[j] = vs[nn][te + j];
      #pragma unroll
      for (int i = 0; i < 4; i++)
        #pragma unroll
        for (int j = 0; j < 4; j++) acc[i][j] += a[i] * bb[j];
    }
    __syncthreads();
  }
  #pragma unroll
  for (int i = 0; i < 4; i++)
    #pragma unroll
    for (int j = 0; j < 4; j++)
      ctxp[(size_t)blockIdx.z * 262144 + (size_t)bh * 16384 +
           (size_t)(f0 + tf + i) * 64 + te + j] = acc[i][j];
}

// ============ ctx reduce + transpose -> ctxT bf16 [bh][e=64][f=256]
__global__ __launch_bounds__(256)
void ctx_reduce_kernel(const float* __restrict__ ctxp, short* __restrict__ ctxT) {
  __shared__ float T[64][65];
  int ftile = blockIdx.x, bh = blockIdx.y;
  int tid = threadIdx.x;
  int e = tid & 63, q = tid >> 6;
  #pragma unroll
  for (int i = 0; i < 16; ++i) {
    int fl = i * 4 + q;
    size_t idx = (size_t)bh * 16384 + (size_t)(ftile * 64 + fl) * 64 + e;
    float s = 0.f;
    #pragma unroll
    for (int c = 0; c < 16; ++c) s += ctxp[(size_t)c * 262144 + idx];
    T[fl][e] = s;
  }
  __syncthreads();
  #pragma unroll
  for (int i = 0; i < 16; ++i) {
    int er = i * 4 + q;
    ctxT[(size_t)bh * 16384 + (size_t)er * 256 + ftile * 64 + e] = f2b(T[e][er]);
  }
}

// ============ PV via MFMA: aob = Dinv * (qfb[M=2048,K=256] @ ctxT[64,256]^T), per bh
__global__ __launch_bounds__(256)
void pv_mfma_kernel(const short* __restrict__ qfb, const short* __restrict__ ctxT,
                    const float* __restrict__ Dinv, short* __restrict__ aob) {
  __shared__ short As[128 * 64];
  __shared__ short Bs[64 * 64];
  int bh = blockIdx.y, b = bh >> 3, h = bh & 7;
  int n0 = blockIdx.x * 128;
  int tid = threadIdx.x;
  int lane = tid & 63, wave = tid >> 6;
  int srow = tid >> 3, scol = (tid & 7) * 8;

  f32x4 acc[2][4] = {};
  for (int k0 = 0; k0 < NF; k0 += 64) {
    #pragma unroll
    for (int c = 0; c < 4; ++c) {
      int r = c * 32 + srow;
      gload16(qfb + (size_t)(b * N_TOK + n0 + r) * HF + h * NF + k0 + scol,
              As + c * 2048 + wave * 512);
    }
    #pragma unroll
    for (int c = 0; c < 2; ++c) {
      int r = c * 32 + srow;
      gload16(ctxT + (size_t)bh * 16384 + (size_t)r * 256 + k0 + scol,
              Bs + c * 2048 + wave * 512);
    }
    __syncthreads();
    #pragma unroll
    for (int kk = 0; kk < 2; ++kk) {
      bf16x8 af[2], bf[4];
      int kq = kk * 32 + (lane >> 4) * 8;
      #pragma unroll
      for (int i = 0; i < 2; ++i)
        af[i] = *(const bf16x8*)&As[(wave * 32 + i * 16 + (lane & 15)) * 64 + kq];
      #pragma unroll
      for (int j = 0; j < 4; ++j)
        bf[j] = *(const bf16x8*)&Bs[(j * 16 + (lane & 15)) * 64 + kq];
      #pragma unroll
      for (int i = 0; i < 2; ++i)
        #pragma unroll
        for (int j = 0; j < 4; ++j)
          acc[i][j] = __builtin_amdgcn_mfma_f32_16x16x32_bf16(af[i], bf[j], acc[i][j], 0, 0, 0);
    }
    __syncthreads();
  }

  #pragma unroll
  for (int i = 0; i < 2; ++i) {
    #pragma unroll
    for (int j = 0; j < 4; ++j) {
      int e = j * 16 + (lane & 15);
      #pragma unroll
      for (int r = 0; r < 4; ++r) {
        int n = n0 + wave * 32 + i * 16 + (lane >> 4) * 4 + r;
        float dv = Dinv[bh * N_TOK + n];
        aob[(size_t)(b * N_TOK + n) * DM + h * DHH + e] = f2b(acc[i][j][r] * dv);
      }
    }
  }
}

// ============ LayerNorm over D=512
template<bool OUT_BF16>
__global__ void ln_kernel(const float* __restrict__ x, const float* __restrict__ g,
                          const float* __restrict__ beta, void* __restrict__ y) {
  int row = blockIdx.x, t = threadIdx.x;
  __shared__ float red[4];
  __shared__ float bcast[2];
  const float* xr = x + (size_t)row * DM;
  float v0 = xr[t], v1 = xr[t + 256];
  float s = v0 + v1;
  #pragma unroll
  for (int o = 32; o > 0; o >>= 1) s += __shfl_xor(s, o, 64);
  if ((t & 63) == 0) red[t >> 6] = s;
  __syncthreads();
  if (t == 0) bcast[0] = (red[0] + red[1] + red[2] + red[3]) * (1.0f / 512.0f);
  __syncthreads();
  float mean = bcast[0];
  float d0 = v0 - mean, d1 = v1 - mean;
  float s2 = d0 * d0 + d1 * d1;
  #pragma unroll
  for (int o = 32; o > 0; o >>= 1) s2 += __shfl_xor(s2, o, 64);
  if ((t & 63) == 0) red[t >> 6] = s2;
  __syncthreads();
  if (t == 0) bcast[1] = (red[0] + red[1] + red[2] + red[3]) * (1.0f / 512.0f);
  __syncthreads();
  float inv = rsqrtf(bcast[1] + LN_EPS);
  float o0 = g[t] * d0 * inv + beta[t];
  float o1 = g[t + 256] * d1 * inv + beta[t + 256];
  if (OUT_BF16) {
    ((short*)y)[(size_t)row * DM + t] = f2b(o0);
    ((short*)y)[(size_t)row * DM + t + 256] = f2b(o1);
  } else {
    ((float*)y)[(size_t)row * DM + t] = o0;
    ((float*)y)[(size_t)row * DM + t + 256] = o1;
  }
}

extern "C" void kernel_launch(void* const* d_in, const int* in_sizes, int n_in,
                              void* d_out, int out_size, void* d_ws, size_t ws_size,
                              hipStream_t stream) {
  const float* x     = (const float*)d_in[0];
  const float* Wq    = (const float*)d_in[1];
  const float* bq    = (const float*)d_in[2];
  const float* Wk    = (const float*)d_in[3];
  const float* bk    = (const float*)d_in[4];
  const float* Wv    = (const float*)d_in[5];
  const float* bv    = (const float*)d_in[6];
  const float* Wo    = (const float*)d_in[7];
  const float* bo    = (const float*)d_in[8];
  const float* proj  = (const float*)d_in[9];
  const float* W1    = (const float*)d_in[10];
  const float* b1    = (const float*)d_in[11];
  const float* W2    = (const float*)d_in[12];
  const float* b2    = (const float*)d_in[13];
  const float* g1    = (const float*)d_in[14];
  const float* beta1 = (const float*)d_in[15];
  const float* g2    = (const float*)d_in[16];
  const float* beta2 = (const float*)d_in[17];

  float* ws = (float*)d_ws;
  float* y_out = (float*)d_out;
  float* attnw = y_out + (size_t)B_SZ * N_TOK * DM;

  float* ktmp  = ws + OFF_S0;
  float* ctxp  = ws + OFF_S0;                 // after ktmp dead
  short* qb    = (short*)(ws + OFF_S0);       // after ctxp dead
  float* out2  = ws + OFF_OUT2;
  short* ff1b  = (short*)(ws + OFF_FF1B);
  float* ff2   = ws + OFF_FF2;
  short* qfb   = (short*)(ws + OFF_QFB);
  short* xb    = (short*)(ws + OFF_QFB);      // before qfb written
  short* kb    = (short*)(ws + OFF_KB);
  short* Wqt   = (short*)(ws + OFF_KB);       // before kb written
  short* Wkt   = Wqt + 262144;
  short* Wvt   = Wkt + 262144;
  float* Qlin  = ws + OFF_QLIN;
  float* Klin  = ws + OFF_KLIN;
  float* Vlin  = ws + OFF_VLIN;
  short* aob   = (short*)(ws + OFF_AOB);
  short* h1b   = (short*)(ws + OFF_H1B);
  short* Wot   = (short*)(ws + OFF_WOT);
  short* W1t   = (short*)(ws + OFF_W1T);
  short* W2t   = (short*)(ws + OFF_W2T);
  float* ksum  = ws + OFF_KSUM;
  float* part  = ws + OFF_PART;
  float* Dinv  = ws + OFF_DINV;
  short* ctxT  = (short*)(ws + OFF_CTXT);
  float* bmax  = ws + OFF_BMAX;
  float* gmax  = ws + OFF_GMAX;

  dim3 blk(256);
  int MT = B_SZ * N_TOK;

  // 0) conversions and weight transposes
  cvt_bf16_kernel<<<(MT * DM) / (256 * 8), blk, 0, stream>>>(x, xb);
  transpose_w<<<dim3(8, 8), blk, 0, stream>>>(Wq, Wqt, DM, DM);
  transpose_w<<<dim3(8, 8), blk, 0, stream>>>(Wk, Wkt, DM, DM);
  transpose_w<<<dim3(8, 8), blk, 0, stream>>>(Wv, Wvt, DM, DM);
  transpose_w<<<dim3(8, 8), blk, 0, stream>>>(Wo, Wot, DM, DM);
  transpose_w<<<dim3(32, 8), blk, 0, stream>>>(W1, W1t, DM, DFF);
  transpose_w<<<dim3(8, 32), blk, 0, stream>>>(W2, W2t, DFF, DM);

  // 1) QKV projections (bf16 MFMA, fp32 out)
  gemm_mfma<false, false, true><<<dim3(4, 32, 1), blk, 0, stream>>>(
      xb, Wqt, bq, Qlin, MT, DM, DM, 0, 0, 0);
  gemm_mfma<false, false, true><<<dim3(4, 32, 1), blk, 0, stream>>>(
      xb, Wkt, bk, Klin, MT, DM, DM, 0, 0, 0);
  gemm_mfma<false, false, true><<<dim3(4, 32, 1), blk, 0, stream>>>(
      xb, Wvt, bv, Vlin, MT, DM, DM, 0, 0, 0);

  // 2) feature maps
  feat_kernel<true><<<dim3(N_TOK / 64, B_SZ * NH), blk, 0, stream>>>(Qlin, proj, qfb, nullptr, nullptr);
  feat_kernel<false><<<dim3(N_TOK / 64, B_SZ * NH), blk, 0, stream>>>(Klin, proj, nullptr, ktmp, bmax);
  gmax_kernel<<<1, blk, 0, stream>>>(bmax, gmax);
  featk2_kernel<<<(B_SZ * N_TOK * HF) / (256 * 8), blk, 0, stream>>>(ktmp, gmax, kb);

  // 3) k_sum and D_inv
  ksum_part_kernel<<<dim3(8, B_SZ * NH), blk, 0, stream>>>(kb, part);
  ksum_final_kernel<<<B_SZ * NH, blk, 0, stream>>>(part, ksum);
  dinv_kernel<<<(B_SZ * NH * N_TOK) / 4, blk, 0, stream>>>(qfb, ksum, Dinv);

  // 4) linear attention: split-K ctx, then MFMA pv
  ctx_part_kernel<<<dim3(NF / 64, B_SZ * NH, 16), blk, 0, stream>>>(kb, Vlin, ctxp);
  ctx_reduce_kernel<<<dim3(4, B_SZ * NH), blk, 0, stream>>>(ctxp, ctxT);
  pv_mfma_kernel<<<dim3(N_TOK / 128, B_SZ * NH), blk, 0, stream>>>(qfb, ctxT, Dinv, aob);

  // 5) attn-weight output
  qscale_kernel<<<(B_SZ * N_TOK * HF) / (256 * 8), blk, 0, stream>>>(qfb, Dinv, qb);
  gemm_mfma<false, false, false><<<dim3(16, 16, 2), blk, 0, stream>>>(
      qb, kb, nullptr, attnw, N_TOK, N_TOK, HF,
      (size_t)N_TOK * HF, (size_t)N_TOK * HF, (size_t)N_TOK * N_TOK);

  // 6) Wo projection
  gemm_mfma<false, false, true><<<dim3(4, 32, 1), blk, 0, stream>>>(
      aob, Wot, bo, out2, MT, DM, DM, 0, 0, 0);

  // 7) FFN
  ln_kernel<true><<<MT, blk, 0, stream>>>(out2, g1, beta1, h1b);
  gemm_mfma<true, true, true><<<dim3(16, 32, 1), blk, 0, stream>>>(
      h1b, W1t, b1, ff1b, MT, DFF, DM, 0, 0, 0);
  gemm_mfma<false, false, true><<<dim3(4, 32, 1), blk, 0, stream>>>(
      ff1b, W2t, b2, ff2, MT, DM, DFF, 0, 0, 0);
  ln_kernel<false><<<MT, blk, 0, stream>>>(ff2, g2, beta2, y_out);
}

// Round 5
// 271.267 us; speedup vs baseline: 5.5253x; 1.2430x over previous
//
#include <hip/hip_runtime.h>
#include <math.h>

// Problem constants
#define B_SZ   2
#define N_TOK  2048
#define DM     512
#define NH     8
#define DHH    64
#define NF     256
#define DFF    2048
#define HF     2048    // NH*NF
#define LDQKV  1536    // fused QKV row stride

constexpr float DN_SCALE   = 0.35355339059327373f; // 64^-0.25
constexpr float DIAG_SCALE = 0.0625f;              // 0.5 * dn^2
constexpr float RATIO      = 0.0625f;              // 256^-0.5
constexpr float FEPS       = 1e-4f;
constexpr float LN_EPS     = 1e-5f;

typedef __attribute__((ext_vector_type(8))) short bf16x8;
typedef __attribute__((ext_vector_type(8))) _Float16 f16x8;
typedef __attribute__((ext_vector_type(4))) float f32x4;

__device__ __forceinline__ short f2b(float f) {
  union { float f; unsigned u; } x; x.f = f;
  unsigned r = (x.u + 0x7fff + ((x.u >> 16) & 1)) >> 16;
  return (short)r;
}
__device__ __forceinline__ float b2f(short s) {
  union { unsigned u; float f; } x; x.u = ((unsigned)(unsigned short)s) << 16;
  return x.f;
}
__device__ __forceinline__ void gload16(const void* g, void* l) {
  __builtin_amdgcn_global_load_lds((const __attribute__((address_space(1))) void*)g,
                                   (__attribute__((address_space(3))) void*)l, 16, 0, 0);
}
// XOR swizzle for [R][64-elem] 16-bit LDS tiles (128B rows): 16B-chunk granular
__device__ __forceinline__ int swz64(int row, int kbyte) {
  return (row * 128 + kbyte) ^ ((row & 7) << 4);
}

// Workspace layout (float-offset units)
// S0 [0, 8388608): ktmp(full) -> {ctxp [0,4.2M) | qb [4.2M,8.4M)} -> out2/ff1b/ff2
constexpr size_t OFF_S0    = 0;
constexpr size_t OFF_CTXP  = 0;              // fp32 16x[16][256][64] = 4194304
constexpr size_t OFF_QB    = 4194304;        // bf16 [2,2048,2048] = 4194304 slots
constexpr size_t OFF_OUT2  = 0;              // fp32 [4096,512]
constexpr size_t OFF_FF1B  = 2097152;        // bf16 [4096,2048]
constexpr size_t OFF_FF2   = 6291456;        // fp32 [4096,512]
constexpr size_t OFF_QFB   = 8388608;        // bf16 [2,2048,2048]; earlier: xb
constexpr size_t OFF_KB    = 12582912;       // bf16 [2,2048,2048]; earlier: Wqkvt
constexpr size_t OFF_QKV   = 16777216;       // fp32 [4096,1536]
constexpr size_t OFF_AOB   = 20971520;       // bf16 [4096,512] (QKV dead by then)
constexpr size_t OFF_H1B   = 22020096;       // bf16 [4096,512]
constexpr size_t OFF_WOT   = 23068672;       // bf16 [512,512]
constexpr size_t OFF_W1T   = 23199744;       // bf16 [2048,512]
constexpr size_t OFF_W2T   = 23724032;       // bf16 [512,2048]
constexpr size_t OFF_KSUM  = 24248320;
constexpr size_t OFF_PART  = 24252416;
constexpr size_t OFF_DINV  = 24285184;
constexpr size_t OFF_CTXT  = 24317952;       // bf16 ctxT [16,64,256]
constexpr size_t OFF_BMAX  = 24580096;       // [512]
constexpr size_t OFF_GMAX  = 24612864;

// ============ bf16 MFMA GEMM: C = A[M,K] @ Bt[N,K]^T (+bias, relu), m97 structure
template<bool RELU, bool OUT_BF16, bool HAS_BIAS, bool SWZ>
__global__ __launch_bounds__(256)
void gemm_mfma(const short* __restrict__ A, const short* __restrict__ Bt,
               const float* __restrict__ bias, void* __restrict__ Cout,
               int M, int N, int K, size_t sA, size_t sB, size_t sC, int ldC) {
  __shared__ short As[128 * 64];
  __shared__ short Bs[128 * 64];
  int tid = threadIdx.x;
  int lane = tid & 63, wave = tid >> 6;
  int wm = wave >> 1, wn = wave & 1;
  int bx = blockIdx.x, by = blockIdx.y;
  if (SWZ) {  // XCD-aware bijective remap (grid.x*grid.y % 8 == 0 required)
    int nwg = gridDim.x * gridDim.y;
    int flat = by * gridDim.x + bx;
    int swz = (flat & 7) * (nwg >> 3) + (flat >> 3);
    bx = swz % gridDim.x; by = swz / gridDim.x;
  }
  int bm = by * 128, bn = bx * 128;
  const short* Ab = A + (size_t)blockIdx.z * sA;
  const short* Bb = Bt + (size_t)blockIdx.z * sB;

  f32x4 acc[4][4] = {};
  int srow = tid >> 3;
  int scol = (tid & 7) * 8;

  for (int k0 = 0; k0 < K; k0 += 64) {
    #pragma unroll
    for (int c = 0; c < 4; ++c) {
      int r = c * 32 + srow;
      gload16(Ab + (size_t)(bm + r) * K + k0 + scol, As + c * 2048 + wave * 512);
      gload16(Bb + (size_t)(bn + r) * K + k0 + scol, Bs + c * 2048 + wave * 512);
    }
    __syncthreads();
    #pragma unroll
    for (int kk = 0; kk < 2; ++kk) {
      bf16x8 af[4], bf[4];
      int kq = kk * 32 + (lane >> 4) * 8;
      #pragma unroll
      for (int i = 0; i < 4; ++i)
        af[i] = *(const bf16x8*)&As[(wm * 64 + i * 16 + (lane & 15)) * 64 + kq];
      #pragma unroll
      for (int j = 0; j < 4; ++j)
        bf[j] = *(const bf16x8*)&Bs[(wn * 64 + j * 16 + (lane & 15)) * 64 + kq];
      #pragma unroll
      for (int i = 0; i < 4; ++i)
        #pragma unroll
        for (int j = 0; j < 4; ++j)
          acc[i][j] = __builtin_amdgcn_mfma_f32_16x16x32_bf16(af[i], bf[j], acc[i][j], 0, 0, 0);
    }
    __syncthreads();
  }

  int row0 = bm + wm * 64, col0 = bn + wn * 64;
  #pragma unroll
  for (int i = 0; i < 4; ++i) {
    #pragma unroll
    for (int j = 0; j < 4; ++j) {
      int col = col0 + j * 16 + (lane & 15);
      float bv = HAS_BIAS ? bias[col] : 0.f;
      #pragma unroll
      for (int r = 0; r < 4; ++r) {
        int row = row0 + i * 16 + (lane >> 4) * 4 + r;
        float v = acc[i][j][r] + bv;
        if (RELU) v = fmaxf(v, 0.f);
        size_t off = (size_t)blockIdx.z * sC + (size_t)row * ldC + col;
        if (OUT_BF16) ((short*)Cout)[off] = f2b(v);
        else          ((float*)Cout)[off] = v;
      }
    }
  }
}

// ============ fp32 -> bf16 convert (vectorized x8)
__global__ void cvt_bf16_kernel(const float* __restrict__ in, short* __restrict__ out) {
  size_t base = ((size_t)blockIdx.x * 256 + threadIdx.x) * 8;
  #pragma unroll
  for (int u = 0; u < 8; ++u) out[base + u] = f2b(in[base + u]);
}

// ============ 4x 512x512 weight transpose+convert in one launch
__global__ void transpose_w4(const float* s0, const float* s1, const float* s2, const float* s3,
                             short* d0, short* d1, short* d2, short* d3) {
  __shared__ float t[64][65];
  int z = blockIdx.z;
  const float* W = (z == 0) ? s0 : (z == 1) ? s1 : (z == 2) ? s2 : s3;
  short* Wt      = (z == 0) ? d0 : (z == 1) ? d1 : (z == 2) ? d2 : d3;
  int k0 = blockIdx.y * 64, n0 = blockIdx.x * 64;
  int lx = threadIdx.x & 63, ly = threadIdx.x >> 6;
  for (int r = ly; r < 64; r += 4)
    t[r][lx] = W[(size_t)(k0 + r) * 512 + n0 + lx];
  __syncthreads();
  for (int r = ly; r < 64; r += 4)
    Wt[(size_t)(n0 + r) * 512 + k0 + lx] = f2b(t[lx][r]);
}

// ============ generic weight transpose+convert: W[K][N] fp32 -> Wt[N][K] bf16
__global__ void transpose_w(const float* __restrict__ W, short* __restrict__ Wt, int K, int N) {
  __shared__ float t[64][65];
  int k0 = blockIdx.y * 64, n0 = blockIdx.x * 64;
  int lx = threadIdx.x & 63, ly = threadIdx.x >> 6;
  for (int r = ly; r < 64; r += 4)
    t[r][lx] = W[(size_t)(k0 + r) * N + n0 + lx];
  __syncthreads();
  for (int r = ly; r < 64; r += 4)
    Wt[(size_t)(n0 + r) * K + k0 + lx] = f2b(t[lx][r]);
}

// ============ feature map via f16x3 MFMA (fp32-quality dd), fully fused
// dd = DN * ((q+bias) @ proj^T). Q: exp(dd - diag - rowmax) -> bf16
// K: ktmp = exp(dd - diag) fp32, bmax = block max of dd
template<bool IS_QUERY>
__global__ __launch_bounds__(256)
void feat_mfma_kernel(const float* __restrict__ qkv, int coff, const float* __restrict__ bias,
                      const float* __restrict__ proj, short* __restrict__ qfb,
                      float* __restrict__ ktmp, float* __restrict__ bmax) {
  __shared__ short qh[64 * 64], ql[64 * 64];     // 8 KB each, f16 bits
  __shared__ short ph[128 * 64], pl[128 * 64];   // 16 KB each
  __shared__ float dpart[64][4];
  __shared__ float diag[64];
  __shared__ float wred[4];
  int t = threadIdx.x;
  int bh = blockIdx.y, b = bh >> 3, h = bh & 7;
  int n0 = blockIdx.x * 64;
  int lane = t & 63, w = t >> 6, l15 = lane & 15, lq = lane >> 4;

  // stage A: 64 rows x 64 dims (+bias), f16 hi/lo split, swizzled
  {
    int r = t >> 2, cg = (t & 3) * 16;
    const float* src = qkv + (size_t)(b * N_TOK + n0 + r) * LDQKV + coff + h * 64 + cg;
    const float* bs = bias + h * 64 + cg;
    float ss = 0.f;
    #pragma unroll
    for (int c2 = 0; c2 < 2; ++c2) {
      f16x8 H, L;
      #pragma unroll
      for (int u = 0; u < 8; ++u) {
        float xv = src[c2 * 8 + u] + bs[c2 * 8 + u];
        ss += xv * xv;
        _Float16 hi = (_Float16)xv;
        H[u] = hi;
        L[u] = (_Float16)(xv - (float)hi);
      }
      int off = swz64(r, cg * 2 + c2 * 16);
      *(f16x8*)((char*)qh + off) = H;
      *(f16x8*)((char*)ql + off) = L;
    }
    dpart[r][t & 3] = ss;
  }
  __syncthreads();
  if (t < 64)
    diag[t] = (dpart[t][0] + dpart[t][1] + dpart[t][2] + dpart[t][3]) * DIAG_SCALE;

  // A fragments (reused across all features)
  f16x8 ah[2], al[2];
  #pragma unroll
  for (int kk = 0; kk < 2; ++kk) {
    int off = swz64(w * 16 + l15, kk * 64 + lq * 16);
    ah[kk] = *(f16x8*)((char*)qh + off);
    al[kk] = *(f16x8*)((char*)ql + off);
  }

  f32x4 acc[16] = {};
  #pragma unroll
  for (int half = 0; half < 2; ++half) {
    __syncthreads();
    { // stage 128 proj rows, f16 hi/lo
      int r = t & 127, cg = (t >> 7) * 32;
      const float* src = proj + (size_t)(half * 128 + r) * DHH + cg;
      #pragma unroll
      for (int c2 = 0; c2 < 4; ++c2) {
        f16x8 H, L;
        #pragma unroll
        for (int u = 0; u < 8; ++u) {
          float xv = src[c2 * 8 + u];
          _Float16 hi = (_Float16)xv;
          H[u] = hi;
          L[u] = (_Float16)(xv - (float)hi);
        }
        int off = swz64(r, cg * 2 + c2 * 16);
        *(f16x8*)((char*)ph + off) = H;
        *(f16x8*)((char*)pl + off) = L;
      }
    }
    __syncthreads();
    #pragma unroll
    for (int jl = 0; jl < 8; ++jl) {
      int row = jl * 16 + l15;
      #pragma unroll
      for (int kk = 0; kk < 2; ++kk) {
        int off = swz64(row, kk * 64 + lq * 16);
        f16x8 bh8 = *(f16x8*)((char*)ph + off);
        f16x8 bl8 = *(f16x8*)((char*)pl + off);
        acc[half * 8 + jl] = __builtin_amdgcn_mfma_f32_16x16x32_f16(ah[kk], bh8, acc[half * 8 + jl], 0, 0, 0);
        acc[half * 8 + jl] = __builtin_amdgcn_mfma_f32_16x16x32_f16(al[kk], bh8, acc[half * 8 + jl], 0, 0, 0);
        acc[half * 8 + jl] = __builtin_amdgcn_mfma_f32_16x16x32_f16(ah[kk], bl8, acc[half * 8 + jl], 0, 0, 0);
      }
    }
  }

  if (IS_QUERY) {
    #pragma unroll
    for (int r = 0; r < 4; ++r) {
      float mx = -3.4e38f;
      #pragma unroll
      for (int j = 0; j < 16; ++j) mx = fmaxf(mx, acc[j][r]);
      #pragma unroll
      for (int o = 1; o < 16; o <<= 1) mx = fmaxf(mx, __shfl_xor(mx, o, 64));
      int lrow = w * 16 + lq * 4 + r;
      float dg = diag[lrow];
      float ddm = mx * DN_SCALE;
      size_t base = (size_t)(b * N_TOK + n0 + lrow) * HF + h * NF + l15;
      #pragma unroll
      for (int j = 0; j < 16; ++j) {
        float v = RATIO * (expf(acc[j][r] * DN_SCALE - dg - ddm) + FEPS);
        qfb[base + j * 16] = f2b(v);
      }
    }
  } else {
    float mxall = -3.4e38f;
    #pragma unroll
    for (int r = 0; r < 4; ++r) {
      int lrow = w * 16 + lq * 4 + r;
      float dg = diag[lrow];
      size_t base = (size_t)(b * N_TOK + n0 + lrow) * HF + h * NF + l15;
      #pragma unroll
      for (int j = 0; j < 16; ++j) {
        float a = acc[j][r];
        mxall = fmaxf(mxall, a);
        ktmp[base + j * 16] = expf(a * DN_SCALE - dg);
      }
    }
    #pragma unroll
    for (int o = 1; o < 64; o <<= 1) mxall = fmaxf(mxall, __shfl_xor(mxall, o, 64));
    if (lane == 0) wred[w] = mxall;
    __syncthreads();
    if (t == 0)
      bmax[bh * 32 + blockIdx.x] =
          fmaxf(fmaxf(wred[0], wred[1]), fmaxf(wred[2], wred[3])) * DN_SCALE;
  }
}

__global__ void gmax_kernel(const float* __restrict__ bmax, float* __restrict__ gmax) {
  __shared__ float red[4];
  float m = -3.4e38f;
  for (int i = threadIdx.x; i < 512; i += 256) m = fmaxf(m, bmax[i]);
  #pragma unroll
  for (int o = 32; o > 0; o >>= 1) m = fmaxf(m, __shfl_xor(m, o, 64));
  if ((threadIdx.x & 63) == 0) red[threadIdx.x >> 6] = m;
  __syncthreads();
  if (threadIdx.x == 0) gmax[0] = fmaxf(fmaxf(red[0], red[1]), fmaxf(red[2], red[3]));
}

// ============ K feature pass 2: kb = RATIO*(e*exp(-m) + eps), bf16
__global__ void featk2_kernel(const float* __restrict__ ktmp, const float* __restrict__ gmax,
                              short* __restrict__ kb) {
  size_t base = ((size_t)blockIdx.x * 256 + threadIdx.x) * 8;
  float s = expf(-gmax[0]);
  #pragma unroll
  for (int u = 0; u < 8; ++u)
    kb[base + u] = f2b(RATIO * (ktmp[base + u] * s + FEPS));
}

__global__ void ksum_part_kernel(const short* __restrict__ kb, float* __restrict__ part) {
  int f = threadIdx.x, chunk = blockIdx.x, bh = blockIdx.y;
  int b = bh >> 3, h = bh & 7;
  int n0 = chunk * 256;
  float s = 0.f;
  for (int n = n0; n < n0 + 256; ++n)
    s += b2f(kb[(size_t)(b * N_TOK + n) * HF + h * NF + f]);
  part[(size_t)(bh * 8 + chunk) * NF + f] = s;
}

__global__ void ksum_final_kernel(const float* __restrict__ part, float* __restrict__ ksum) {
  int f = threadIdx.x, bh = blockIdx.x;
  float s = 0.f;
  #pragma unroll
  for (int c = 0; c < 8; ++c) s += part[(size_t)(bh * 8 + c) * NF + f];
  ksum[bh * NF + f] = s;
}

// ============ fused D_inv + q-scale: one block per token row
__global__ __launch_bounds__(256)
void dinvqs_kernel(const short* __restrict__ qfb, const float* __restrict__ ksum,
                   float* __restrict__ Dinv, short* __restrict__ qb) {
  int R = blockIdx.x;
  int b = R >> 11, n = R & 2047;
  int t = threadIdx.x;
  bf16x8 qv = *(const bf16x8*)(qfb + (size_t)R * HF + t * 8);
  const float* ks = ksum + b * 2048 + t * 8;
  float p = 0.f;
  #pragma unroll
  for (int u = 0; u < 8; ++u) p += b2f(qv[u]) * ks[u];
  #pragma unroll
  for (int o = 1; o < 32; o <<= 1) p += __shfl_xor(p, o, 64);
  float d = 1.0f / p;
  if ((t & 31) == 0) Dinv[(b * NH + (t >> 5)) * N_TOK + n] = d;
  float dv = d * 0.125f;
  bf16x8 o8;
  #pragma unroll
  for (int u = 0; u < 8; ++u) o8[u] = f2b(b2f(qv[u]) * dv);
  *(bf16x8*)(qb + (size_t)R * HF + t * 8) = o8;
}

// ============ ctx partial over 128-row n-chunks (V read from fused QKV + bias)
__global__ __launch_bounds__(256)
void ctx_part_kernel(const short* __restrict__ kb, const float* __restrict__ qkv,
                     const float* __restrict__ bv, float* __restrict__ ctxp) {
  int bh = blockIdx.y, b = bh >> 3, h = bh & 7;
  int f0 = blockIdx.x * 64;
  int ns = blockIdx.z * 128;
  __shared__ float kf[32][68];
  __shared__ float vs[32][68];
  int tid = threadIdx.x;
  int tf = (tid >> 4) * 4, te = (tid & 15) * 4;
  float acc[4][4] = {};
  for (int n0 = ns; n0 < ns + 128; n0 += 32) {
    #pragma unroll
    for (int i = 0; i < 8; i++) {
      int idx = tid + i * 256;
      int nn = idx >> 6, f = idx & 63;
      kf[nn][f] = b2f(kb[(size_t)(b * N_TOK + n0 + nn) * HF + h * NF + f0 + f]);
    }
    #pragma unroll
    for (int i = 0; i < 8; i++) {
      int idx = tid + i * 256;
      int nn = idx >> 6, e = idx & 63;
      vs[nn][e] = qkv[(size_t)(b * N_TOK + n0 + nn) * LDQKV + 1024 + h * DHH + e] + bv[h * DHH + e];
    }
    __syncthreads();
    #pragma unroll
    for (int nn = 0; nn < 32; nn++) {
      float a[4], bb[4];
      #pragma unroll
      for (int i = 0; i < 4; i++) a[i] = kf[nn][tf + i];
      #pragma unroll
      for (int j = 0; j < 4; j++) bb[j] = vs[nn][te + j];
      #pragma unroll
      for (int i = 0; i < 4; i++)
        #pragma unroll
        for (int j = 0; j < 4; j++) acc[i][j] += a[i] * bb[j];
    }
    __syncthreads();
  }
  #pragma unroll
  for (int i = 0; i < 4; i++)
    #pragma unroll
    for (int j = 0; j < 4; j++)
      ctxp[(size_t)blockIdx.z * 262144 + (size_t)bh * 16384 +
           (size_t)(f0 + tf + i) * 64 + te + j] = acc[i][j];
}

// ============ ctx reduce + transpose -> ctxT bf16 [bh][e=64][f=256]
__global__ __launch_bounds__(256)
void ctx_reduce_kernel(const float* __restrict__ ctxp, short* __restrict__ ctxT) {
  __shared__ float T[64][65];
  int ftile = blockIdx.x, bh = blockIdx.y;
  int tid = threadIdx.x;
  int e = tid & 63, q = tid >> 6;
  #pragma unroll
  for (int i = 0; i < 16; ++i) {
    int fl = i * 4 + q;
    size_t idx = (size_t)bh * 16384 + (size_t)(ftile * 64 + fl) * 64 + e;
    float s = 0.f;
    #pragma unroll
    for (int c = 0; c < 16; ++c) s += ctxp[(size_t)c * 262144 + idx];
    T[fl][e] = s;
  }
  __syncthreads();
  #pragma unroll
  for (int i = 0; i < 16; ++i) {
    int er = i * 4 + q;
    ctxT[(size_t)bh * 16384 + (size_t)er * 256 + ftile * 64 + e] = f2b(T[e][er]);
  }
}

// ============ PV via MFMA: aob = Dinv * (qfb @ ctxT^T), per bh
__global__ __launch_bounds__(256)
void pv_mfma_kernel(const short* __restrict__ qfb, const short* __restrict__ ctxT,
                    const float* __restrict__ Dinv, short* __restrict__ aob) {
  __shared__ short As[128 * 64];
  __shared__ short Bs[64 * 64];
  int bh = blockIdx.y, b = bh >> 3, h = bh & 7;
  int n0 = blockIdx.x * 128;
  int tid = threadIdx.x;
  int lane = tid & 63, wave = tid >> 6;
  int srow = tid >> 3, scol = (tid & 7) * 8;

  f32x4 acc[2][4] = {};
  for (int k0 = 0; k0 < NF; k0 += 64) {
    #pragma unroll
    for (int c = 0; c < 4; ++c) {
      int r = c * 32 + srow;
      gload16(qfb + (size_t)(b * N_TOK + n0 + r) * HF + h * NF + k0 + scol,
              As + c * 2048 + wave * 512);
    }
    #pragma unroll
    for (int c = 0; c < 2; ++c) {
      int r = c * 32 + srow;
      gload16(ctxT + (size_t)bh * 16384 + (size_t)r * 256 + k0 + scol,
              Bs + c * 2048 + wave * 512);
    }
    __syncthreads();
    #pragma unroll
    for (int kk = 0; kk < 2; ++kk) {
      bf16x8 af[2], bf[4];
      int kq = kk * 32 + (lane >> 4) * 8;
      #pragma unroll
      for (int i = 0; i < 2; ++i)
        af[i] = *(const bf16x8*)&As[(wave * 32 + i * 16 + (lane & 15)) * 64 + kq];
      #pragma unroll
      for (int j = 0; j < 4; ++j)
        bf[j] = *(const bf16x8*)&Bs[(j * 16 + (lane & 15)) * 64 + kq];
      #pragma unroll
      for (int i = 0; i < 2; ++i)
        #pragma unroll
        for (int j = 0; j < 4; ++j)
          acc[i][j] = __builtin_amdgcn_mfma_f32_16x16x32_bf16(af[i], bf[j], acc[i][j], 0, 0, 0);
    }
    __syncthreads();
  }

  #pragma unroll
  for (int i = 0; i < 2; ++i) {
    #pragma unroll
    for (int j = 0; j < 4; ++j) {
      int e = j * 16 + (lane & 15);
      #pragma unroll
      for (int r = 0; r < 4; ++r) {
        int n = n0 + wave * 32 + i * 16 + (lane >> 4) * 4 + r;
        float dv = Dinv[bh * N_TOK + n];
        aob[(size_t)(b * N_TOK + n) * DM + h * DHH + e] = f2b(acc[i][j][r] * dv);
      }
    }
  }
}

// ============ LayerNorm over D=512
template<bool OUT_BF16>
__global__ void ln_kernel(const float* __restrict__ x, const float* __restrict__ g,
                          const float* __restrict__ beta, void* __restrict__ y) {
  int row = blockIdx.x, t = threadIdx.x;
  __shared__ float red[4];
  __shared__ float bcast[2];
  const float* xr = x + (size_t)row * DM;
  float v0 = xr[t], v1 = xr[t + 256];
  float s = v0 + v1;
  #pragma unroll
  for (int o = 32; o > 0; o >>= 1) s += __shfl_xor(s, o, 64);
  if ((t & 63) == 0) red[t >> 6] = s;
  __syncthreads();
  if (t == 0) bcast[0] = (red[0] + red[1] + red[2] + red[3]) * (1.0f / 512.0f);
  __syncthreads();
  float mean = bcast[0];
  float d0 = v0 - mean, d1 = v1 - mean;
  float s2 = d0 * d0 + d1 * d1;
  #pragma unroll
  for (int o = 32; o > 0; o >>= 1) s2 += __shfl_xor(s2, o, 64);
  if ((t & 63) == 0) red[t >> 6] = s2;
  __syncthreads();
  if (t == 0) bcast[1] = (red[0] + red[1] + red[2] + red[3]) * (1.0f / 512.0f);
  __syncthreads();
  float inv = rsqrtf(bcast[1] + LN_EPS);
  float o0 = g[t] * d0 * inv + beta[t];
  float o1 = g[t + 256] * d1 * inv + beta[t + 256];
  if (OUT_BF16) {
    ((short*)y)[(size_t)row * DM + t] = f2b(o0);
    ((short*)y)[(size_t)row * DM + t + 256] = f2b(o1);
  } else {
    ((float*)y)[(size_t)row * DM + t] = o0;
    ((float*)y)[(size_t)row * DM + t + 256] = o1;
  }
}

extern "C" void kernel_launch(void* const* d_in, const int* in_sizes, int n_in,
                              void* d_out, int out_size, void* d_ws, size_t ws_size,
                              hipStream_t stream) {
  const float* x     = (const float*)d_in[0];
  const float* Wq    = (const float*)d_in[1];
  const float* bq    = (const float*)d_in[2];
  const float* Wk    = (const float*)d_in[3];
  const float* bk    = (const float*)d_in[4];
  const float* Wv    = (const float*)d_in[5];
  const float* bv    = (const float*)d_in[6];
  const float* Wo    = (const float*)d_in[7];
  const float* bo    = (const float*)d_in[8];
  const float* proj  = (const float*)d_in[9];
  const float* W1    = (const float*)d_in[10];
  const float* b1    = (const float*)d_in[11];
  const float* W2    = (const float*)d_in[12];
  const float* b2    = (const float*)d_in[13];
  const float* g1    = (const float*)d_in[14];
  const float* beta1 = (const float*)d_in[15];
  const float* g2    = (const float*)d_in[16];
  const float* beta2 = (const float*)d_in[17];

  float* ws = (float*)d_ws;
  float* y_out = (float*)d_out;
  float* attnw = y_out + (size_t)B_SZ * N_TOK * DM;

  float* ktmp  = ws + OFF_S0;
  float* ctxp  = ws + OFF_CTXP;
  short* qb    = (short*)(ws + OFF_QB);
  float* out2  = ws + OFF_OUT2;
  short* ff1b  = (short*)(ws + OFF_FF1B);
  float* ff2   = ws + OFF_FF2;
  short* qfb   = (short*)(ws + OFF_QFB);
  short* xb    = (short*)(ws + OFF_QFB);      // before qfb written
  short* kb    = (short*)(ws + OFF_KB);
  short* Wqkvt = (short*)(ws + OFF_KB);       // before kb written
  float* QKVlin = ws + OFF_QKV;
  short* aob   = (short*)(ws + OFF_AOB);
  short* h1b   = (short*)(ws + OFF_H1B);
  short* Wot   = (short*)(ws + OFF_WOT);
  short* W1t   = (short*)(ws + OFF_W1T);
  short* W2t   = (short*)(ws + OFF_W2T);
  float* ksum  = ws + OFF_KSUM;
  float* part  = ws + OFF_PART;
  float* Dinv  = ws + OFF_DINV;
  short* ctxT  = (short*)(ws + OFF_CTXT);
  float* bmax  = ws + OFF_BMAX;
  float* gmax  = ws + OFF_GMAX;

  dim3 blk(256);
  int MT = B_SZ * N_TOK;

  // 0) conversions and weight transposes
  cvt_bf16_kernel<<<(MT * DM) / (256 * 8), blk, 0, stream>>>(x, xb);
  transpose_w4<<<dim3(8, 8, 4), blk, 0, stream>>>(
      Wq, Wk, Wv, Wo, Wqkvt, Wqkvt + 262144, Wqkvt + 524288, Wot);
  transpose_w<<<dim3(32, 8), blk, 0, stream>>>(W1, W1t, DM, DFF);
  transpose_w<<<dim3(8, 32), blk, 0, stream>>>(W2, W2t, DFF, DM);

  // 1) fused QKV projection (bias deferred to consumers): QKVlin [4096,1536] fp32
  gemm_mfma<false, false, false, false><<<dim3(LDQKV / 128, MT / 128, 1), blk, 0, stream>>>(
      xb, Wqkvt, nullptr, QKVlin, MT, LDQKV, DM, 0, 0, 0, LDQKV);

  // 2) feature maps (f16x3 MFMA, fused)
  feat_mfma_kernel<true><<<dim3(N_TOK / 64, B_SZ * NH), blk, 0, stream>>>(
      QKVlin, 0, bq, proj, qfb, nullptr, nullptr);
  feat_mfma_kernel<false><<<dim3(N_TOK / 64, B_SZ * NH), blk, 0, stream>>>(
      QKVlin, 512, bk, proj, nullptr, ktmp, bmax);
  gmax_kernel<<<1, blk, 0, stream>>>(bmax, gmax);
  featk2_kernel<<<(B_SZ * N_TOK * HF) / (256 * 8), blk, 0, stream>>>(ktmp, gmax, kb);

  // 3) k_sum, then fused D_inv + q-scale
  ksum_part_kernel<<<dim3(8, B_SZ * NH), blk, 0, stream>>>(kb, part);
  ksum_final_kernel<<<B_SZ * NH, blk, 0, stream>>>(part, ksum);
  dinvqs_kernel<<<MT, blk, 0, stream>>>(qfb, ksum, Dinv, qb);

  // 4) linear attention: split-K ctx, then MFMA pv
  ctx_part_kernel<<<dim3(NF / 64, B_SZ * NH, 16), blk, 0, stream>>>(kb, QKVlin, bv, ctxp);
  ctx_reduce_kernel<<<dim3(4, B_SZ * NH), blk, 0, stream>>>(ctxp, ctxT);
  pv_mfma_kernel<<<dim3(N_TOK / 128, B_SZ * NH), blk, 0, stream>>>(qfb, ctxT, Dinv, aob);

  // 5) attn-weight output (XCD-swizzled)
  gemm_mfma<false, false, false, true><<<dim3(16, 16, 2), blk, 0, stream>>>(
      qb, kb, nullptr, attnw, N_TOK, N_TOK, HF,
      (size_t)N_TOK * HF, (size_t)N_TOK * HF, (size_t)N_TOK * N_TOK, N_TOK);

  // 6) Wo projection
  gemm_mfma<false, false, true, false><<<dim3(4, 32, 1), blk, 0, stream>>>(
      aob, Wot, bo, out2, MT, DM, DM, 0, 0, 0, DM);

  // 7) FFN
  ln_kernel<true><<<MT, blk, 0, stream>>>(out2, g1, beta1, h1b);
  gemm_mfma<true, true, true, false><<<dim3(16, 32, 1), blk, 0, stream>>>(
      h1b, W1t, b1, ff1b, MT, DFF, DM, 0, 0, 0, DFF);
  gemm_mfma<false, false, true, false><<<dim3(4, 32, 1), blk, 0, stream>>>(
      ff1b, W2t, b2, ff2, MT, DM, DFF, 0, 0, 0, DM);
  ln_kernel<false><<<MT, blk, 0, stream>>>(ff2, g2, beta2, y_out);
}

// Round 6
// 263.587 us; speedup vs baseline: 5.6863x; 1.0291x over previous
//
#include <hip/hip_runtime.h>
#include <math.h>

// Problem constants
#define B_SZ   2
#define N_TOK  2048
#define DM     512
#define NH     8
#define DHH    64
#define NF     256
#define DFF    2048
#define HF     2048    // NH*NF
#define LDQKV  1536    // fused QKV row stride

constexpr float DN_SCALE   = 0.35355339059327373f; // 64^-0.25
constexpr float DIAG_SCALE = 0.0625f;              // 0.5 * dn^2
constexpr float RATIO      = 0.0625f;              // 256^-0.5
constexpr float FEPS       = 1e-4f;
constexpr float LN_EPS     = 1e-5f;

typedef __attribute__((ext_vector_type(8))) short bf16x8;
typedef __attribute__((ext_vector_type(8))) _Float16 f16x8;
typedef __attribute__((ext_vector_type(4))) float f32x4;

__device__ __forceinline__ short f2b(float f) {
  union { float f; unsigned u; } x; x.f = f;
  unsigned r = (x.u + 0x7fff + ((x.u >> 16) & 1)) >> 16;
  return (short)r;
}
__device__ __forceinline__ float b2f(short s) {
  union { unsigned u; float f; } x; x.u = ((unsigned)(unsigned short)s) << 16;
  return x.f;
}
__device__ __forceinline__ void gload16(const void* g, void* l) {
  __builtin_amdgcn_global_load_lds((const __attribute__((address_space(1))) void*)g,
                                   (__attribute__((address_space(3))) void*)l, 16, 0, 0);
}
__device__ __forceinline__ int swz64(int row, int kbyte) {
  return (row * 128 + kbyte) ^ ((row & 7) << 4);
}

// Workspace layout (float-offset units)
// S0 [0, 8388608): {ctxp [0,2.1M)} | qb [4.2M,8.4M) -> out2/ff1b/ff2
constexpr size_t OFF_S0    = 0;
constexpr size_t OFF_CTXP  = 0;              // fp32 8x[16][256][64] = 2097152
constexpr size_t OFF_QB    = 4194304;        // bf16 [2,2048,2048]
constexpr size_t OFF_OUT2  = 0;              // fp32 [4096,512]
constexpr size_t OFF_FF1B  = 2097152;        // bf16 [4096,2048]
constexpr size_t OFF_FF2   = 6291456;        // fp32 [4096,512]
constexpr size_t OFF_QFB   = 8388608;        // bf16 [2,2048,2048]; earlier: xb
constexpr size_t OFF_KB    = 12582912;       // bf16 kb' [2,2048,2048]; earlier: Wqkvt
constexpr size_t OFF_QKV   = 16777216;       // fp32 [4096,1536]
constexpr size_t OFF_AOB   = 20971520;       // bf16 [4096,512] (QKV dead by then)
constexpr size_t OFF_H1B   = 22020096;       // bf16 [4096,512]
constexpr size_t OFF_WOT   = 23068672;       // bf16 [512,512]
constexpr size_t OFF_W1T   = 23199744;       // bf16 [2048,512]
constexpr size_t OFF_W2T   = 23724032;       // bf16 [512,2048]
constexpr size_t OFF_KSUM  = 24248320;       // [16,256] affine-applied
constexpr size_t OFF_DINV  = 24252416;       // [16,2048]
constexpr size_t OFF_CTXT  = 24285184;       // bf16 ctxT [16,64,256]
constexpr size_t OFF_BMAX  = 24416256;       // [512]
constexpr size_t OFF_GMAX  = 24416768;       // [1] (stores m)
constexpr size_t OFF_ROWC  = 24416832;       // [4096]
constexpr size_t OFF_PART  = 24420928;       // [16,32,256] col sums of e
constexpr size_t OFF_VSUMP = 24552000;       // [8,16,64]

// ============ bf16 MFMA GEMM: C = A[M,K] @ Bt[N,K]^T, m97 structure
// BMODE: 0 = none, 1 = column bias, 2 = per-row constant (bias + z*M indexed by row)
template<bool RELU, bool OUT_BF16, int BMODE, bool SWZ>
__global__ __launch_bounds__(256)
void gemm_mfma(const short* __restrict__ A, const short* __restrict__ Bt,
               const float* __restrict__ bias, void* __restrict__ Cout,
               int M, int N, int K, size_t sA, size_t sB, size_t sC, int ldC) {
  __shared__ short As[128 * 64];
  __shared__ short Bs[128 * 64];
  int tid = threadIdx.x;
  int lane = tid & 63, wave = tid >> 6;
  int wm = wave >> 1, wn = wave & 1;
  int bx = blockIdx.x, by = blockIdx.y;
  if (SWZ) {
    int nwg = gridDim.x * gridDim.y;
    int flat = by * gridDim.x + bx;
    int swz = (flat & 7) * (nwg >> 3) + (flat >> 3);
    bx = swz % gridDim.x; by = swz / gridDim.x;
  }
  int bm = by * 128, bn = bx * 128;
  const short* Ab = A + (size_t)blockIdx.z * sA;
  const short* Bb = Bt + (size_t)blockIdx.z * sB;
  const float* rc = (BMODE == 2) ? (bias + (size_t)blockIdx.z * M) : bias;

  f32x4 acc[4][4] = {};
  int srow = tid >> 3;
  int scol = (tid & 7) * 8;

  for (int k0 = 0; k0 < K; k0 += 64) {
    #pragma unroll
    for (int c = 0; c < 4; ++c) {
      int r = c * 32 + srow;
      gload16(Ab + (size_t)(bm + r) * K + k0 + scol, As + c * 2048 + wave * 512);
      gload16(Bb + (size_t)(bn + r) * K + k0 + scol, Bs + c * 2048 + wave * 512);
    }
    __syncthreads();
    #pragma unroll
    for (int kk = 0; kk < 2; ++kk) {
      bf16x8 af[4], bf[4];
      int kq = kk * 32 + (lane >> 4) * 8;
      #pragma unroll
      for (int i = 0; i < 4; ++i)
        af[i] = *(const bf16x8*)&As[(wm * 64 + i * 16 + (lane & 15)) * 64 + kq];
      #pragma unroll
      for (int j = 0; j < 4; ++j)
        bf[j] = *(const bf16x8*)&Bs[(wn * 64 + j * 16 + (lane & 15)) * 64 + kq];
      #pragma unroll
      for (int i = 0; i < 4; ++i)
        #pragma unroll
        for (int j = 0; j < 4; ++j)
          acc[i][j] = __builtin_amdgcn_mfma_f32_16x16x32_bf16(af[i], bf[j], acc[i][j], 0, 0, 0);
    }
    __syncthreads();
  }

  int row0 = bm + wm * 64, col0 = bn + wn * 64;
  #pragma unroll
  for (int i = 0; i < 4; ++i) {
    #pragma unroll
    for (int j = 0; j < 4; ++j) {
      int col = col0 + j * 16 + (lane & 15);
      float bv = (BMODE == 1) ? rc[col] : 0.f;
      #pragma unroll
      for (int r = 0; r < 4; ++r) {
        int row = row0 + i * 16 + (lane >> 4) * 4 + r;
        float v = acc[i][j][r] + bv;
        if (BMODE == 2) v += rc[row];
        if (RELU) v = fmaxf(v, 0.f);
        size_t off = (size_t)blockIdx.z * sC + (size_t)row * ldC + col;
        if (OUT_BF16) ((short*)Cout)[off] = f2b(v);
        else          ((float*)Cout)[off] = v;
      }
    }
  }
}

// ============ BN=64 MFMA GEMM (pv geometry): C[M,N] = A[M,K] @ Bt[N,K]^T + bias
template<bool RELU, bool OUT_BF16>
__global__ __launch_bounds__(256)
void gemm_bn64(const short* __restrict__ A, const short* __restrict__ Bt,
               const float* __restrict__ bias, void* __restrict__ Cout,
               int M, int N, int K) {
  __shared__ short As[128 * 64];
  __shared__ short Bs[64 * 64];
  int tid = threadIdx.x, lane = tid & 63, wave = tid >> 6;
  int bn = blockIdx.x * 64, bm = blockIdx.y * 128;
  int srow = tid >> 3, scol = (tid & 7) * 8;
  f32x4 acc[2][4] = {};
  for (int k0 = 0; k0 < K; k0 += 64) {
    #pragma unroll
    for (int c = 0; c < 4; ++c)
      gload16(A + (size_t)(bm + c * 32 + srow) * K + k0 + scol, As + c * 2048 + wave * 512);
    #pragma unroll
    for (int c = 0; c < 2; ++c)
      gload16(Bt + (size_t)(bn + c * 32 + srow) * K + k0 + scol, Bs + c * 2048 + wave * 512);
    __syncthreads();
    #pragma unroll
    for (int kk = 0; kk < 2; ++kk) {
      bf16x8 af[2], bf[4];
      int kq = kk * 32 + (lane >> 4) * 8;
      #pragma unroll
      for (int i = 0; i < 2; ++i)
        af[i] = *(const bf16x8*)&As[(wave * 32 + i * 16 + (lane & 15)) * 64 + kq];
      #pragma unroll
      for (int j = 0; j < 4; ++j)
        bf[j] = *(const bf16x8*)&Bs[(j * 16 + (lane & 15)) * 64 + kq];
      #pragma unroll
      for (int i = 0; i < 2; ++i)
        #pragma unroll
        for (int j = 0; j < 4; ++j)
          acc[i][j] = __builtin_amdgcn_mfma_f32_16x16x32_bf16(af[i], bf[j], acc[i][j], 0, 0, 0);
    }
    __syncthreads();
  }
  #pragma unroll
  for (int i = 0; i < 2; ++i) {
    #pragma unroll
    for (int j = 0; j < 4; ++j) {
      int col = bn + j * 16 + (lane & 15);
      float bv = bias[col];
      #pragma unroll
      for (int r = 0; r < 4; ++r) {
        int row = bm + wave * 32 + i * 16 + (lane >> 4) * 4 + r;
        float v = acc[i][j][r] + bv;
        if (RELU) v = fmaxf(v, 0.f);
        if (OUT_BF16) ((short*)Cout)[(size_t)row * N + col] = f2b(v);
        else          ((float*)Cout)[(size_t)row * N + col] = v;
      }
    }
  }
}

// ============ fused prep: x->bf16 + all 6 weight transposes, one launch
__global__ void prep_kernel(const float* __restrict__ x, short* __restrict__ xb,
                            const float* Wq, const float* Wk, const float* Wv, const float* Wo,
                            short* Wqt, short* Wkt, short* Wvt, short* Wot,
                            const float* W1, short* W1t, const float* W2, short* W2t) {
  __shared__ float t[64][65];
  int id = blockIdx.x, tid = threadIdx.x;
  if (id >= 768) {  // cvt x -> xb
    size_t base = ((size_t)(id - 768) * 256 + tid) * 8;
    #pragma unroll
    for (int u = 0; u < 8; ++u) xb[base + u] = f2b(x[base + u]);
    return;
  }
  const float* W; short* Wt; int K, N, bx, by;
  if (id < 256) {
    int z = id >> 6, sub = id & 63;
    W  = (z == 0) ? Wq : (z == 1) ? Wk : (z == 2) ? Wv : Wo;
    Wt = (z == 0) ? Wqt : (z == 1) ? Wkt : (z == 2) ? Wvt : Wot;
    K = 512; N = 512; bx = sub & 7; by = sub >> 3;
  } else if (id < 512) {
    int sub = id - 256;
    W = W1; Wt = W1t; K = 512; N = 2048; bx = sub & 31; by = sub >> 5;
  } else {
    int sub = id - 512;
    W = W2; Wt = W2t; K = 2048; N = 512; bx = sub & 7; by = sub >> 3;
  }
  int k0 = by * 64, n0 = bx * 64;
  int lx = tid & 63, ly = tid >> 6;
  for (int r = ly; r < 64; r += 4)
    t[r][lx] = W[(size_t)(k0 + r) * N + n0 + lx];
  __syncthreads();
  for (int r = ly; r < 64; r += 4)
    Wt[(size_t)(n0 + r) * K + k0 + lx] = f2b(t[lx][r]);
}

// ============ feature map via f16x3 MFMA, fully fused
// Q: qfb = bf16(RATIO*(exp(dd-diag-rowmax)+FEPS))
// K: kout = bf16(e), e = exp(dd-diag); part = per-block column sums of e; bmax = max dd
template<bool IS_QUERY>
__global__ __launch_bounds__(256)
void feat_mfma_kernel(const float* __restrict__ qkv, int coff, const float* __restrict__ bias,
                      const float* __restrict__ proj, short* __restrict__ qout,
                      float* __restrict__ part, float* __restrict__ bmax) {
  __shared__ short qh[64 * 64], ql[64 * 64];
  __shared__ short ph[128 * 64], pl[128 * 64];
  __shared__ float dpart[64][4];
  __shared__ float diag[64];
  __shared__ float wred[4];
  __shared__ float colp[4][256];
  int t = threadIdx.x;
  int bh = blockIdx.y, b = bh >> 3, h = bh & 7;
  int n0 = blockIdx.x * 64;
  int lane = t & 63, w = t >> 6, l15 = lane & 15, lq = lane >> 4;

  {
    int r = t >> 2, cg = (t & 3) * 16;
    const float* src = qkv + (size_t)(b * N_TOK + n0 + r) * LDQKV + coff + h * 64 + cg;
    const float* bs = bias + h * 64 + cg;
    float ss = 0.f;
    #pragma unroll
    for (int c2 = 0; c2 < 2; ++c2) {
      f16x8 H, L;
      #pragma unroll
      for (int u = 0; u < 8; ++u) {
        float xv = src[c2 * 8 + u] + bs[c2 * 8 + u];
        ss += xv * xv;
        _Float16 hi = (_Float16)xv;
        H[u] = hi;
        L[u] = (_Float16)(xv - (float)hi);
      }
      int off = swz64(r, cg * 2 + c2 * 16);
      *(f16x8*)((char*)qh + off) = H;
      *(f16x8*)((char*)ql + off) = L;
    }
    dpart[r][t & 3] = ss;
  }
  __syncthreads();
  if (t < 64)
    diag[t] = (dpart[t][0] + dpart[t][1] + dpart[t][2] + dpart[t][3]) * DIAG_SCALE;

  f16x8 ah[2], al[2];
  #pragma unroll
  for (int kk = 0; kk < 2; ++kk) {
    int off = swz64(w * 16 + l15, kk * 64 + lq * 16);
    ah[kk] = *(f16x8*)((char*)qh + off);
    al[kk] = *(f16x8*)((char*)ql + off);
  }

  f32x4 acc[16] = {};
  #pragma unroll
  for (int half = 0; half < 2; ++half) {
    __syncthreads();
    {
      int r = t & 127, cg = (t >> 7) * 32;
      const float* src = proj + (size_t)(half * 128 + r) * DHH + cg;
      #pragma unroll
      for (int c2 = 0; c2 < 4; ++c2) {
        f16x8 H, L;
        #pragma unroll
        for (int u = 0; u < 8; ++u) {
          float xv = src[c2 * 8 + u];
          _Float16 hi = (_Float16)xv;
          H[u] = hi;
          L[u] = (_Float16)(xv - (float)hi);
        }
        int off = swz64(r, cg * 2 + c2 * 16);
        *(f16x8*)((char*)ph + off) = H;
        *(f16x8*)((char*)pl + off) = L;
      }
    }
    __syncthreads();
    #pragma unroll
    for (int jl = 0; jl < 8; ++jl) {
      int row = jl * 16 + l15;
      #pragma unroll
      for (int kk = 0; kk < 2; ++kk) {
        int off = swz64(row, kk * 64 + lq * 16);
        f16x8 bh8 = *(f16x8*)((char*)ph + off);
        f16x8 bl8 = *(f16x8*)((char*)pl + off);
        acc[half * 8 + jl] = __builtin_amdgcn_mfma_f32_16x16x32_f16(ah[kk], bh8, acc[half * 8 + jl], 0, 0, 0);
        acc[half * 8 + jl] = __builtin_amdgcn_mfma_f32_16x16x32_f16(al[kk], bh8, acc[half * 8 + jl], 0, 0, 0);
        acc[half * 8 + jl] = __builtin_amdgcn_mfma_f32_16x16x32_f16(ah[kk], bl8, acc[half * 8 + jl], 0, 0, 0);
      }
    }
  }

  if (IS_QUERY) {
    #pragma unroll
    for (int r = 0; r < 4; ++r) {
      float mx = -3.4e38f;
      #pragma unroll
      for (int j = 0; j < 16; ++j) mx = fmaxf(mx, acc[j][r]);
      #pragma unroll
      for (int o = 1; o < 16; o <<= 1) mx = fmaxf(mx, __shfl_xor(mx, o, 64));
      int lrow = w * 16 + lq * 4 + r;
      float dg = diag[lrow];
      float ddm = mx * DN_SCALE;
      size_t base = (size_t)(b * N_TOK + n0 + lrow) * HF + h * NF + l15;
      #pragma unroll
      for (int j = 0; j < 16; ++j) {
        float v = RATIO * (expf(acc[j][r] * DN_SCALE - dg - ddm) + FEPS);
        qout[base + j * 16] = f2b(v);
      }
    }
  } else {
    float mxall = -3.4e38f;
    float cs[16];
    #pragma unroll
    for (int j = 0; j < 16; ++j) cs[j] = 0.f;
    #pragma unroll
    for (int r = 0; r < 4; ++r) {
      int lrow = w * 16 + lq * 4 + r;
      float dg = diag[lrow];
      size_t base = (size_t)(b * N_TOK + n0 + lrow) * HF + h * NF + l15;
      #pragma unroll
      for (int j = 0; j < 16; ++j) {
        float a = acc[j][r];
        mxall = fmaxf(mxall, a);
        float e = expf(a * DN_SCALE - dg);
        cs[j] += e;
        qout[base + j * 16] = f2b(e);
      }
    }
    #pragma unroll
    for (int j = 0; j < 16; ++j) {
      cs[j] += __shfl_xor(cs[j], 16, 64);
      cs[j] += __shfl_xor(cs[j], 32, 64);
    }
    if (lq == 0) {
      #pragma unroll
      for (int j = 0; j < 16; ++j) colp[w][j * 16 + l15] = cs[j];
    }
    #pragma unroll
    for (int o = 1; o < 64; o <<= 1) mxall = fmaxf(mxall, __shfl_xor(mxall, o, 64));
    if (lane == 0) wred[w] = mxall;
    __syncthreads();
    part[(size_t)(bh * 32 + blockIdx.x) * 256 + t] =
        colp[0][t] + colp[1][t] + colp[2][t] + colp[3][t];
    if (t == 0)
      bmax[bh * 32 + blockIdx.x] =
          fmaxf(fmaxf(wred[0], wred[1]), fmaxf(wred[2], wred[3])) * DN_SCALE;
  }
}

// ============ ksum finalize: m from bmax, ksum = RATIO*(s*sum(part) + N*FEPS); gmax = m
__global__ void ksum_final_kernel(const float* __restrict__ part, const float* __restrict__ bmax,
                                  float* __restrict__ ksum, float* __restrict__ gmax) {
  __shared__ float red[4];
  __shared__ float bc[1];
  int bh = blockIdx.x, t = threadIdx.x;
  float m = fmaxf(bmax[t], bmax[t + 256]);
  #pragma unroll
  for (int o = 1; o < 64; o <<= 1) m = fmaxf(m, __shfl_xor(m, o, 64));
  if ((t & 63) == 0) red[t >> 6] = m;
  __syncthreads();
  if (t == 0) {
    bc[0] = fmaxf(fmaxf(red[0], red[1]), fmaxf(red[2], red[3]));
    if (bh == 0) gmax[0] = bc[0];
  }
  __syncthreads();
  float s = expf(-bc[0]);
  float sum = 0.f;
  #pragma unroll 8
  for (int c = 0; c < 32; ++c) sum += part[(size_t)(bh * 32 + c) * 256 + t];
  ksum[bh * 256 + t] = RATIO * (s * sum + (float)N_TOK * FEPS);
}

// ============ fused D_inv + q-scale + row constant
__global__ __launch_bounds__(256)
void dinvqs_kernel(const short* __restrict__ qfb, const float* __restrict__ ksum,
                   const float* __restrict__ gmax, float* __restrict__ Dinv,
                   float* __restrict__ rowc, short* __restrict__ qb) {
  __shared__ float wsum[4];
  int R = blockIdx.x;
  int b = R >> 11, n = R & 2047;
  int t = threadIdx.x;
  float sc = RATIO * expf(-gmax[0]);
  bf16x8 qv = *(const bf16x8*)(qfb + (size_t)R * HF + t * 8);
  const float* ks = ksum + b * 2048 + t * 8;
  float p = 0.f;
  #pragma unroll
  for (int u = 0; u < 8; ++u) p += b2f(qv[u]) * ks[u];
  #pragma unroll
  for (int o = 1; o < 32; o <<= 1) p += __shfl_xor(p, o, 64);
  float d = 1.0f / p;
  if ((t & 31) == 0) Dinv[(b * NH + (t >> 5)) * N_TOK + n] = d;
  float dv = d * 0.125f;
  float qs = 0.f;
  bf16x8 o8;
  #pragma unroll
  for (int u = 0; u < 8; ++u) {
    float qb_f = b2f(qv[u]) * dv;
    qs += qb_f;
    o8[u] = f2b(qb_f * sc);
  }
  *(bf16x8*)(qb + (size_t)R * HF + t * 8) = o8;
  #pragma unroll
  for (int o = 1; o < 64; o <<= 1) qs += __shfl_xor(qs, o, 64);
  if ((t & 63) == 0) wsum[t >> 6] = qs;
  __syncthreads();
  if (t == 0) rowc[R] = RATIO * FEPS * (wsum[0] + wsum[1] + wsum[2] + wsum[3]);
}

// ============ ctx partial over 256-row n-chunks; x-block 0 also sums V columns
__global__ __launch_bounds__(256)
void ctx_part_kernel(const short* __restrict__ kb, const float* __restrict__ qkv,
                     const float* __restrict__ bv, float* __restrict__ ctxp,
                     float* __restrict__ vsump) {
  int bh = blockIdx.y, b = bh >> 3, h = bh & 7;
  int f0 = blockIdx.x * 64;
  int ns = blockIdx.z * 256;
  __shared__ float kf[32][68];
  __shared__ float vs[32][68];
  int tid = threadIdx.x;
  int tf = (tid >> 4) * 4, te = (tid & 15) * 4;
  float acc[4][4] = {};
  float vloc[4] = {};
  for (int n0 = ns; n0 < ns + 256; n0 += 32) {
    #pragma unroll
    for (int i = 0; i < 8; i++) {
      int idx = tid + i * 256;
      int nn = idx >> 6, f = idx & 63;
      kf[nn][f] = b2f(kb[(size_t)(b * N_TOK + n0 + nn) * HF + h * NF + f0 + f]);
    }
    #pragma unroll
    for (int i = 0; i < 8; i++) {
      int idx = tid + i * 256;
      int nn = idx >> 6, e = idx & 63;
      vs[nn][e] = qkv[(size_t)(b * N_TOK + n0 + nn) * LDQKV + 1024 + h * DHH + e] + bv[h * DHH + e];
    }
    __syncthreads();
    #pragma unroll
    for (int nn = 0; nn < 32; nn++) {
      float a[4], bb[4];
      #pragma unroll
      for (int i = 0; i < 4; i++) a[i] = kf[nn][tf + i];
      #pragma unroll
      for (int j = 0; j < 4; j++) bb[j] = vs[nn][te + j];
      #pragma unroll
      for (int i = 0; i < 4; i++)
        #pragma unroll
        for (int j = 0; j < 4; j++) acc[i][j] += a[i] * bb[j];
    }
    if (blockIdx.x == 0 && (tid >> 4) == 0) {
      #pragma unroll
      for (int j = 0; j < 4; j++) {
        float s = 0.f;
        for (int nn = 0; nn < 32; nn++) s += vs[nn][te + j];
        vloc[j] += s;
      }
    }
    __syncthreads();
  }
  #pragma unroll
  for (int i = 0; i < 4; i++)
    #pragma unroll
    for (int j = 0; j < 4; j++)
      ctxp[(size_t)blockIdx.z * 262144 + (size_t)bh * 16384 +
           (size_t)(f0 + tf + i) * 64 + te + j] = acc[i][j];
  if (blockIdx.x == 0 && (tid >> 4) == 0) {
    #pragma unroll
    for (int j = 0; j < 4; j++)
      vsump[((size_t)blockIdx.z * 16 + bh) * 64 + te + j] = vloc[j];
  }
}

// ============ ctx reduce + affine + transpose -> ctxT bf16 [bh][e=64][f=256]
__global__ __launch_bounds__(256)
void ctx_reduce_kernel(const float* __restrict__ ctxp, const float* __restrict__ vsump,
                       const float* __restrict__ gmax, short* __restrict__ ctxT) {
  __shared__ float T[64][65];
  int ftile = blockIdx.x, bh = blockIdx.y;
  int tid = threadIdx.x;
  int e = tid & 63, q = tid >> 6;
  float s = expf(-gmax[0]);
  float vsum_e = 0.f;
  #pragma unroll
  for (int c = 0; c < 8; ++c) vsum_e += vsump[((size_t)c * 16 + bh) * 64 + e];
  #pragma unroll
  for (int i = 0; i < 16; ++i) {
    int fl = i * 4 + q;
    size_t idx = (size_t)bh * 16384 + (size_t)(ftile * 64 + fl) * 64 + e;
    float sum = 0.f;
    #pragma unroll
    for (int c = 0; c < 8; ++c) sum += ctxp[(size_t)c * 262144 + idx];
    T[fl][e] = RATIO * (s * sum + FEPS * vsum_e);
  }
  __syncthreads();
  #pragma unroll
  for (int i = 0; i < 16; ++i) {
    int er = i * 4 + q;
    ctxT[(size_t)bh * 16384 + (size_t)er * 256 + ftile * 64 + e] = f2b(T[e][er]);
  }
}

// ============ PV via MFMA: aob = Dinv * (qfb @ ctxT^T), per bh
__global__ __launch_bounds__(256)
void pv_mfma_kernel(const short* __restrict__ qfb, const short* __restrict__ ctxT,
                    const float* __restrict__ Dinv, short* __restrict__ aob) {
  __shared__ short As[128 * 64];
  __shared__ short Bs[64 * 64];
  int bh = blockIdx.y, b = bh >> 3, h = bh & 7;
  int n0 = blockIdx.x * 128;
  int tid = threadIdx.x;
  int lane = tid & 63, wave = tid >> 6;
  int srow = tid >> 3, scol = (tid & 7) * 8;

  f32x4 acc[2][4] = {};
  for (int k0 = 0; k0 < NF; k0 += 64) {
    #pragma unroll
    for (int c = 0; c < 4; ++c) {
      int r = c * 32 + srow;
      gload16(qfb + (size_t)(b * N_TOK + n0 + r) * HF + h * NF + k0 + scol,
              As + c * 2048 + wave * 512);
    }
    #pragma unroll
    for (int c = 0; c < 2; ++c) {
      int r = c * 32 + srow;
      gload16(ctxT + (size_t)bh * 16384 + (size_t)r * 256 + k0 + scol,
              Bs + c * 2048 + wave * 512);
    }
    __syncthreads();
    #pragma unroll
    for (int kk = 0; kk < 2; ++kk) {
      bf16x8 af[2], bf[4];
      int kq = kk * 32 + (lane >> 4) * 8;
      #pragma unroll
      for (int i = 0; i < 2; ++i)
        af[i] = *(const bf16x8*)&As[(wave * 32 + i * 16 + (lane & 15)) * 64 + kq];
      #pragma unroll
      for (int j = 0; j < 4; ++j)
        bf[j] = *(const bf16x8*)&Bs[(j * 16 + (lane & 15)) * 64 + kq];
      #pragma unroll
      for (int i = 0; i < 2; ++i)
        #pragma unroll
        for (int j = 0; j < 4; ++j)
          acc[i][j] = __builtin_amdgcn_mfma_f32_16x16x32_bf16(af[i], bf[j], acc[i][j], 0, 0, 0);
    }
    __syncthreads();
  }

  #pragma unroll
  for (int i = 0; i < 2; ++i) {
    #pragma unroll
    for (int j = 0; j < 4; ++j) {
      int e = j * 16 + (lane & 15);
      #pragma unroll
      for (int r = 0; r < 4; ++r) {
        int n = n0 + wave * 32 + i * 16 + (lane >> 4) * 4 + r;
        float dv = Dinv[bh * N_TOK + n];
        aob[(size_t)(b * N_TOK + n) * DM + h * DHH + e] = f2b(acc[i][j][r] * dv);
      }
    }
  }
}

// ============ LayerNorm over D=512
template<bool OUT_BF16>
__global__ void ln_kernel(const float* __restrict__ x, const float* __restrict__ g,
                          const float* __restrict__ beta, void* __restrict__ y) {
  int row = blockIdx.x, t = threadIdx.x;
  __shared__ float red[4];
  __shared__ float bcast[2];
  const float* xr = x + (size_t)row * DM;
  float v0 = xr[t], v1 = xr[t + 256];
  float s = v0 + v1;
  #pragma unroll
  for (int o = 32; o > 0; o >>= 1) s += __shfl_xor(s, o, 64);
  if ((t & 63) == 0) red[t >> 6] = s;
  __syncthreads();
  if (t == 0) bcast[0] = (red[0] + red[1] + red[2] + red[3]) * (1.0f / 512.0f);
  __syncthreads();
  float mean = bcast[0];
  float d0 = v0 - mean, d1 = v1 - mean;
  float s2 = d0 * d0 + d1 * d1;
  #pragma unroll
  for (int o = 32; o > 0; o >>= 1) s2 += __shfl_xor(s2, o, 64);
  if ((t & 63) == 0) red[t >> 6] = s2;
  __syncthreads();
  if (t == 0) bcast[1] = (red[0] + red[1] + red[2] + red[3]) * (1.0f / 512.0f);
  __syncthreads();
  float inv = rsqrtf(bcast[1] + LN_EPS);
  float o0 = g[t] * d0 * inv + beta[t];
  float o1 = g[t + 256] * d1 * inv + beta[t + 256];
  if (OUT_BF16) {
    ((short*)y)[(size_t)row * DM + t] = f2b(o0);
    ((short*)y)[(size_t)row * DM + t + 256] = f2b(o1);
  } else {
    ((float*)y)[(size_t)row * DM + t] = o0;
    ((float*)y)[(size_t)row * DM + t + 256] = o1;
  }
}

extern "C" void kernel_launch(void* const* d_in, const int* in_sizes, int n_in,
                              void* d_out, int out_size, void* d_ws, size_t ws_size,
                              hipStream_t stream) {
  const float* x     = (const float*)d_in[0];
  const float* Wq    = (const float*)d_in[1];
  const float* bq    = (const float*)d_in[2];
  const float* Wk    = (const float*)d_in[3];
  const float* bk    = (const float*)d_in[4];
  const float* Wv    = (const float*)d_in[5];
  const float* bv    = (const float*)d_in[6];
  const float* Wo    = (const float*)d_in[7];
  const float* bo    = (const float*)d_in[8];
  const float* proj  = (const float*)d_in[9];
  const float* W1    = (const float*)d_in[10];
  const float* b1    = (const float*)d_in[11];
  const float* W2    = (const float*)d_in[12];
  const float* b2    = (const float*)d_in[13];
  const float* g1    = (const float*)d_in[14];
  const float* beta1 = (const float*)d_in[15];
  const float* g2    = (const float*)d_in[16];
  const float* beta2 = (const float*)d_in[17];

  float* ws = (float*)d_ws;
  float* y_out = (float*)d_out;
  float* attnw = y_out + (size_t)B_SZ * N_TOK * DM;

  float* ctxp  = ws + OFF_CTXP;
  short* qb    = (short*)(ws + OFF_QB);
  float* out2  = ws + OFF_OUT2;
  short* ff1b  = (short*)(ws + OFF_FF1B);
  float* ff2   = ws + OFF_FF2;
  short* qfb   = (short*)(ws + OFF_QFB);
  short* xb    = (short*)(ws + OFF_QFB);      // before qfb written
  short* kb    = (short*)(ws + OFF_KB);       // kb' = exp(dd - diag)
  short* Wqkvt = (short*)(ws + OFF_KB);       // before kb written
  float* QKVlin = ws + OFF_QKV;
  short* aob   = (short*)(ws + OFF_AOB);
  short* h1b   = (short*)(ws + OFF_H1B);
  short* Wot   = (short*)(ws + OFF_WOT);
  short* W1t   = (short*)(ws + OFF_W1T);
  short* W2t   = (short*)(ws + OFF_W2T);
  float* ksum  = ws + OFF_KSUM;
  float* Dinv  = ws + OFF_DINV;
  short* ctxT  = (short*)(ws + OFF_CTXT);
  float* bmax  = ws + OFF_BMAX;
  float* gmax  = ws + OFF_GMAX;
  float* rowc  = ws + OFF_ROWC;
  float* part  = ws + OFF_PART;
  float* vsump = ws + OFF_VSUMP;

  dim3 blk(256);
  int MT = B_SZ * N_TOK;

  // 0) prep: cvt + all weight transposes (1 launch)
  prep_kernel<<<1792, blk, 0, stream>>>(x, xb, Wq, Wk, Wv, Wo,
                                        Wqkvt, Wqkvt + 262144, Wqkvt + 524288, Wot,
                                        W1, W1t, W2, W2t);

  // 1) fused QKV projection (bias deferred): QKVlin [4096,1536] fp32
  gemm_mfma<false, false, 0, false><<<dim3(LDQKV / 128, MT / 128, 1), blk, 0, stream>>>(
      xb, Wqkvt, nullptr, QKVlin, MT, LDQKV, DM, 0, 0, 0, LDQKV);

  // 2) feature maps: Q final bf16; K raw e=exp(dd-diag) bf16 + col-sum partials + bmax
  feat_mfma_kernel<true><<<dim3(N_TOK / 64, B_SZ * NH), blk, 0, stream>>>(
      QKVlin, 0, bq, proj, qfb, nullptr, nullptr);
  feat_mfma_kernel<false><<<dim3(N_TOK / 64, B_SZ * NH), blk, 0, stream>>>(
      QKVlin, 512, bk, proj, kb, part, bmax);

  // 3) ksum finalize (affine, writes m), then fused D_inv + q-scale + rowc
  ksum_final_kernel<<<B_SZ * NH, blk, 0, stream>>>(part, bmax, ksum, gmax);
  dinvqs_kernel<<<MT, blk, 0, stream>>>(qfb, ksum, gmax, Dinv, rowc, qb);

  // 4) linear attention: split-K ctx (affine in reduce), then MFMA pv
  ctx_part_kernel<<<dim3(NF / 64, B_SZ * NH, 8), blk, 0, stream>>>(kb, QKVlin, bv, ctxp, vsump);
  ctx_reduce_kernel<<<dim3(4, B_SZ * NH), blk, 0, stream>>>(ctxp, vsump, gmax, ctxT);
  pv_mfma_kernel<<<dim3(N_TOK / 128, B_SZ * NH), blk, 0, stream>>>(qfb, ctxT, Dinv, aob);

  // 5) attn-weight output: GEMM(qb, kb') + per-row FEPS constant
  gemm_mfma<false, false, 2, true><<<dim3(16, 16, 2), blk, 0, stream>>>(
      qb, kb, rowc, attnw, N_TOK, N_TOK, HF,
      (size_t)N_TOK * HF, (size_t)N_TOK * HF, (size_t)N_TOK * N_TOK, N_TOK);

  // 6) Wo projection (BN64: 256 blocks)
  gemm_bn64<false, false><<<dim3(DM / 64, MT / 128), blk, 0, stream>>>(
      aob, Wot, bo, out2, MT, DM, DM);

  // 7) FFN
  ln_kernel<true><<<MT, blk, 0, stream>>>(out2, g1, beta1, h1b);
  gemm_mfma<true, true, 1, false><<<dim3(16, 32, 1), blk, 0, stream>>>(
      h1b, W1t, b1, ff1b, MT, DFF, DM, 0, 0, 0, DFF);
  gemm_bn64<false, false><<<dim3(DM / 64, MT / 128), blk, 0, stream>>>(
      ff1b, W2t, b2, ff2, MT, DM, DFF);
  ln_kernel<false><<<MT, blk, 0, stream>>>(ff2, g2, beta2, y_out);
}

// Round 7
// 250.129 us; speedup vs baseline: 5.9923x; 1.0538x over previous
//
#include <hip/hip_runtime.h>
#include <math.h>

// Problem constants
#define B_SZ   2
#define N_TOK  2048
#define DM     512
#define NH     8
#define DHH    64
#define NF     256
#define DFF    2048
#define HF     2048    // NH*NF
#define LDQKV  1536    // fused QKV row stride

constexpr float DN_SCALE   = 0.35355339059327373f; // 64^-0.25
constexpr float DIAG_SCALE = 0.0625f;              // 0.5 * dn^2
constexpr float RATIO      = 0.0625f;              // 256^-0.5
constexpr float FEPS       = 1e-4f;
constexpr float LN_EPS     = 1e-5f;

typedef __attribute__((ext_vector_type(8))) short bf16x8;
typedef __attribute__((ext_vector_type(8))) _Float16 f16x8;
typedef __attribute__((ext_vector_type(4))) float f32x4;

__device__ __forceinline__ short f2b(float f) {
  union { float f; unsigned u; } x; x.f = f;
  unsigned r = (x.u + 0x7fff + ((x.u >> 16) & 1)) >> 16;
  return (short)r;
}
__device__ __forceinline__ float b2f(short s) {
  union { unsigned u; float f; } x; x.u = ((unsigned)(unsigned short)s) << 16;
  return x.f;
}
__device__ __forceinline__ void gload16(const void* g, void* l) {
  __builtin_amdgcn_global_load_lds((const __attribute__((address_space(1))) void*)g,
                                   (__attribute__((address_space(3))) void*)l, 16, 0, 0);
}
__device__ __forceinline__ int swz64(int row, int kbyte) {
  return (row * 128 + kbyte) ^ ((row & 7) << 4);
}
// all-block-uniform max over bmax[512]; needs 256 threads
__device__ __forceinline__ float reduce_bmax512(const float* __restrict__ bmax,
                                                float* __restrict__ red) {
  int t = threadIdx.x;
  float m = fmaxf(bmax[t], bmax[t + 256]);
  #pragma unroll
  for (int o = 1; o < 64; o <<= 1) m = fmaxf(m, __shfl_xor(m, o, 64));
  if ((t & 63) == 0) red[t >> 6] = m;
  __syncthreads();
  float r = fmaxf(fmaxf(red[0], red[1]), fmaxf(red[2], red[3]));
  __syncthreads();
  return r;
}

// Workspace layout (float-offset units)
constexpr size_t OFF_CTXP  = 0;              // fp32 8x[16][256][64] = 2097152
constexpr size_t OFF_QB    = 4194304;        // bf16 [2,2048,2048]
constexpr size_t OFF_OUT2  = 0;              // fp32 [4096,512]  (after ctxp dead)
constexpr size_t OFF_FF1B  = 2097152;        // bf16 [4096,2048] (after qb dead)
constexpr size_t OFF_FF2   = 6291456;        // fp32 [4096,512]
constexpr size_t OFF_QFB   = 8388608;        // bf16 [2,2048,2048]; earlier: xb
constexpr size_t OFF_KB    = 12582912;       // bf16 e=exp(dd-diag); earlier: Wqkvt
constexpr size_t OFF_QKV   = 16777216;       // fp32 [4096,1536]
constexpr size_t OFF_AOB   = 20971520;       // bf16 [4096,512]
constexpr size_t OFF_H1B   = 22020096;       // bf16 [4096,512]
constexpr size_t OFF_WOT   = 23068672;       // bf16 [512,512]
constexpr size_t OFF_W1T   = 23199744;       // bf16 [2048,512]
constexpr size_t OFF_W2T   = 23724032;       // bf16 [512,2048]
constexpr size_t OFF_KSUM  = 24248320;       // [16,256] affine-applied
constexpr size_t OFF_DINV  = 24252416;       // [16,2048]
constexpr size_t OFF_CTXT  = 24285184;       // bf16 ctxT [16,64,256]
constexpr size_t OFF_BMAX  = 24416256;       // [512]
constexpr size_t OFF_ROWC  = 24416832;       // [4096]
constexpr size_t OFF_PART  = 24420928;       // [16,32,256] col sums of e
constexpr size_t OFF_VSUMP = 24552000;       // [8,16,64]

// ============ bf16 MFMA GEMM: C = A[M,K] @ Bt[N,K]^T, m97 structure
// BMODE: 0 = none, 1 = column bias
template<bool RELU, bool OUT_BF16, int BMODE>
__global__ __launch_bounds__(256)
void gemm_mfma(const short* __restrict__ A, const short* __restrict__ Bt,
               const float* __restrict__ bias, void* __restrict__ Cout,
               int M, int N, int K, int ldC) {
  __shared__ short As[128 * 64];
  __shared__ short Bs[128 * 64];
  int tid = threadIdx.x;
  int lane = tid & 63, wave = tid >> 6;
  int wm = wave >> 1, wn = wave & 1;
  int bm = blockIdx.y * 128, bn = blockIdx.x * 128;

  f32x4 acc[4][4] = {};
  int srow = tid >> 3;
  int scol = (tid & 7) * 8;

  for (int k0 = 0; k0 < K; k0 += 64) {
    #pragma unroll
    for (int c = 0; c < 4; ++c) {
      int r = c * 32 + srow;
      gload16(A + (size_t)(bm + r) * K + k0 + scol, As + c * 2048 + wave * 512);
      gload16(Bt + (size_t)(bn + r) * K + k0 + scol, Bs + c * 2048 + wave * 512);
    }
    __syncthreads();
    #pragma unroll
    for (int kk = 0; kk < 2; ++kk) {
      bf16x8 af[4], bf[4];
      int kq = kk * 32 + (lane >> 4) * 8;
      #pragma unroll
      for (int i = 0; i < 4; ++i)
        af[i] = *(const bf16x8*)&As[(wm * 64 + i * 16 + (lane & 15)) * 64 + kq];
      #pragma unroll
      for (int j = 0; j < 4; ++j)
        bf[j] = *(const bf16x8*)&Bs[(wn * 64 + j * 16 + (lane & 15)) * 64 + kq];
      #pragma unroll
      for (int i = 0; i < 4; ++i)
        #pragma unroll
        for (int j = 0; j < 4; ++j)
          acc[i][j] = __builtin_amdgcn_mfma_f32_16x16x32_bf16(af[i], bf[j], acc[i][j], 0, 0, 0);
    }
    __syncthreads();
  }

  int row0 = bm + wm * 64, col0 = bn + wn * 64;
  #pragma unroll
  for (int i = 0; i < 4; ++i) {
    #pragma unroll
    for (int j = 0; j < 4; ++j) {
      int col = col0 + j * 16 + (lane & 15);
      float bv = (BMODE == 1) ? bias[col] : 0.f;
      #pragma unroll
      for (int r = 0; r < 4; ++r) {
        int row = row0 + i * 16 + (lane >> 4) * 4 + r;
        float v = acc[i][j][r] + bv;
        if (RELU) v = fmaxf(v, 0.f);
        size_t off = (size_t)row * ldC + col;
        if (OUT_BF16) ((short*)Cout)[off] = f2b(v);
        else          ((float*)Cout)[off] = v;
      }
    }
  }
}

// ============ BN=64 MFMA GEMM: C[M,N] = A[M,K] @ Bt[N,K]^T + bias
template<bool RELU, bool OUT_BF16>
__global__ __launch_bounds__(256)
void gemm_bn64(const short* __restrict__ A, const short* __restrict__ Bt,
               const float* __restrict__ bias, void* __restrict__ Cout,
               int M, int N, int K) {
  __shared__ short As[128 * 64];
  __shared__ short Bs[64 * 64];
  int tid = threadIdx.x, lane = tid & 63, wave = tid >> 6;
  int bn = blockIdx.x * 64, bm = blockIdx.y * 128;
  int srow = tid >> 3, scol = (tid & 7) * 8;
  f32x4 acc[2][4] = {};
  for (int k0 = 0; k0 < K; k0 += 64) {
    #pragma unroll
    for (int c = 0; c < 4; ++c)
      gload16(A + (size_t)(bm + c * 32 + srow) * K + k0 + scol, As + c * 2048 + wave * 512);
    #pragma unroll
    for (int c = 0; c < 2; ++c)
      gload16(Bt + (size_t)(bn + c * 32 + srow) * K + k0 + scol, Bs + c * 2048 + wave * 512);
    __syncthreads();
    #pragma unroll
    for (int kk = 0; kk < 2; ++kk) {
      bf16x8 af[2], bf[4];
      int kq = kk * 32 + (lane >> 4) * 8;
      #pragma unroll
      for (int i = 0; i < 2; ++i)
        af[i] = *(const bf16x8*)&As[(wave * 32 + i * 16 + (lane & 15)) * 64 + kq];
      #pragma unroll
      for (int j = 0; j < 4; ++j)
        bf[j] = *(const bf16x8*)&Bs[(j * 16 + (lane & 15)) * 64 + kq];
      #pragma unroll
      for (int i = 0; i < 2; ++i)
        #pragma unroll
        for (int j = 0; j < 4; ++j)
          acc[i][j] = __builtin_amdgcn_mfma_f32_16x16x32_bf16(af[i], bf[j], acc[i][j], 0, 0, 0);
    }
    __syncthreads();
  }
  #pragma unroll
  for (int i = 0; i < 2; ++i) {
    #pragma unroll
    for (int j = 0; j < 4; ++j) {
      int col = bn + j * 16 + (lane & 15);
      float bv = bias[col];
      #pragma unroll
      for (int r = 0; r < 4; ++r) {
        int row = bm + wave * 32 + i * 16 + (lane >> 4) * 4 + r;
        float v = acc[i][j][r] + bv;
        if (RELU) v = fmaxf(v, 0.f);
        if (OUT_BF16) ((short*)Cout)[(size_t)row * N + col] = f2b(v);
        else          ((float*)Cout)[(size_t)row * N + col] = v;
      }
    }
  }
}

// ============ fused prep: x->bf16 + all 6 weight transposes, one launch
__global__ void prep_kernel(const float* __restrict__ x, short* __restrict__ xb,
                            const float* Wq, const float* Wk, const float* Wv, const float* Wo,
                            short* Wqt, short* Wkt, short* Wvt, short* Wot,
                            const float* W1, short* W1t, const float* W2, short* W2t) {
  __shared__ float t[64][65];
  int id = blockIdx.x, tid = threadIdx.x;
  if (id >= 768) {
    size_t base = ((size_t)(id - 768) * 256 + tid) * 8;
    #pragma unroll
    for (int u = 0; u < 8; ++u) xb[base + u] = f2b(x[base + u]);
    return;
  }
  const float* W; short* Wt; int K, N, bx, by;
  if (id < 256) {
    int z = id >> 6, sub = id & 63;
    W  = (z == 0) ? Wq : (z == 1) ? Wk : (z == 2) ? Wv : Wo;
    Wt = (z == 0) ? Wqt : (z == 1) ? Wkt : (z == 2) ? Wvt : Wot;
    K = 512; N = 512; bx = sub & 7; by = sub >> 3;
  } else if (id < 512) {
    int sub = id - 256;
    W = W1; Wt = W1t; K = 512; N = 2048; bx = sub & 31; by = sub >> 5;
  } else {
    int sub = id - 512;
    W = W2; Wt = W2t; K = 2048; N = 512; bx = sub & 7; by = sub >> 3;
  }
  int k0 = by * 64, n0 = bx * 64;
  int lx = tid & 63, ly = tid >> 6;
  for (int r = ly; r < 64; r += 4)
    t[r][lx] = W[(size_t)(k0 + r) * N + n0 + lx];
  __syncthreads();
  for (int r = ly; r < 64; r += 4)
    Wt[(size_t)(n0 + r) * K + k0 + lx] = f2b(t[lx][r]);
}

// ============ feature maps, Q and K in one launch (z=0: Q, z=1: K)
__global__ __launch_bounds__(256)
void feat_mfma_kernel(const float* __restrict__ qkv, const float* __restrict__ bq,
                      const float* __restrict__ bk, const float* __restrict__ proj,
                      short* __restrict__ qfb, short* __restrict__ kbo,
                      float* __restrict__ part, float* __restrict__ bmax) {
  __shared__ short qh[64 * 64], ql[64 * 64];
  __shared__ short ph[128 * 64], pl[128 * 64];
  __shared__ float dpart[64][4];
  __shared__ float diag[64];
  __shared__ float wred[4];
  __shared__ float colp[4][256];
  int t = threadIdx.x;
  bool isq = (blockIdx.z == 0);
  int coff = isq ? 0 : 512;
  const float* bias = isq ? bq : bk;
  short* qout = isq ? qfb : kbo;
  int bh = blockIdx.y, b = bh >> 3, h = bh & 7;
  int n0 = blockIdx.x * 64;
  int lane = t & 63, w = t >> 6, l15 = lane & 15, lq = lane >> 4;

  {
    int r = t >> 2, cg = (t & 3) * 16;
    const float* src = qkv + (size_t)(b * N_TOK + n0 + r) * LDQKV + coff + h * 64 + cg;
    const float* bs = bias + h * 64 + cg;
    float ss = 0.f;
    #pragma unroll
    for (int c2 = 0; c2 < 2; ++c2) {
      f16x8 H, L;
      #pragma unroll
      for (int u = 0; u < 8; ++u) {
        float xv = src[c2 * 8 + u] + bs[c2 * 8 + u];
        ss += xv * xv;
        _Float16 hi = (_Float16)xv;
        H[u] = hi;
        L[u] = (_Float16)(xv - (float)hi);
      }
      int off = swz64(r, cg * 2 + c2 * 16);
      *(f16x8*)((char*)qh + off) = H;
      *(f16x8*)((char*)ql + off) = L;
    }
    dpart[r][t & 3] = ss;
  }
  __syncthreads();
  if (t < 64)
    diag[t] = (dpart[t][0] + dpart[t][1] + dpart[t][2] + dpart[t][3]) * DIAG_SCALE;

  f16x8 ah[2], al[2];
  #pragma unroll
  for (int kk = 0; kk < 2; ++kk) {
    int off = swz64(w * 16 + l15, kk * 64 + lq * 16);
    ah[kk] = *(f16x8*)((char*)qh + off);
    al[kk] = *(f16x8*)((char*)ql + off);
  }

  f32x4 acc[16] = {};
  #pragma unroll
  for (int half = 0; half < 2; ++half) {
    __syncthreads();
    {
      int r = t & 127, cg = (t >> 7) * 32;
      const float* src = proj + (size_t)(half * 128 + r) * DHH + cg;
      #pragma unroll
      for (int c2 = 0; c2 < 4; ++c2) {
        f16x8 H, L;
        #pragma unroll
        for (int u = 0; u < 8; ++u) {
          float xv = src[c2 * 8 + u];
          _Float16 hi = (_Float16)xv;
          H[u] = hi;
          L[u] = (_Float16)(xv - (float)hi);
        }
        int off = swz64(r, cg * 2 + c2 * 16);
        *(f16x8*)((char*)ph + off) = H;
        *(f16x8*)((char*)pl + off) = L;
      }
    }
    __syncthreads();
    #pragma unroll
    for (int jl = 0; jl < 8; ++jl) {
      int row = jl * 16 + l15;
      #pragma unroll
      for (int kk = 0; kk < 2; ++kk) {
        int off = swz64(row, kk * 64 + lq * 16);
        f16x8 bh8 = *(f16x8*)((char*)ph + off);
        f16x8 bl8 = *(f16x8*)((char*)pl + off);
        acc[half * 8 + jl] = __builtin_amdgcn_mfma_f32_16x16x32_f16(ah[kk], bh8, acc[half * 8 + jl], 0, 0, 0);
        acc[half * 8 + jl] = __builtin_amdgcn_mfma_f32_16x16x32_f16(al[kk], bh8, acc[half * 8 + jl], 0, 0, 0);
        acc[half * 8 + jl] = __builtin_amdgcn_mfma_f32_16x16x32_f16(ah[kk], bl8, acc[half * 8 + jl], 0, 0, 0);
      }
    }
  }

  if (isq) {
    #pragma unroll
    for (int r = 0; r < 4; ++r) {
      float mx = -3.4e38f;
      #pragma unroll
      for (int j = 0; j < 16; ++j) mx = fmaxf(mx, acc[j][r]);
      #pragma unroll
      for (int o = 1; o < 16; o <<= 1) mx = fmaxf(mx, __shfl_xor(mx, o, 64));
      int lrow = w * 16 + lq * 4 + r;
      float dg = diag[lrow];
      float ddm = mx * DN_SCALE;
      size_t base = (size_t)(b * N_TOK + n0 + lrow) * HF + h * NF + l15;
      #pragma unroll
      for (int j = 0; j < 16; ++j) {
        float v = RATIO * (expf(acc[j][r] * DN_SCALE - dg - ddm) + FEPS);
        qout[base + j * 16] = f2b(v);
      }
    }
  } else {
    float mxall = -3.4e38f;
    float cs[16];
    #pragma unroll
    for (int j = 0; j < 16; ++j) cs[j] = 0.f;
    #pragma unroll
    for (int r = 0; r < 4; ++r) {
      int lrow = w * 16 + lq * 4 + r;
      float dg = diag[lrow];
      size_t base = (size_t)(b * N_TOK + n0 + lrow) * HF + h * NF + l15;
      #pragma unroll
      for (int j = 0; j < 16; ++j) {
        float a = acc[j][r];
        mxall = fmaxf(mxall, a);
        float e = expf(a * DN_SCALE - dg);
        cs[j] += e;
        qout[base + j * 16] = f2b(e);
      }
    }
    #pragma unroll
    for (int j = 0; j < 16; ++j) {
      cs[j] += __shfl_xor(cs[j], 16, 64);
      cs[j] += __shfl_xor(cs[j], 32, 64);
    }
    if (lq == 0) {
      #pragma unroll
      for (int j = 0; j < 16; ++j) colp[w][j * 16 + l15] = cs[j];
    }
    #pragma unroll
    for (int o = 1; o < 64; o <<= 1) mxall = fmaxf(mxall, __shfl_xor(mxall, o, 64));
    if (lane == 0) wred[w] = mxall;
    __syncthreads();
    part[(size_t)(bh * 32 + blockIdx.x) * 256 + t] =
        colp[0][t] + colp[1][t] + colp[2][t] + colp[3][t];
    if (t == 0)
      bmax[bh * 32 + blockIdx.x] =
          fmaxf(fmaxf(wred[0], wred[1]), fmaxf(wred[2], wred[3])) * DN_SCALE;
  }
}

// ============ ctx partial over 256-row n-chunks; x-block 0 also sums V columns
__global__ __launch_bounds__(256)
void ctx_part_kernel(const short* __restrict__ kb, const float* __restrict__ qkv,
                     const float* __restrict__ bv, float* __restrict__ ctxp,
                     float* __restrict__ vsump) {
  int bh = blockIdx.y, b = bh >> 3, h = bh & 7;
  int f0 = blockIdx.x * 64;
  int ns = blockIdx.z * 256;
  __shared__ float kf[32][68];
  __shared__ float vs[32][68];
  int tid = threadIdx.x;
  int tf = (tid >> 4) * 4, te = (tid & 15) * 4;
  float acc[4][4] = {};
  float vloc[4] = {};
  for (int n0 = ns; n0 < ns + 256; n0 += 32) {
    #pragma unroll
    for (int i = 0; i < 8; i++) {
      int idx = tid + i * 256;
      int nn = idx >> 6, f = idx & 63;
      kf[nn][f] = b2f(kb[(size_t)(b * N_TOK + n0 + nn) * HF + h * NF + f0 + f]);
    }
    #pragma unroll
    for (int i = 0; i < 8; i++) {
      int idx = tid + i * 256;
      int nn = idx >> 6, e = idx & 63;
      vs[nn][e] = qkv[(size_t)(b * N_TOK + n0 + nn) * LDQKV + 1024 + h * DHH + e] + bv[h * DHH + e];
    }
    __syncthreads();
    #pragma unroll
    for (int nn = 0; nn < 32; nn++) {
      float a[4], bb[4];
      #pragma unroll
      for (int i = 0; i < 4; i++) a[i] = kf[nn][tf + i];
      #pragma unroll
      for (int j = 0; j < 4; j++) bb[j] = vs[nn][te + j];
      #pragma unroll
      for (int i = 0; i < 4; i++)
        #pragma unroll
        for (int j = 0; j < 4; j++) acc[i][j] += a[i] * bb[j];
    }
    if (blockIdx.x == 0 && (tid >> 4) == 0) {
      #pragma unroll
      for (int j = 0; j < 4; j++) {
        float s = 0.f;
        for (int nn = 0; nn < 32; nn++) s += vs[nn][te + j];
        vloc[j] += s;
      }
    }
    __syncthreads();
  }
  #pragma unroll
  for (int i = 0; i < 4; i++)
    #pragma unroll
    for (int j = 0; j < 4; j++)
      ctxp[(size_t)blockIdx.z * 262144 + (size_t)bh * 16384 +
           (size_t)(f0 + tf + i) * 64 + te + j] = acc[i][j];
  if (blockIdx.x == 0 && (tid >> 4) == 0) {
    #pragma unroll
    for (int j = 0; j < 4; j++)
      vsump[((size_t)blockIdx.z * 16 + bh) * 64 + te + j] = vloc[j];
  }
}

// ============ small fat: blocks 0..15 = ksum finalize; 16..79 = ctx reduce+transpose
__global__ __launch_bounds__(256)
void smallfat_kernel(const float* __restrict__ part, const float* __restrict__ bmax,
                     float* __restrict__ ksum, const float* __restrict__ ctxp,
                     const float* __restrict__ vsump, short* __restrict__ ctxT) {
  __shared__ float T[64][65];
  __shared__ float red[4];
  int t = threadIdx.x;
  float m = reduce_bmax512(bmax, red);
  float s = expf(-m);
  if (blockIdx.x < 16) {
    int bh = blockIdx.x;
    float sum = 0.f;
    #pragma unroll 8
    for (int c = 0; c < 32; ++c) sum += part[(size_t)(bh * 32 + c) * 256 + t];
    ksum[bh * 256 + t] = RATIO * (s * sum + (float)N_TOK * FEPS);
  } else {
    int id = blockIdx.x - 16;
    int ftile = id & 3, bh = id >> 2;
    int e = t & 63, q = t >> 6;
    float vsum_e = 0.f;
    #pragma unroll
    for (int c = 0; c < 8; ++c) vsum_e += vsump[((size_t)c * 16 + bh) * 64 + e];
    #pragma unroll
    for (int i = 0; i < 16; ++i) {
      int fl = i * 4 + q;
      size_t idx = (size_t)bh * 16384 + (size_t)(ftile * 64 + fl) * 64 + e;
      float sum = 0.f;
      #pragma unroll
      for (int c = 0; c < 8; ++c) sum += ctxp[(size_t)c * 262144 + idx];
      T[fl][e] = RATIO * (s * sum + FEPS * vsum_e);
    }
    __syncthreads();
    #pragma unroll
    for (int i = 0; i < 16; ++i) {
      int er = i * 4 + q;
      ctxT[(size_t)bh * 16384 + (size_t)er * 256 + ftile * 64 + e] = f2b(T[e][er]);
    }
  }
}

// ============ fused D_inv + q-scale + row constant (local bmax reduce)
__global__ __launch_bounds__(256)
void dinvqs_kernel(const short* __restrict__ qfb, const float* __restrict__ ksum,
                   const float* __restrict__ bmax, float* __restrict__ Dinv,
                   float* __restrict__ rowc, short* __restrict__ qb) {
  __shared__ float red[4];
  __shared__ float wsum[4];
  int R = blockIdx.x;
  int b = R >> 11, n = R & 2047;
  int t = threadIdx.x;
  float m = reduce_bmax512(bmax, red);
  float sc = RATIO * expf(-m);
  bf16x8 qv = *(const bf16x8*)(qfb + (size_t)R * HF + t * 8);
  const float* ks = ksum + b * 2048 + t * 8;
  float p = 0.f;
  #pragma unroll
  for (int u = 0; u < 8; ++u) p += b2f(qv[u]) * ks[u];
  #pragma unroll
  for (int o = 1; o < 32; o <<= 1) p += __shfl_xor(p, o, 64);
  float d = 1.0f / p;
  if ((t & 31) == 0) Dinv[(b * NH + (t >> 5)) * N_TOK + n] = d;
  float dv = d * 0.125f;
  float qs = 0.f;
  bf16x8 o8;
  #pragma unroll
  for (int u = 0; u < 8; ++u) {
    float qb_f = b2f(qv[u]) * dv;
    qs += qb_f;
    o8[u] = f2b(qb_f * sc);
  }
  *(bf16x8*)(qb + (size_t)R * HF + t * 8) = o8;
  #pragma unroll
  for (int o = 1; o < 64; o <<= 1) qs += __shfl_xor(qs, o, 64);
  if ((t & 63) == 0) wsum[t >> 6] = qs;
  __syncthreads();
  if (t == 0) rowc[R] = RATIO * FEPS * (wsum[0] + wsum[1] + wsum[2] + wsum[3]);
}

// ============ FAT: blocks 0..511 = attnw GEMM (z b = bid>>8); 512..767 = pv MFMA
__global__ __launch_bounds__(256)
void fat_attnw_pv(const short* __restrict__ qb, const short* __restrict__ kb,
                  const float* __restrict__ rowc, float* __restrict__ attnw,
                  const short* __restrict__ qfb, const short* __restrict__ ctxT,
                  const float* __restrict__ Dinv, short* __restrict__ aob) {
  __shared__ short As[128 * 64];
  __shared__ short Bs[128 * 64];
  int bid = blockIdx.x;
  int tid = threadIdx.x;
  int lane = tid & 63, wave = tid >> 6;
  int srow = tid >> 3, scol = (tid & 7) * 8;

  if (bid < 512) {
    // ---- attnw: C[z] = qb[z] @ kb[z]^T + rowc[z][row], fp32 out
    int z = bid >> 8;
    int flat = bid & 255;
    // 4x4 super-tile walk for LLC locality
    int tile = flat >> 4, wi = flat & 15;
    int by = (tile >> 2) * 4 + (wi >> 2);
    int bx = (tile & 3) * 4 + (wi & 3);
    int bm = by * 128, bn = bx * 128;
    const short* Ab = qb + (size_t)z * N_TOK * HF;
    const short* Bb = kb + (size_t)z * N_TOK * HF;
    const float* rc = rowc + (size_t)z * N_TOK;
    float* out = attnw + (size_t)z * N_TOK * N_TOK;
    int wm = wave >> 1, wn = wave & 1;

    f32x4 acc[4][4] = {};
    for (int k0 = 0; k0 < HF; k0 += 64) {
      #pragma unroll
      for (int c = 0; c < 4; ++c) {
        int r = c * 32 + srow;
        gload16(Ab + (size_t)(bm + r) * HF + k0 + scol, As + c * 2048 + wave * 512);
        gload16(Bb + (size_t)(bn + r) * HF + k0 + scol, Bs + c * 2048 + wave * 512);
      }
      __syncthreads();
      #pragma unroll
      for (int kk = 0; kk < 2; ++kk) {
        bf16x8 af[4], bf[4];
        int kq = kk * 32 + (lane >> 4) * 8;
        #pragma unroll
        for (int i = 0; i < 4; ++i)
          af[i] = *(const bf16x8*)&As[(wm * 64 + i * 16 + (lane & 15)) * 64 + kq];
        #pragma unroll
        for (int j = 0; j < 4; ++j)
          bf[j] = *(const bf16x8*)&Bs[(wn * 64 + j * 16 + (lane & 15)) * 64 + kq];
        #pragma unroll
        for (int i = 0; i < 4; ++i)
          #pragma unroll
          for (int j = 0; j < 4; ++j)
            acc[i][j] = __builtin_amdgcn_mfma_f32_16x16x32_bf16(af[i], bf[j], acc[i][j], 0, 0, 0);
      }
      __syncthreads();
    }
    int row0 = bm + wm * 64, col0 = bn + wn * 64;
    #pragma unroll
    for (int i = 0; i < 4; ++i) {
      #pragma unroll
      for (int j = 0; j < 4; ++j) {
        int col = col0 + j * 16 + (lane & 15);
        #pragma unroll
        for (int r = 0; r < 4; ++r) {
          int row = row0 + i * 16 + (lane >> 4) * 4 + r;
          out[(size_t)row * N_TOK + col] = acc[i][j][r] + rc[row];
        }
      }
    }
  } else {
    // ---- pv: aob = Dinv * (qfb @ ctxT^T), per bh
    int pid = bid - 512;
    int bx = pid & 15, bh = pid >> 4;
    int b = bh >> 3, h = bh & 7;
    int n0 = bx * 128;

    f32x4 acc[2][4] = {};
    for (int k0 = 0; k0 < NF; k0 += 64) {
      #pragma unroll
      for (int c = 0; c < 4; ++c) {
        int r = c * 32 + srow;
        gload16(qfb + (size_t)(b * N_TOK + n0 + r) * HF + h * NF + k0 + scol,
                As + c * 2048 + wave * 512);
      }
      #pragma unroll
      for (int c = 0; c < 2; ++c) {
        int r = c * 32 + srow;
        gload16(ctxT + (size_t)bh * 16384 + (size_t)r * 256 + k0 + scol,
                Bs + c * 2048 + wave * 512);
      }
      __syncthreads();
      #pragma unroll
      for (int kk = 0; kk < 2; ++kk) {
        bf16x8 af[2], bf[4];
        int kq = kk * 32 + (lane >> 4) * 8;
        #pragma unroll
        for (int i = 0; i < 2; ++i)
          af[i] = *(const bf16x8*)&As[(wave * 32 + i * 16 + (lane & 15)) * 64 + kq];
        #pragma unroll
        for (int j = 0; j < 4; ++j)
          bf[j] = *(const bf16x8*)&Bs[(j * 16 + (lane & 15)) * 64 + kq];
        #pragma unroll
        for (int i = 0; i < 2; ++i)
          #pragma unroll
          for (int j = 0; j < 4; ++j)
            acc[i][j] = __builtin_amdgcn_mfma_f32_16x16x32_bf16(af[i], bf[j], acc[i][j], 0, 0, 0);
      }
      __syncthreads();
    }
    #pragma unroll
    for (int i = 0; i < 2; ++i) {
      #pragma unroll
      for (int j = 0; j < 4; ++j) {
        int e = j * 16 + (lane & 15);
        #pragma unroll
        for (int r = 0; r < 4; ++r) {
          int n = n0 + wave * 32 + i * 16 + (lane >> 4) * 4 + r;
          float dv = Dinv[bh * N_TOK + n];
          aob[(size_t)(b * N_TOK + n) * DM + h * DHH + e] = f2b(acc[i][j][r] * dv);
        }
      }
    }
  }
}

// ============ LayerNorm over D=512
template<bool OUT_BF16>
__global__ void ln_kernel(const float* __restrict__ x, const float* __restrict__ g,
                          const float* __restrict__ beta, void* __restrict__ y) {
  int row = blockIdx.x, t = threadIdx.x;
  __shared__ float red[4];
  __shared__ float bcast[2];
  const float* xr = x + (size_t)row * DM;
  float v0 = xr[t], v1 = xr[t + 256];
  float s = v0 + v1;
  #pragma unroll
  for (int o = 32; o > 0; o >>= 1) s += __shfl_xor(s, o, 64);
  if ((t & 63) == 0) red[t >> 6] = s;
  __syncthreads();
  if (t == 0) bcast[0] = (red[0] + red[1] + red[2] + red[3]) * (1.0f / 512.0f);
  __syncthreads();
  float mean = bcast[0];
  float d0 = v0 - mean, d1 = v1 - mean;
  float s2 = d0 * d0 + d1 * d1;
  #pragma unroll
  for (int o = 32; o > 0; o >>= 1) s2 += __shfl_xor(s2, o, 64);
  if ((t & 63) == 0) red[t >> 6] = s2;
  __syncthreads();
  if (t == 0) bcast[1] = (red[0] + red[1] + red[2] + red[3]) * (1.0f / 512.0f);
  __syncthreads();
  float inv = rsqrtf(bcast[1] + LN_EPS);
  float o0 = g[t] * d0 * inv + beta[t];
  float o1 = g[t + 256] * d1 * inv + beta[t + 256];
  if (OUT_BF16) {
    ((short*)y)[(size_t)row * DM + t] = f2b(o0);
    ((short*)y)[(size_t)row * DM + t + 256] = f2b(o1);
  } else {
    ((float*)y)[(size_t)row * DM + t] = o0;
    ((float*)y)[(size_t)row * DM + t + 256] = o1;
  }
}

extern "C" void kernel_launch(void* const* d_in, const int* in_sizes, int n_in,
                              void* d_out, int out_size, void* d_ws, size_t ws_size,
                              hipStream_t stream) {
  const float* x     = (const float*)d_in[0];
  const float* Wq    = (const float*)d_in[1];
  const float* bq    = (const float*)d_in[2];
  const float* Wk    = (const float*)d_in[3];
  const float* bk    = (const float*)d_in[4];
  const float* Wv    = (const float*)d_in[5];
  const float* bv    = (const float*)d_in[6];
  const float* Wo    = (const float*)d_in[7];
  const float* bo    = (const float*)d_in[8];
  const float* proj  = (const float*)d_in[9];
  const float* W1    = (const float*)d_in[10];
  const float* b1    = (const float*)d_in[11];
  const float* W2    = (const float*)d_in[12];
  const float* b2    = (const float*)d_in[13];
  const float* g1    = (const float*)d_in[14];
  const float* beta1 = (const float*)d_in[15];
  const float* g2    = (const float*)d_in[16];
  const float* beta2 = (const float*)d_in[17];

  float* ws = (float*)d_ws;
  float* y_out = (float*)d_out;
  float* attnw = y_out + (size_t)B_SZ * N_TOK * DM;

  float* ctxp  = ws + OFF_CTXP;
  short* qb    = (short*)(ws + OFF_QB);
  float* out2  = ws + OFF_OUT2;
  short* ff1b  = (short*)(ws + OFF_FF1B);
  float* ff2   = ws + OFF_FF2;
  short* qfb   = (short*)(ws + OFF_QFB);
  short* xb    = (short*)(ws + OFF_QFB);      // before qfb written
  short* kb    = (short*)(ws + OFF_KB);       // e = exp(dd - diag)
  short* Wqkvt = (short*)(ws + OFF_KB);       // before kb written
  float* QKVlin = ws + OFF_QKV;
  short* aob   = (short*)(ws + OFF_AOB);
  short* h1b   = (short*)(ws + OFF_H1B);
  short* Wot   = (short*)(ws + OFF_WOT);
  short* W1t   = (short*)(ws + OFF_W1T);
  short* W2t   = (short*)(ws + OFF_W2T);
  float* ksum  = ws + OFF_KSUM;
  float* Dinv  = ws + OFF_DINV;
  short* ctxT  = (short*)(ws + OFF_CTXT);
  float* bmax  = ws + OFF_BMAX;
  float* rowc  = ws + OFF_ROWC;
  float* part  = ws + OFF_PART;
  float* vsump = ws + OFF_VSUMP;

  dim3 blk(256);
  int MT = B_SZ * N_TOK;

  // 0) prep: cvt + all weight transposes
  prep_kernel<<<1792, blk, 0, stream>>>(x, xb, Wq, Wk, Wv, Wo,
                                        Wqkvt, Wqkvt + 262144, Wqkvt + 524288, Wot,
                                        W1, W1t, W2, W2t);

  // 1) fused QKV projection: QKVlin [4096,1536] fp32 (biases deferred)
  gemm_mfma<false, false, 0><<<dim3(LDQKV / 128, MT / 128), blk, 0, stream>>>(
      xb, Wqkvt, nullptr, QKVlin, MT, LDQKV, DM, LDQKV);

  // 2) feature maps Q+K in one launch
  feat_mfma_kernel<<<dim3(N_TOK / 64, B_SZ * NH, 2), blk, 0, stream>>>(
      QKVlin, bq, bk, proj, qfb, kb, part, bmax);

  // 3) ctx partials (needs only kb + V)
  ctx_part_kernel<<<dim3(NF / 64, B_SZ * NH, 8), blk, 0, stream>>>(kb, QKVlin, bv, ctxp, vsump);

  // 4) ksum finalize + ctx reduce in one launch (both locally reduce bmax)
  smallfat_kernel<<<80, blk, 0, stream>>>(part, bmax, ksum, ctxp, vsump, ctxT);

  // 5) fused D_inv + q-scale + rowc
  dinvqs_kernel<<<MT, blk, 0, stream>>>(qfb, ksum, bmax, Dinv, rowc, qb);

  // 6) FAT: attnw GEMM (512 blocks) + pv (256 blocks) co-scheduled
  fat_attnw_pv<<<768, blk, 0, stream>>>(qb, kb, rowc, attnw, qfb, ctxT, Dinv, aob);

  // 7) Wo projection
  gemm_bn64<false, false><<<dim3(DM / 64, MT / 128), blk, 0, stream>>>(
      aob, Wot, bo, out2, MT, DM, DM);

  // 8) FFN
  ln_kernel<true><<<MT, blk, 0, stream>>>(out2, g1, beta1, h1b);
  gemm_mfma<true, true, 1><<<dim3(DFF / 128, MT / 128), blk, 0, stream>>>(
      h1b, W1t, b1, ff1b, MT, DFF, DM, DFF);
  gemm_bn64<false, false><<<dim3(DM / 64, MT / 128), blk, 0, stream>>>(
      ff1b, W2t, b2, ff2, MT, DM, DFF);
  ln_kernel<false><<<MT, blk, 0, stream>>>(ff2, g2, beta2, y_out);
}